// Round 1
// baseline (1267.778 us; speedup 1.0000x reference)
//
#include <hip/hip_runtime.h>
#include <hip/hip_bf16.h>
#include <math.h>

#define B_   64
#define NN_  1000
#define NV_  10
#define H_   128
#define FS_  8
#define FV_  6
#define T_   8
#define O_   64
#define EN_  512000
#define EV_  2560
#define NS_  (B_*NN_)   /* 64000 */
#define NVT_ (B_*NV_)   /* 640 */

__device__ __forceinline__ float fast_tanh(float x) {
  float ax = fabsf(x);
  float e  = __expf(2.f*ax);
  float t  = 1.f - 2.f/(e + 1.f);
  return x >= 0.f ? t : -t;
}
__device__ __forceinline__ float fast_sigmoid(float x) {
  return 1.f/(1.f + __expf(-x));
}

// ---------- CSR build ----------
__global__ __launch_bounds__(256) void k_count(const int* dst, int E, int* counts) {
  int i = blockIdx.x*256 + threadIdx.x;
  if (i < E) atomicAdd(&counts[dst[i]], 1);
}

__global__ __launch_bounds__(1024) void k_scan(const int* cnt, int n, int* rowptr) {
  __shared__ int sums[1024];
  int t = threadIdx.x;
  int C = (n + 1023) >> 10;
  int lo = t*C, hi = min(lo + C, n);
  int s = 0;
  for (int i = lo; i < hi; ++i) s += cnt[i];
  sums[t] = s;
  __syncthreads();
  for (int offd = 1; offd < 1024; offd <<= 1) {
    int v = (t >= offd) ? sums[t-offd] : 0;
    __syncthreads();
    sums[t] += v;
    __syncthreads();
  }
  int base = (t == 0) ? 0 : sums[t-1];
  for (int i = lo; i < hi; ++i) { rowptr[i] = base; base += cnt[i]; }
  if (t == 1023) rowptr[n] = sums[1023];
}

__global__ __launch_bounds__(256) void k_scatter(const int* src, const int* dst, int E,
                                                 const int* rowptr, int* cursor,
                                                 int* srcp, int* dstp) {
  int i = blockIdx.x*256 + threadIdx.x;
  if (i >= E) return;
  int d = dst[i];
  int pos = rowptr[d] + atomicAdd(&cursor[d], 1);
  srcp[pos] = src[i];
  dstp[pos] = d;
}

// ---------- GAT pieces ----------
__global__ __launch_bounds__(256) void k_edge_exp(int E, const int* srcp, const int* dstp,
                                                  const float* el, const float* er, float* expe) {
  int i = blockIdx.x*256 + threadIdx.x;
  if (i >= E) return;
  float e = el[srcp[i]] + er[dstp[i]];
  e = (e > 0.f) ? e : 0.2f*e;       // leaky_relu slope 0.2
  expe[i] = __expf(e);              // softmax shift skipped: |e| small, invariant
}

// one wave per dst node; 2 features per lane; normalized weighted sum + bias
__global__ __launch_bounds__(256) void k_aggregate(int nNodes, const int* rowptr,
                                                   const int* srcp, const float* expe,
                                                   const float* z, const float* bias, float* out) {
  int w = (blockIdx.x*256 + threadIdx.x) >> 6;
  int lane = threadIdx.x & 63;
  if (w >= nNodes) return;
  int beg = rowptr[w], end = rowptr[w+1];
  float a0 = 0.f, a1 = 0.f, wsum = 0.f;
  for (int i = beg; i < end; ++i) {
    int sI = srcp[i];
    float wt = expe[i];
    float2 zz = *(const float2*)(z + (size_t)sI*H_ + lane*2);
    a0 += wt*zz.x; a1 += wt*zz.y; wsum += wt;
  }
  float inv = (end > beg) ? 1.f/wsum : 0.f;   // empty segment -> bias only (matches ref)
  float2 o;
  o.x = a0*inv + bias[lane*2];
  o.y = a1*inv + bias[lane*2 + 1];
  *(float2*)(out + (size_t)w*H_ + lane*2) = o;
}

// ---------- generic f32 GEMM: C[M,N] = A[M,K] @ W[K,N] (+bias), optional el/er epilogue ----------
// block: 256 threads; tile 16 rows x 128 cols; W staged in 64-row LDS chunks
__global__ __launch_bounds__(256) void k_gemm(const float* A, int M, int K, int N,
                                              const float* W, const float* bias, float* C,
                                              const float* al, const float* ar,
                                              float* el, float* er) {
  __shared__ float Ws_[64*128];
  __shared__ float As_[16*128];
  __shared__ float redl[16][17];
  __shared__ float redr[16][17];
  int t = threadIdx.x;
  int j0 = blockIdx.y * 128;
  int row0 = blockIdx.x * 16;
  for (int l = t; l < 16*K; l += 256) {
    int r = l / K, k = l - r*K;
    int row = row0 + r;
    As_[r*K + k] = (row < M) ? A[(size_t)row*K + k] : 0.f;
  }
  int jg = t & 15, r = t >> 4;
  float acc[8];
  #pragma unroll
  for (int q = 0; q < 8; ++q) acc[q] = 0.f;
  for (int kc = 0; kc < K; kc += 64) {
    int kl = min(64, K - kc);
    __syncthreads();
    for (int l = t; l < (kl << 7); l += 256) {
      int k = l >> 7, j = l & 127;
      int jj = j0 + j;
      Ws_[l] = (jj < N) ? W[(size_t)(kc + k)*N + jj] : 0.f;
    }
    __syncthreads();
    for (int k = 0; k < kl; ++k) {
      float a = As_[r*K + kc + k];
      const float* wr = &Ws_[(k << 7) + jg*8];
      #pragma unroll
      for (int q = 0; q < 8; ++q) acc[q] += a * wr[q];
    }
  }
  int row = row0 + r;
  if (row < M) {
    float* crow = C + (size_t)row*N + j0 + jg*8;
    #pragma unroll
    for (int q = 0; q < 8; ++q) {
      int j = j0 + jg*8 + q;
      if (j < N) crow[q] = acc[q] + (bias ? bias[j] : 0.f);
    }
  }
  if (el) {   // only used on N==128 single-col-block calls
    float pl = 0.f, pr = 0.f;
    #pragma unroll
    for (int q = 0; q < 8; ++q) {
      int j = jg*8 + q;
      pl += acc[q]*al[j];
      pr += acc[q]*ar[j];
    }
    redl[r][jg] = pl; redr[r][jg] = pr;
    __syncthreads();
    if (t < 16) {
      float sl = 0.f, sr = 0.f;
      for (int q = 0; q < 16; ++q) { sl += redl[t][q]; sr += redr[t][q]; }
      int row2 = row0 + t;
      if (row2 < M) { el[row2] = sl; er[row2] = sr; }
    }
  }
}

// ---------- small transpose for weight re-layout ----------
__global__ __launch_bounds__(256) void k_transpose(const float* in, int inStride,
                                                   int K, int J, float* out) {
  int idx = blockIdx.x*256 + threadIdx.x;
  if (idx >= K*J) return;
  int k = idx / J, j = idx - k*J;
  out[idx] = in[(size_t)j*inStride + k];
}

// ---------- GRU decoder: one block per batch; gh dots wave-parallel ----------
__global__ __launch_bounds__(512) void k_decoder(const float* GI, const float* W_hh,
                                                 const float* b_hh, const float* W_attn,
                                                 const float* h0, float* A2) {
  int b = blockIdx.x;
  __shared__ float hprev[128];
  __shared__ float gh[384];
  int t = threadIdx.x;
  int lane = t & 63, wid = t >> 6;
  if (t < 128) hprev[t] = h0[t];
  __syncthreads();
  for (int s = 0; s < 10; ++s) {
    float2 h2 = *(const float2*)(hprev + lane*2);
    for (int j = wid; j < 384; j += 8) {
      float2 w = *(const float2*)(W_hh + (size_t)j*128 + lane*2);
      float p = w.x*h2.x + w.y*h2.y;
      #pragma unroll
      for (int o = 32; o; o >>= 1) p += __shfl_xor(p, o, 64);
      if (lane == 0) gh[j] = p + b_hh[j];
    }
    __syncthreads();
    if (t < 128) {
      const float* gi = GI + (size_t)(b*NV_ + s)*384;
      float rr = fast_sigmoid(gi[t]       + gh[t]);
      float zz = fast_sigmoid(gi[128 + t] + gh[128 + t]);
      float nn = fast_tanh   (gi[256 + t] + rr*gh[256 + t]);
      hprev[t] = (1.f - zz)*nn + zz*hprev[t];
    }
    __syncthreads();
    float2 hn2 = *(const float2*)(hprev + lane*2);
    for (int j = wid; j < 128; j += 8) {
      float2 w = *(const float2*)(W_attn + (size_t)j*256 + 128 + lane*2);
      float p = w.x*hn2.x + w.y*hn2.y;
      #pragma unroll
      for (int o = 32; o; o >>= 1) p += __shfl_xor(p, o, 64);
      if (lane == 0) A2[((size_t)s*B_ + b)*128 + j] = p;
    }
    __syncthreads();
  }
}

// ---------- attention score + mask: one wave per (b,n), loops 10 steps ----------
__global__ __launch_bounds__(256) void k_attn(const float* A1, const float* A2,
                                              const float* v_attn, const int* vnr_VNF,
                                              const int* net_VNF, float* pi) {
  int g = (blockIdx.x*256 + threadIdx.x) >> 6;
  int lane = threadIdx.x & 63;
  if (g >= NS_) return;
  int b = g / NN_, n = g - b*NN_;
  float2 a1 = *(const float2*)(A1 + (size_t)g*H_ + lane*2);
  float2 vv = *(const float2*)(v_attn + lane*2);
  for (int s = 0; s < NV_; ++s) {
    float2 a2 = *(const float2*)(A2 + ((size_t)s*B_ + b)*H_ + lane*2);
    float p = vv.x*fast_tanh(a1.x + a2.x) + vv.y*fast_tanh(a1.y + a2.y);
    #pragma unroll
    for (int o = 32; o; o >>= 1) p += __shfl_xor(p, o, 64);
    if (lane == 0) {
      int vnf = vnr_VNF[b*NV_ + s];
      int m   = net_VNF[(size_t)g*T_ + vnf];
      pi[(size_t)b*(NV_*NN_) + s*NN_ + n] = p + __logf((float)m);
    }
  }
}

// ---------- value head ----------
__global__ __launch_bounds__(128) void k_y1(const float* Hv, const float* nmask, float* y1) {
  int b = blockIdx.x, h = threadIdx.x;
  float s = 0.f, d = 0.f;
  for (int i = 0; i < NV_; ++i) {
    float m = nmask[b*NV_ + i];
    s += Hv[(size_t)(b*NV_ + i)*H_ + h]*m;
    d += m;
  }
  y1[b*H_ + h] = s/d;
}

__global__ __launch_bounds__(128) void k_y2(const float* Hs, float* y2) {
  int b = blockIdx.x, slice = blockIdx.y, h = threadIdx.x;
  int n0 = slice*125, n1 = n0 + 125;
  float s = 0.f;
  for (int n = n0; n < n1; ++n) s += Hs[((size_t)b*NN_ + n)*H_ + h];
  atomicAdd(&y2[b*H_ + h], s);
}

__global__ __launch_bounds__(64) void k_value(const float* y1, const float* y2,
                                              const float* W_out, const float* b_out,
                                              float* val) {
  int b = blockIdx.x, o = threadIdx.x;
  const float* w = W_out + (size_t)o*256;
  float s = b_out[o];
  for (int h = 0; h < H_; ++h)
    s += y1[b*H_ + h]*w[h] + (y2[b*H_ + h]*(1.f/1000.f))*w[128 + h];
  val[b*O_ + o] = s;
}

extern "C" void kernel_launch(void* const* d_in, const int* in_sizes, int n_in,
                              void* d_out, int out_size, void* d_ws, size_t ws_size,
                              hipStream_t stream) {
  (void)in_sizes; (void)n_in; (void)out_size; (void)ws_size;
  const float* static_feat = (const float*)d_in[0];
  const float* vnr_feat    = (const float*)d_in[1];
  const float* nmask       = (const float*)d_in[2];
  const float* Ws1 = (const float*)d_in[3];  const float* als1 = (const float*)d_in[4];
  const float* ars1 = (const float*)d_in[5]; const float* bs1 = (const float*)d_in[6];
  const float* Ws2 = (const float*)d_in[7];  const float* als2 = (const float*)d_in[8];
  const float* ars2 = (const float*)d_in[9]; const float* bs2 = (const float*)d_in[10];
  const float* Ws3 = (const float*)d_in[11]; const float* als3 = (const float*)d_in[12];
  const float* ars3 = (const float*)d_in[13]; const float* bs3 = (const float*)d_in[14];
  const float* Wv1 = (const float*)d_in[15]; const float* alv1 = (const float*)d_in[16];
  const float* arv1 = (const float*)d_in[17]; const float* bv1 = (const float*)d_in[18];
  const float* Wv2 = (const float*)d_in[19]; const float* alv2 = (const float*)d_in[20];
  const float* arv2 = (const float*)d_in[21]; const float* bv2 = (const float*)d_in[22];
  const float* Wv3 = (const float*)d_in[23]; const float* alv3 = (const float*)d_in[24];
  const float* arv3 = (const float*)d_in[25]; const float* bv3 = (const float*)d_in[26];
  const float* W_attn = (const float*)d_in[27];
  const float* v_attn = (const float*)d_in[28];
  const float* W_ih = (const float*)d_in[29];
  const float* W_hh = (const float*)d_in[30];
  const float* b_ih = (const float*)d_in[31];
  const float* b_hh = (const float*)d_in[32];
  const float* h0   = (const float*)d_in[33];
  const float* W_out = (const float*)d_in[34];
  const float* b_out = (const float*)d_in[35];
  const int* src_s = (const int*)d_in[36];
  const int* dst_s = (const int*)d_in[37];
  const int* src_v = (const int*)d_in[38];
  const int* dst_v = (const int*)d_in[39];
  const int* vnr_VNF = (const int*)d_in[40];
  const int* net_VNF = (const int*)d_in[41];

  char* ws = (char*)d_ws;
  size_t off = 0;
  auto alloc = [&](size_t bytes) -> char* {
    off = (off + 255) & ~(size_t)255;
    char* p = ws + off;
    off += bytes;
    return p;
  };
  float* Z    = (float*)alloc((size_t)NS_*H_*4);   // z buffer; later A1
  float* Hs   = (float*)alloc((size_t)NS_*H_*4);   // static hidden
  float* Zv   = (float*)alloc((size_t)NVT_*H_*4);
  float* Hv   = (float*)alloc((size_t)NVT_*H_*4);
  float* el_s = (float*)alloc((size_t)NS_*4);
  float* er_s = (float*)alloc((size_t)NS_*4);
  float* el_v = (float*)alloc((size_t)NVT_*4);
  float* er_v = (float*)alloc((size_t)NVT_*4);
  // contiguous zero block: counts_s, cursor_s, counts_v, cursor_v, y2
  size_t zcount = (size_t)NS_ + NS_ + NVT_ + NVT_ + B_*H_;
  char* zb = alloc(zcount*4);
  int*   counts_s = (int*)zb;
  int*   cursor_s = counts_s + NS_;
  int*   counts_v = cursor_s + NS_;
  int*   cursor_v = counts_v + NVT_;
  float* y2buf    = (float*)(cursor_v + NVT_);
  int* rowptr_s = (int*)alloc((size_t)(NS_+1)*4);
  int* rowptr_v = (int*)alloc((size_t)(NVT_+1)*4);
  int* srcp_s   = (int*)alloc((size_t)EN_*4);
  int* dstp_s   = (int*)alloc((size_t)EN_*4);
  float* expe_s = (float*)alloc((size_t)EN_*4);
  int* srcp_v   = (int*)alloc((size_t)EV_*4);
  int* dstp_v   = (int*)alloc((size_t)EV_*4);
  float* expe_v = (float*)alloc((size_t)EV_*4);
  float* WTattn = (float*)alloc((size_t)H_*H_*4);       // [k][j] = W_attn[j, k], k<128
  float* WTih   = (float*)alloc((size_t)H_*384*4);      // [k][j] = W_ih[j, k]
  float* GI     = (float*)alloc((size_t)NVT_*384*4);    // x @ W_ih^T + b_ih for all (b,s)
  float* A2     = (float*)alloc((size_t)NV_*B_*H_*4);
  float* y1buf  = (float*)alloc((size_t)B_*H_*4);

  float* pi  = (float*)d_out;
  float* val = pi + (size_t)B_*NV_*NN_;

  hipMemsetAsync(zb, 0, zcount*4, stream);

  // weight re-layouts
  k_transpose<<<(H_*H_ + 255)/256, 256, 0, stream>>>(W_attn, 256, H_, H_, WTattn);
  k_transpose<<<(H_*384 + 255)/256, 256, 0, stream>>>(W_ih, 128, H_, 384, WTih);

  // CSR build (both graphs)
  k_count<<<EN_/256, 256, 0, stream>>>(dst_s, EN_, counts_s);
  k_count<<<EV_/256, 256, 0, stream>>>(dst_v, EV_, counts_v);
  k_scan<<<1, 1024, 0, stream>>>(counts_s, NS_, rowptr_s);
  k_scan<<<1, 1024, 0, stream>>>(counts_v, NVT_, rowptr_v);
  k_scatter<<<EN_/256, 256, 0, stream>>>(src_s, dst_s, EN_, rowptr_s, cursor_s, srcp_s, dstp_s);
  k_scatter<<<EV_/256, 256, 0, stream>>>(src_v, dst_v, EV_, rowptr_v, cursor_v, srcp_v, dstp_v);

  dim3 gemmS(NS_/16, 1), gemmV(NVT_/16, 1);
  int aggS = (NS_ + 3)/4, aggV = (NVT_ + 3)/4;

  // ---- static GAT stack ----
  k_gemm<<<gemmS, 256, 0, stream>>>(static_feat, NS_, FS_, H_, Ws1, nullptr, Z, als1, ars1, el_s, er_s);
  k_edge_exp<<<EN_/256, 256, 0, stream>>>(EN_, srcp_s, dstp_s, el_s, er_s, expe_s);
  k_aggregate<<<aggS, 256, 0, stream>>>(NS_, rowptr_s, srcp_s, expe_s, Z, bs1, Hs);
  k_gemm<<<gemmS, 256, 0, stream>>>(Hs, NS_, H_, H_, Ws2, nullptr, Z, als2, ars2, el_s, er_s);
  k_edge_exp<<<EN_/256, 256, 0, stream>>>(EN_, srcp_s, dstp_s, el_s, er_s, expe_s);
  k_aggregate<<<aggS, 256, 0, stream>>>(NS_, rowptr_s, srcp_s, expe_s, Z, bs2, Hs);
  k_gemm<<<gemmS, 256, 0, stream>>>(Hs, NS_, H_, H_, Ws3, nullptr, Z, als3, ars3, el_s, er_s);
  k_edge_exp<<<EN_/256, 256, 0, stream>>>(EN_, srcp_s, dstp_s, el_s, er_s, expe_s);
  k_aggregate<<<aggS, 256, 0, stream>>>(NS_, rowptr_s, srcp_s, expe_s, Z, bs3, Hs);

  // ---- vnr GAT stack ----
  k_gemm<<<gemmV, 256, 0, stream>>>(vnr_feat, NVT_, FV_, H_, Wv1, nullptr, Zv, alv1, arv1, el_v, er_v);
  k_edge_exp<<<EV_/256, 256, 0, stream>>>(EV_, srcp_v, dstp_v, el_v, er_v, expe_v);
  k_aggregate<<<aggV, 256, 0, stream>>>(NVT_, rowptr_v, srcp_v, expe_v, Zv, bv1, Hv);
  k_gemm<<<gemmV, 256, 0, stream>>>(Hv, NVT_, H_, H_, Wv2, nullptr, Zv, alv2, arv2, el_v, er_v);
  k_edge_exp<<<EV_/256, 256, 0, stream>>>(EV_, srcp_v, dstp_v, el_v, er_v, expe_v);
  k_aggregate<<<aggV, 256, 0, stream>>>(NVT_, rowptr_v, srcp_v, expe_v, Zv, bv2, Hv);
  k_gemm<<<gemmV, 256, 0, stream>>>(Hv, NVT_, H_, H_, Wv3, nullptr, Zv, alv3, arv3, el_v, er_v);
  k_edge_exp<<<EV_/256, 256, 0, stream>>>(EV_, srcp_v, dstp_v, el_v, er_v, expe_v);
  k_aggregate<<<aggV, 256, 0, stream>>>(NVT_, rowptr_v, srcp_v, expe_v, Zv, bv3, Hv);

  // ---- decoder precomputation ----
  // GI[row(b,s), j] = sum_k Hv[row,k]*W_ih[j,k] + b_ih[j]
  k_gemm<<<dim3(NVT_/16, 3), 256, 0, stream>>>(Hv, NVT_, H_, 384, WTih, b_ih, GI,
                                               nullptr, nullptr, nullptr, nullptr);
  // A1[b*NN+n, h] = sum_k Hs[.,k]*W_attn[h,k]  (reuses Z)
  k_gemm<<<gemmS, 256, 0, stream>>>(Hs, NS_, H_, H_, WTattn, nullptr, Z,
                                    nullptr, nullptr, nullptr, nullptr);
  // sequential GRU + A2
  k_decoder<<<B_, 512, 0, stream>>>(GI, W_hh, b_hh, W_attn, h0, A2);
  // pi
  k_attn<<<(NS_ + 3)/4, 256, 0, stream>>>(Z, A2, v_attn, vnr_VNF, net_VNF, pi);

  // ---- value head ----
  k_y1<<<B_, 128, 0, stream>>>(Hv, nmask, y1buf);
  k_y2<<<dim3(B_, 8), 128, 0, stream>>>(Hs, y2buf);
  k_value<<<B_, 64, 0, stream>>>(y1buf, y2buf, W_out, b_out, val);
}

// Round 2
// 1088.904 us; speedup vs baseline: 1.1643x; 1.1643x over previous
//
#include <hip/hip_runtime.h>
#include <hip/hip_bf16.h>
#include <math.h>

#define B_   64
#define NN_  1000
#define NV_  10
#define H_   128
#define FS_  8
#define FV_  6
#define T_   8
#define O_   64
#define EN_  512000
#define EV_  2560
#define NS_  (B_*NN_)   /* 64000 */
#define NVT_ (B_*NV_)   /* 640 */

__device__ __forceinline__ float fast_tanh(float x) {
  float ax = fabsf(x);
  float e  = __expf(2.f*ax);
  float t  = 1.f - 2.f/(e + 1.f);
  return x >= 0.f ? t : -t;
}
__device__ __forceinline__ float fast_sigmoid(float x) {
  return 1.f/(1.f + __expf(-x));
}

// ---------- CSR build ----------
__global__ __launch_bounds__(256) void k_count(const int* dst, int E, int* counts) {
  int i = blockIdx.x*256 + threadIdx.x;
  if (i < E) atomicAdd(&counts[dst[i]], 1);
}

__global__ __launch_bounds__(1024) void k_scan(const int* cnt, int n, int* rowptr) {
  __shared__ int sums[1024];
  int t = threadIdx.x;
  int C = (n + 1023) >> 10;
  int lo = t*C, hi = min(lo + C, n);
  int s = 0;
  for (int i = lo; i < hi; ++i) s += cnt[i];
  sums[t] = s;
  __syncthreads();
  for (int offd = 1; offd < 1024; offd <<= 1) {
    int v = (t >= offd) ? sums[t-offd] : 0;
    __syncthreads();
    sums[t] += v;
    __syncthreads();
  }
  int base = (t == 0) ? 0 : sums[t-1];
  for (int i = lo; i < hi; ++i) { rowptr[i] = base; base += cnt[i]; }
  if (t == 1023) rowptr[n] = sums[1023];
}

__global__ __launch_bounds__(256) void k_scatter(const int* src, const int* dst, int E,
                                                 const int* rowptr, int* cursor,
                                                 int* srcp, int* dstp) {
  int i = blockIdx.x*256 + threadIdx.x;
  if (i >= E) return;
  int d = dst[i];
  int pos = rowptr[d] + atomicAdd(&cursor[d], 1);
  srcp[pos] = src[i];
  dstp[pos] = d;
}

// ---------- GAT pieces ----------
__global__ __launch_bounds__(256) void k_edge_exp(int E, const int* srcp, const int* dstp,
                                                  const float* el, const float* er, float* expe) {
  int i = blockIdx.x*256 + threadIdx.x;
  if (i >= E) return;
  float e = el[srcp[i]] + er[dstp[i]];
  e = (e > 0.f) ? e : 0.2f*e;       // leaky_relu slope 0.2
  expe[i] = __expf(e);              // softmax shift skipped: |e| small, invariant
}

// one wave per dst node; 2 features per lane; normalized weighted sum + bias
__global__ __launch_bounds__(256) void k_aggregate(int nNodes, const int* rowptr,
                                                   const int* srcp, const float* expe,
                                                   const float* z, const float* bias, float* out) {
  int w = (blockIdx.x*256 + threadIdx.x) >> 6;
  int lane = threadIdx.x & 63;
  if (w >= nNodes) return;
  int beg = rowptr[w], end = rowptr[w+1];
  float a0 = 0.f, a1 = 0.f, wsum = 0.f;
  for (int i = beg; i < end; ++i) {
    int sI = srcp[i];
    float wt = expe[i];
    float2 zz = *(const float2*)(z + (size_t)sI*H_ + lane*2);
    a0 += wt*zz.x; a1 += wt*zz.y; wsum += wt;
  }
  float inv = (end > beg) ? 1.f/wsum : 0.f;   // empty segment -> bias only (matches ref)
  float2 o;
  o.x = a0*inv + bias[lane*2];
  o.y = a1*inv + bias[lane*2 + 1];
  *(float2*)(out + (size_t)w*H_ + lane*2) = o;
}

// ---------- generic f32 GEMM: C[M,N] = A[M,K] @ W[K,N] (+bias), optional el/er epilogue ----------
__global__ __launch_bounds__(256) void k_gemm(const float* A, int M, int K, int N,
                                              const float* W, const float* bias, float* C,
                                              const float* al, const float* ar,
                                              float* el, float* er) {
  __shared__ float Ws_[64*128];
  __shared__ float As_[16*128];
  __shared__ float redl[16][17];
  __shared__ float redr[16][17];
  int t = threadIdx.x;
  int j0 = blockIdx.y * 128;
  int row0 = blockIdx.x * 16;
  for (int l = t; l < 16*K; l += 256) {
    int r = l / K, k = l - r*K;
    int row = row0 + r;
    As_[r*K + k] = (row < M) ? A[(size_t)row*K + k] : 0.f;
  }
  int jg = t & 15, r = t >> 4;
  float acc[8];
  #pragma unroll
  for (int q = 0; q < 8; ++q) acc[q] = 0.f;
  for (int kc = 0; kc < K; kc += 64) {
    int kl = min(64, K - kc);
    __syncthreads();
    for (int l = t; l < (kl << 7); l += 256) {
      int k = l >> 7, j = l & 127;
      int jj = j0 + j;
      Ws_[l] = (jj < N) ? W[(size_t)(kc + k)*N + jj] : 0.f;
    }
    __syncthreads();
    for (int k = 0; k < kl; ++k) {
      float a = As_[r*K + kc + k];
      const float* wr = &Ws_[(k << 7) + jg*8];
      #pragma unroll
      for (int q = 0; q < 8; ++q) acc[q] += a * wr[q];
    }
  }
  int row = row0 + r;
  if (row < M) {
    float* crow = C + (size_t)row*N + j0 + jg*8;
    #pragma unroll
    for (int q = 0; q < 8; ++q) {
      int j = j0 + jg*8 + q;
      if (j < N) crow[q] = acc[q] + (bias ? bias[j] : 0.f);
    }
  }
  if (el) {   // only used on N==128 single-col-block calls
    float pl = 0.f, pr = 0.f;
    #pragma unroll
    for (int q = 0; q < 8; ++q) {
      int j = jg*8 + q;
      pl += acc[q]*al[j];
      pr += acc[q]*ar[j];
    }
    redl[r][jg] = pl; redr[r][jg] = pr;
    __syncthreads();
    if (t < 16) {
      float sl = 0.f, sr = 0.f;
      for (int q = 0; q < 16; ++q) { sl += redl[t][q]; sr += redr[t][q]; }
      int row2 = row0 + t;
      if (row2 < M) { el[row2] = sl; er[row2] = sr; }
    }
  }
}

// ---------- small transpose for weight re-layout ----------
__global__ __launch_bounds__(256) void k_transpose(const float* in, int inStride,
                                                   int K, int J, float* out) {
  int idx = blockIdx.x*256 + threadIdx.x;
  if (idx >= K*J) return;
  int k = idx / J, j = idx - k*J;
  out[idx] = in[(size_t)j*inStride + k];
}

// ---------- GRU decoder: one block per batch; per-thread dot products ----------
// Latency-bound kernel: avoid wave-level shuffle reductions (6-deep dependent
// chains serialized 48x per step was 250us). Per-thread dots pipeline L2 loads.
__global__ __launch_bounds__(512) void k_decoder(const float* __restrict__ GI,
                                                 const float* __restrict__ W_hh,
                                                 const float* __restrict__ b_hh,
                                                 const float* __restrict__ W_attn,
                                                 const float* __restrict__ h0,
                                                 float* __restrict__ A2) {
  int b = blockIdx.x;
  __shared__ float h[128];
  __shared__ float gh[384];
  int t = threadIdx.x;
  if (t < 128) h[t] = h0[t];
  __syncthreads();
  for (int s = 0; s < 10; ++s) {
    // gh[j] = dot(W_hh[j,:], h) + b_hh[j]  -- one thread per j
    if (t < 384) {
      const float4* wr = (const float4*)(W_hh + (size_t)t*128);
      const float4* hv = (const float4*)h;
      float a0 = 0.f, a1 = 0.f, a2 = 0.f, a3 = 0.f;
      #pragma unroll
      for (int k = 0; k < 32; k += 4) {
        float4 w0 = wr[k+0], x0 = hv[k+0];
        float4 w1 = wr[k+1], x1 = hv[k+1];
        float4 w2 = wr[k+2], x2 = hv[k+2];
        float4 w3 = wr[k+3], x3 = hv[k+3];
        a0 += w0.x*x0.x + w0.y*x0.y + w0.z*x0.z + w0.w*x0.w;
        a1 += w1.x*x1.x + w1.y*x1.y + w1.z*x1.z + w1.w*x1.w;
        a2 += w2.x*x2.x + w2.y*x2.y + w2.z*x2.z + w2.w*x2.w;
        a3 += w3.x*x3.x + w3.y*x3.y + w3.z*x3.z + w3.w*x3.w;
      }
      gh[t] = (a0 + a1) + (a2 + a3) + b_hh[t];
    }
    __syncthreads();
    // gates
    if (t < 128) {
      const float* gi = GI + (size_t)(b*NV_ + s)*384;
      float rr = fast_sigmoid(gi[t]       + gh[t]);
      float zz = fast_sigmoid(gi[128 + t] + gh[128 + t]);
      float nn = fast_tanh   (gi[256 + t] + rr*gh[256 + t]);
      h[t] = (1.f - zz)*nn + zz*h[t];
    }
    __syncthreads();
    // A2[j] = dot(W_attn[j, 128:256], h_new) -- 4 threads per j, 2 shuffles
    {
      int j = t >> 2, part = t & 3;
      const float4* wr = (const float4*)(W_attn + (size_t)j*256 + 128 + part*32);
      const float4* hv = (const float4*)(h + part*32);
      float a0 = 0.f, a1 = 0.f;
      #pragma unroll
      for (int k = 0; k < 8; k += 2) {
        float4 w0 = wr[k+0], x0 = hv[k+0];
        float4 w1 = wr[k+1], x1 = hv[k+1];
        a0 += w0.x*x0.x + w0.y*x0.y + w0.z*x0.z + w0.w*x0.w;
        a1 += w1.x*x1.x + w1.y*x1.y + w1.z*x1.z + w1.w*x1.w;
      }
      float p = a0 + a1;
      p += __shfl_xor(p, 1, 64);
      p += __shfl_xor(p, 2, 64);
      if (part == 0) A2[((size_t)s*B_ + b)*128 + j] = p;
    }
    __syncthreads();
  }
}

// ---------- attention score + mask: one wave per (b,n), loops 10 steps ----------
__global__ __launch_bounds__(256) void k_attn(const float* A1, const float* A2,
                                              const float* v_attn, const int* vnr_VNF,
                                              const int* net_VNF, float* pi) {
  int g = (blockIdx.x*256 + threadIdx.x) >> 6;
  int lane = threadIdx.x & 63;
  if (g >= NS_) return;
  int b = g / NN_, n = g - b*NN_;
  float2 a1 = *(const float2*)(A1 + (size_t)g*H_ + lane*2);
  float2 vv = *(const float2*)(v_attn + lane*2);
  for (int s = 0; s < NV_; ++s) {
    float2 a2 = *(const float2*)(A2 + ((size_t)s*B_ + b)*H_ + lane*2);
    float p = vv.x*fast_tanh(a1.x + a2.x) + vv.y*fast_tanh(a1.y + a2.y);
    #pragma unroll
    for (int o = 32; o; o >>= 1) p += __shfl_xor(p, o, 64);
    if (lane == 0) {
      int vnf = vnr_VNF[b*NV_ + s];
      int m   = net_VNF[(size_t)g*T_ + vnf];
      pi[(size_t)b*(NV_*NN_) + s*NN_ + n] = p + __logf((float)m);
    }
  }
}

// ---------- value head ----------
__global__ __launch_bounds__(128) void k_y1(const float* Hv, const float* nmask, float* y1) {
  int b = blockIdx.x, h = threadIdx.x;
  float s = 0.f, d = 0.f;
  for (int i = 0; i < NV_; ++i) {
    float m = nmask[b*NV_ + i];
    s += Hv[(size_t)(b*NV_ + i)*H_ + h]*m;
    d += m;
  }
  y1[b*H_ + h] = s/d;
}

__global__ __launch_bounds__(128) void k_y2(const float* Hs, float* y2) {
  int b = blockIdx.x, slice = blockIdx.y, h = threadIdx.x;
  int n0 = slice*125, n1 = n0 + 125;
  float s = 0.f;
  for (int n = n0; n < n1; ++n) s += Hs[((size_t)b*NN_ + n)*H_ + h];
  atomicAdd(&y2[b*H_ + h], s);
}

__global__ __launch_bounds__(64) void k_value(const float* y1, const float* y2,
                                              const float* W_out, const float* b_out,
                                              float* val) {
  int b = blockIdx.x, o = threadIdx.x;
  const float* w = W_out + (size_t)o*256;
  float s = b_out[o];
  for (int h = 0; h < H_; ++h)
    s += y1[b*H_ + h]*w[h] + (y2[b*H_ + h]*(1.f/1000.f))*w[128 + h];
  val[b*O_ + o] = s;
}

extern "C" void kernel_launch(void* const* d_in, const int* in_sizes, int n_in,
                              void* d_out, int out_size, void* d_ws, size_t ws_size,
                              hipStream_t stream) {
  (void)in_sizes; (void)n_in; (void)out_size; (void)ws_size;
  const float* static_feat = (const float*)d_in[0];
  const float* vnr_feat    = (const float*)d_in[1];
  const float* nmask       = (const float*)d_in[2];
  const float* Ws1 = (const float*)d_in[3];  const float* als1 = (const float*)d_in[4];
  const float* ars1 = (const float*)d_in[5]; const float* bs1 = (const float*)d_in[6];
  const float* Ws2 = (const float*)d_in[7];  const float* als2 = (const float*)d_in[8];
  const float* ars2 = (const float*)d_in[9]; const float* bs2 = (const float*)d_in[10];
  const float* Ws3 = (const float*)d_in[11]; const float* als3 = (const float*)d_in[12];
  const float* ars3 = (const float*)d_in[13]; const float* bs3 = (const float*)d_in[14];
  const float* Wv1 = (const float*)d_in[15]; const float* alv1 = (const float*)d_in[16];
  const float* arv1 = (const float*)d_in[17]; const float* bv1 = (const float*)d_in[18];
  const float* Wv2 = (const float*)d_in[19]; const float* alv2 = (const float*)d_in[20];
  const float* arv2 = (const float*)d_in[21]; const float* bv2 = (const float*)d_in[22];
  const float* Wv3 = (const float*)d_in[23]; const float* alv3 = (const float*)d_in[24];
  const float* arv3 = (const float*)d_in[25]; const float* bv3 = (const float*)d_in[26];
  const float* W_attn = (const float*)d_in[27];
  const float* v_attn = (const float*)d_in[28];
  const float* W_ih = (const float*)d_in[29];
  const float* W_hh = (const float*)d_in[30];
  const float* b_ih = (const float*)d_in[31];
  const float* b_hh = (const float*)d_in[32];
  const float* h0   = (const float*)d_in[33];
  const float* W_out = (const float*)d_in[34];
  const float* b_out = (const float*)d_in[35];
  const int* src_s = (const int*)d_in[36];
  const int* dst_s = (const int*)d_in[37];
  const int* src_v = (const int*)d_in[38];
  const int* dst_v = (const int*)d_in[39];
  const int* vnr_VNF = (const int*)d_in[40];
  const int* net_VNF = (const int*)d_in[41];

  char* ws = (char*)d_ws;
  size_t off = 0;
  auto alloc = [&](size_t bytes) -> char* {
    off = (off + 255) & ~(size_t)255;
    char* p = ws + off;
    off += bytes;
    return p;
  };
  float* Z    = (float*)alloc((size_t)NS_*H_*4);   // z buffer; later A1
  float* Hs   = (float*)alloc((size_t)NS_*H_*4);   // static hidden
  float* Zv   = (float*)alloc((size_t)NVT_*H_*4);
  float* Hv   = (float*)alloc((size_t)NVT_*H_*4);
  float* el_s = (float*)alloc((size_t)NS_*4);
  float* er_s = (float*)alloc((size_t)NS_*4);
  float* el_v = (float*)alloc((size_t)NVT_*4);
  float* er_v = (float*)alloc((size_t)NVT_*4);
  size_t zcount = (size_t)NS_ + NS_ + NVT_ + NVT_ + B_*H_;
  char* zb = alloc(zcount*4);
  int*   counts_s = (int*)zb;
  int*   cursor_s = counts_s + NS_;
  int*   counts_v = cursor_s + NS_;
  int*   cursor_v = counts_v + NVT_;
  float* y2buf    = (float*)(cursor_v + NVT_);
  int* rowptr_s = (int*)alloc((size_t)(NS_+1)*4);
  int* rowptr_v = (int*)alloc((size_t)(NVT_+1)*4);
  int* srcp_s   = (int*)alloc((size_t)EN_*4);
  int* dstp_s   = (int*)alloc((size_t)EN_*4);
  float* expe_s = (float*)alloc((size_t)EN_*4);
  int* srcp_v   = (int*)alloc((size_t)EV_*4);
  int* dstp_v   = (int*)alloc((size_t)EV_*4);
  float* expe_v = (float*)alloc((size_t)EV_*4);
  float* WTattn = (float*)alloc((size_t)H_*H_*4);
  float* WTih   = (float*)alloc((size_t)H_*384*4);
  float* GI     = (float*)alloc((size_t)NVT_*384*4);
  float* A2     = (float*)alloc((size_t)NV_*B_*H_*4);
  float* y1buf  = (float*)alloc((size_t)B_*H_*4);

  float* pi  = (float*)d_out;
  float* val = pi + (size_t)B_*NV_*NN_;

  hipMemsetAsync(zb, 0, zcount*4, stream);

  // weight re-layouts
  k_transpose<<<(H_*H_ + 255)/256, 256, 0, stream>>>(W_attn, 256, H_, H_, WTattn);
  k_transpose<<<(H_*384 + 255)/256, 256, 0, stream>>>(W_ih, 128, H_, 384, WTih);

  // CSR build (both graphs)
  k_count<<<EN_/256, 256, 0, stream>>>(dst_s, EN_, counts_s);
  k_count<<<EV_/256, 256, 0, stream>>>(dst_v, EV_, counts_v);
  k_scan<<<1, 1024, 0, stream>>>(counts_s, NS_, rowptr_s);
  k_scan<<<1, 1024, 0, stream>>>(counts_v, NVT_, rowptr_v);
  k_scatter<<<EN_/256, 256, 0, stream>>>(src_s, dst_s, EN_, rowptr_s, cursor_s, srcp_s, dstp_s);
  k_scatter<<<EV_/256, 256, 0, stream>>>(src_v, dst_v, EV_, rowptr_v, cursor_v, srcp_v, dstp_v);

  dim3 gemmS(NS_/16, 1), gemmV(NVT_/16, 1);
  int aggS = (NS_ + 3)/4, aggV = (NVT_ + 3)/4;

  // ---- static GAT stack ----
  k_gemm<<<gemmS, 256, 0, stream>>>(static_feat, NS_, FS_, H_, Ws1, nullptr, Z, als1, ars1, el_s, er_s);
  k_edge_exp<<<EN_/256, 256, 0, stream>>>(EN_, srcp_s, dstp_s, el_s, er_s, expe_s);
  k_aggregate<<<aggS, 256, 0, stream>>>(NS_, rowptr_s, srcp_s, expe_s, Z, bs1, Hs);
  k_gemm<<<gemmS, 256, 0, stream>>>(Hs, NS_, H_, H_, Ws2, nullptr, Z, als2, ars2, el_s, er_s);
  k_edge_exp<<<EN_/256, 256, 0, stream>>>(EN_, srcp_s, dstp_s, el_s, er_s, expe_s);
  k_aggregate<<<aggS, 256, 0, stream>>>(NS_, rowptr_s, srcp_s, expe_s, Z, bs2, Hs);
  k_gemm<<<gemmS, 256, 0, stream>>>(Hs, NS_, H_, H_, Ws3, nullptr, Z, als3, ars3, el_s, er_s);
  k_edge_exp<<<EN_/256, 256, 0, stream>>>(EN_, srcp_s, dstp_s, el_s, er_s, expe_s);
  k_aggregate<<<aggS, 256, 0, stream>>>(NS_, rowptr_s, srcp_s, expe_s, Z, bs3, Hs);

  // ---- vnr GAT stack ----
  k_gemm<<<gemmV, 256, 0, stream>>>(vnr_feat, NVT_, FV_, H_, Wv1, nullptr, Zv, alv1, arv1, el_v, er_v);
  k_edge_exp<<<EV_/256, 256, 0, stream>>>(EV_, srcp_v, dstp_v, el_v, er_v, expe_v);
  k_aggregate<<<aggV, 256, 0, stream>>>(NVT_, rowptr_v, srcp_v, expe_v, Zv, bv1, Hv);
  k_gemm<<<gemmV, 256, 0, stream>>>(Hv, NVT_, H_, H_, Wv2, nullptr, Zv, alv2, arv2, el_v, er_v);
  k_edge_exp<<<EV_/256, 256, 0, stream>>>(EV_, srcp_v, dstp_v, el_v, er_v, expe_v);
  k_aggregate<<<aggV, 256, 0, stream>>>(NVT_, rowptr_v, srcp_v, expe_v, Zv, bv2, Hv);
  k_gemm<<<gemmV, 256, 0, stream>>>(Hv, NVT_, H_, H_, Wv3, nullptr, Zv, alv3, arv3, el_v, er_v);
  k_edge_exp<<<EV_/256, 256, 0, stream>>>(EV_, srcp_v, dstp_v, el_v, er_v, expe_v);
  k_aggregate<<<aggV, 256, 0, stream>>>(NVT_, rowptr_v, srcp_v, expe_v, Zv, bv3, Hv);

  // ---- decoder precomputation ----
  k_gemm<<<dim3(NVT_/16, 3), 256, 0, stream>>>(Hv, NVT_, H_, 384, WTih, b_ih, GI,
                                               nullptr, nullptr, nullptr, nullptr);
  k_gemm<<<gemmS, 256, 0, stream>>>(Hs, NS_, H_, H_, WTattn, nullptr, Z,
                                    nullptr, nullptr, nullptr, nullptr);
  k_decoder<<<B_, 512, 0, stream>>>(GI, W_hh, b_hh, W_attn, h0, A2);
  k_attn<<<(NS_ + 3)/4, 256, 0, stream>>>(Z, A2, v_attn, vnr_VNF, net_VNF, pi);

  // ---- value head ----
  k_y1<<<B_, 128, 0, stream>>>(Hv, nmask, y1buf);
  k_y2<<<dim3(B_, 8), 128, 0, stream>>>(Hs, y2buf);
  k_value<<<B_, 64, 0, stream>>>(y1buf, y2buf, W_out, b_out, val);
}

// Round 3
// 727.458 us; speedup vs baseline: 1.7428x; 1.4969x over previous
//
#include <hip/hip_runtime.h>
#include <hip/hip_bf16.h>
#include <math.h>

#define B_   64
#define NN_  1000
#define NV_  10
#define H_   128
#define FS_  8
#define FV_  6
#define T_   8
#define O_   64
#define EN_  512000
#define EV_  2560
#define NS_  (B_*NN_)   /* 64000 */
#define NVT_ (B_*NV_)   /* 640 */

typedef __attribute__((ext_vector_type(8))) short short8v;   // 8 bf16
typedef __attribute__((ext_vector_type(4))) float floatx4;

__device__ __forceinline__ float fast_tanh(float x) {
  float ax = fabsf(x);
  float e  = __expf(2.f*ax);
  float t  = 1.f - 2.f/(e + 1.f);
  return x >= 0.f ? t : -t;
}
__device__ __forceinline__ float fast_sigmoid(float x) {
  return 1.f/(1.f + __expf(-x));
}
__device__ __forceinline__ unsigned short bf16_rne(float x) {
  unsigned u = __float_as_uint(x);
  return (unsigned short)((u + 0x7FFFu + ((u >> 16) & 1u)) >> 16);
}
__device__ __forceinline__ float bf16_tof(unsigned short b) {
  return __uint_as_float(((unsigned)b) << 16);
}

// ---------- CSR build ----------
__global__ __launch_bounds__(256) void k_count(const int* dst, int E, int* counts) {
  int i = blockIdx.x*256 + threadIdx.x;
  if (i < E) atomicAdd(&counts[dst[i]], 1);
}

__global__ __launch_bounds__(1024) void k_scan(const int* cnt, int n, int* rowptr) {
  __shared__ int sums[1024];
  int t = threadIdx.x;
  int C = (n + 1023) >> 10;
  int lo = t*C, hi = min(lo + C, n);
  int s = 0;
  for (int i = lo; i < hi; ++i) s += cnt[i];
  sums[t] = s;
  __syncthreads();
  for (int offd = 1; offd < 1024; offd <<= 1) {
    int v = (t >= offd) ? sums[t-offd] : 0;
    __syncthreads();
    sums[t] += v;
    __syncthreads();
  }
  int base = (t == 0) ? 0 : sums[t-1];
  for (int i = lo; i < hi; ++i) { rowptr[i] = base; base += cnt[i]; }
  if (t == 1023) rowptr[n] = sums[1023];
}

__global__ __launch_bounds__(256) void k_scatter(const int* src, const int* dst, int E,
                                                 const int* rowptr, int* cursor,
                                                 int* srcp, int* dstp) {
  int i = blockIdx.x*256 + threadIdx.x;
  if (i >= E) return;
  int d = dst[i];
  int pos = rowptr[d] + atomicAdd(&cursor[d], 1);
  srcp[pos] = src[i];
  dstp[pos] = d;
}

// ---------- vnr-path GAT pieces (f32, tiny graphs) ----------
__global__ __launch_bounds__(256) void k_edge_exp(int E, const int* srcp, const int* dstp,
                                                  const float* el, const float* er, float* expe) {
  int i = blockIdx.x*256 + threadIdx.x;
  if (i >= E) return;
  float e = el[srcp[i]] + er[dstp[i]];
  e = (e > 0.f) ? e : 0.2f*e;
  expe[i] = __expf(e);
}

__global__ __launch_bounds__(256) void k_aggregate(int nNodes, const int* rowptr,
                                                   const int* srcp, const float* expe,
                                                   const float* z, const float* bias, float* out) {
  int w = (blockIdx.x*256 + threadIdx.x) >> 6;
  int lane = threadIdx.x & 63;
  if (w >= nNodes) return;
  int beg = rowptr[w], end = rowptr[w+1];
  float a0 = 0.f, a1 = 0.f, wsum = 0.f;
  for (int i = beg; i < end; ++i) {
    int sI = srcp[i];
    float wt = expe[i];
    float2 zz = *(const float2*)(z + (size_t)sI*H_ + lane*2);
    a0 += wt*zz.x; a1 += wt*zz.y; wsum += wt;
  }
  float inv = (end > beg) ? 1.f/wsum : 0.f;
  float2 o;
  o.x = a0*inv + bias[lane*2];
  o.y = a1*inv + bias[lane*2 + 1];
  *(float2*)(out + (size_t)w*H_ + lane*2) = o;
}

// ---------- static-path aggregate: fused edge-exp, split-bf16 output ----------
__global__ __launch_bounds__(256) void k_aggregate_split(int nNodes, const int* rowptr,
    const int* srcp, const float* el, const float* er,
    const float* z, const float* bias,
    unsigned short* outHi, unsigned short* outLo) {
  int w = (blockIdx.x*256 + threadIdx.x) >> 6;
  int lane = threadIdx.x & 63;
  if (w >= nNodes) return;
  int beg = rowptr[w], end = rowptr[w+1];
  float erw = er[w];
  float a0 = 0.f, a1 = 0.f, wsum = 0.f;
  for (int i = beg; i < end; ++i) {
    int sI = srcp[i];
    float e = el[sI] + erw;
    e = (e > 0.f) ? e : 0.2f*e;
    float wt = __expf(e);
    float2 zz = *(const float2*)(z + (size_t)sI*H_ + lane*2);
    a0 += wt*zz.x; a1 += wt*zz.y; wsum += wt;
  }
  float inv = (end > beg) ? 1.f/wsum : 0.f;
  float o0 = a0*inv + bias[lane*2];
  float o1 = a1*inv + bias[lane*2 + 1];
  unsigned short h0 = bf16_rne(o0), h1 = bf16_rne(o1);
  unsigned short l0 = bf16_rne(o0 - bf16_tof(h0)), l1 = bf16_rne(o1 - bf16_tof(h1));
  ushort2 hv; hv.x = h0; hv.y = h1;
  ushort2 lv; lv.x = l0; lv.y = l1;
  *(ushort2*)(outHi + (size_t)w*H_ + lane*2) = hv;
  *(ushort2*)(outLo + (size_t)w*H_ + lane*2) = lv;
}

// ---------- weight split (+optional transpose): out[j][k] (hi,lo bf16) ----------
__global__ __launch_bounds__(256) void k_wsplit(const float* in, int ld, int trans,
                                                unsigned short* hi, unsigned short* lo) {
  int idx = blockIdx.x*256 + threadIdx.x;
  if (idx >= H_*H_) return;
  int j = idx >> 7, k = idx & 127;
  float v = trans ? in[(size_t)k*ld + j] : in[(size_t)j*ld + k];
  unsigned short h = bf16_rne(v);
  unsigned short l = bf16_rne(v - bf16_tof(h));
  hi[idx] = h; lo[idx] = l;
}

// ---------- MFMA split-bf16 GEMM: C[M,128] = (Ahi+Alo)@(Whi+Wlo), WT[col][k] ----------
// 64 rows/block, 4 waves; wave owns 32 cols, all 4 row-tiles. el/er epilogue optional.
__global__ __launch_bounds__(256) void k_mfma_gemm(
    const unsigned short* __restrict__ Ahi, const unsigned short* __restrict__ Alo,
    const unsigned short* __restrict__ WThi, const unsigned short* __restrict__ WTlo,
    float* __restrict__ C,
    const float* __restrict__ al, const float* __restrict__ ar,
    float* __restrict__ el, float* __restrict__ er) {
  __shared__ unsigned short lAhi[64*136];
  __shared__ unsigned short lAlo[64*136];
  __shared__ float redl[4][64];
  __shared__ float redr[4][64];
  int t = threadIdx.x;
  int row0 = blockIdx.x * 64;
  int wid = t >> 6, lane = t & 63;
  int g = lane >> 4, c = lane & 15;

  // stage A tiles (stride 136 shorts = 272B: 16B-aligned rows, bank-balanced)
  #pragma unroll
  for (int i = 0; i < 4; ++i) {
    int m = t + 256*i;            // 0..1023
    int r = m >> 4;               // 0..63
    int kc = (m & 15) * 8;        // 0..120
    *(short8v*)(lAhi + r*136 + kc) = *(const short8v*)(Ahi + (size_t)(row0 + r)*H_ + kc);
    *(short8v*)(lAlo + r*136 + kc) = *(const short8v*)(Alo + (size_t)(row0 + r)*H_ + kc);
  }

  // B fragments in registers: same (lane,e)->k map as A frags (k = kb*32 + g*8 + e)
  short8v bhi[2][4], blo[2][4];
  #pragma unroll
  for (int ct = 0; ct < 2; ++ct) {
    int col = wid*32 + ct*16 + c;
    #pragma unroll
    for (int kb = 0; kb < 4; ++kb) {
      size_t o = (size_t)col*H_ + kb*32 + g*8;
      bhi[ct][kb] = *(const short8v*)(WThi + o);
      blo[ct][kb] = *(const short8v*)(WTlo + o);
    }
  }

  floatx4 acc[4][2];
  #pragma unroll
  for (int rt = 0; rt < 4; ++rt)
    #pragma unroll
    for (int ct = 0; ct < 2; ++ct)
      acc[rt][ct] = (floatx4){0.f, 0.f, 0.f, 0.f};

  __syncthreads();

  #pragma unroll
  for (int kb = 0; kb < 4; ++kb) {
    short8v ahi[4], alo[4];
    #pragma unroll
    for (int rt = 0; rt < 4; ++rt) {
      int r = rt*16 + c;
      ahi[rt] = *(const short8v*)(lAhi + r*136 + kb*32 + g*8);
      alo[rt] = *(const short8v*)(lAlo + r*136 + kb*32 + g*8);
    }
    #pragma unroll
    for (int rt = 0; rt < 4; ++rt)
      #pragma unroll
      for (int ct = 0; ct < 2; ++ct) {
        acc[rt][ct] = __builtin_amdgcn_mfma_f32_16x16x32_bf16(ahi[rt], bhi[ct][kb], acc[rt][ct], 0, 0, 0);
        acc[rt][ct] = __builtin_amdgcn_mfma_f32_16x16x32_bf16(alo[rt], bhi[ct][kb], acc[rt][ct], 0, 0, 0);
        acc[rt][ct] = __builtin_amdgcn_mfma_f32_16x16x32_bf16(ahi[rt], blo[ct][kb], acc[rt][ct], 0, 0, 0);
      }
  }

  // C store: verified C/D map col=lane&15, row=(lane>>4)*4+reg
  #pragma unroll
  for (int rt = 0; rt < 4; ++rt)
    #pragma unroll
    for (int i = 0; i < 4; ++i) {
      int row = row0 + rt*16 + g*4 + i;
      float* cr = C + (size_t)row*H_ + wid*32;
      cr[c]      = acc[rt][0][i];
      cr[16 + c] = acc[rt][1][i];
    }

  if (el) {
    float av0 = al[wid*32 + c], av1 = al[wid*32 + 16 + c];
    float rv0 = ar[wid*32 + c], rv1 = ar[wid*32 + 16 + c];
    #pragma unroll
    for (int rt = 0; rt < 4; ++rt)
      #pragma unroll
      for (int i = 0; i < 4; ++i) {
        float pl = acc[rt][0][i]*av0 + acc[rt][1][i]*av1;
        float pr = acc[rt][0][i]*rv0 + acc[rt][1][i]*rv1;
        pl += __shfl_xor(pl, 1, 64); pl += __shfl_xor(pl, 2, 64);
        pl += __shfl_xor(pl, 4, 64); pl += __shfl_xor(pl, 8, 64);
        pr += __shfl_xor(pr, 1, 64); pr += __shfl_xor(pr, 2, 64);
        pr += __shfl_xor(pr, 4, 64); pr += __shfl_xor(pr, 8, 64);
        if (c == 0) { redl[wid][rt*16 + g*4 + i] = pl; redr[wid][rt*16 + g*4 + i] = pr; }
      }
    __syncthreads();
    if (t < 64) {
      el[row0 + t] = redl[0][t] + redl[1][t] + redl[2][t] + redl[3][t];
      er[row0 + t] = redr[0][t] + redr[1][t] + redr[2][t] + redr[3][t];
    }
  }
}

// ---------- generic f32 GEMM (layer-1 K=8 + tiny vnr/GI GEMMs) ----------
__global__ __launch_bounds__(256) void k_gemm(const float* A, int M, int K, int N,
                                              const float* W, const float* bias, float* C,
                                              const float* al, const float* ar,
                                              float* el, float* er) {
  __shared__ float Ws_[64*128];
  __shared__ float As_[16*128];
  __shared__ float redl[16][17];
  __shared__ float redr[16][17];
  int t = threadIdx.x;
  int j0 = blockIdx.y * 128;
  int row0 = blockIdx.x * 16;
  for (int l = t; l < 16*K; l += 256) {
    int r = l / K, k = l - r*K;
    int row = row0 + r;
    As_[r*K + k] = (row < M) ? A[(size_t)row*K + k] : 0.f;
  }
  int jg = t & 15, r = t >> 4;
  float acc[8];
  #pragma unroll
  for (int q = 0; q < 8; ++q) acc[q] = 0.f;
  for (int kc = 0; kc < K; kc += 64) {
    int kl = min(64, K - kc);
    __syncthreads();
    for (int l = t; l < (kl << 7); l += 256) {
      int k = l >> 7, j = l & 127;
      int jj = j0 + j;
      Ws_[l] = (jj < N) ? W[(size_t)(kc + k)*N + jj] : 0.f;
    }
    __syncthreads();
    for (int k = 0; k < kl; ++k) {
      float a = As_[r*K + kc + k];
      const float* wr = &Ws_[(k << 7) + jg*8];
      #pragma unroll
      for (int q = 0; q < 8; ++q) acc[q] += a * wr[q];
    }
  }
  int row = row0 + r;
  if (row < M) {
    float* crow = C + (size_t)row*N + j0 + jg*8;
    #pragma unroll
    for (int q = 0; q < 8; ++q) {
      int j = j0 + jg*8 + q;
      if (j < N) crow[q] = acc[q] + (bias ? bias[j] : 0.f);
    }
  }
  if (el) {
    float pl = 0.f, pr = 0.f;
    #pragma unroll
    for (int q = 0; q < 8; ++q) {
      int j = jg*8 + q;
      pl += acc[q]*al[j];
      pr += acc[q]*ar[j];
    }
    redl[r][jg] = pl; redr[r][jg] = pr;
    __syncthreads();
    if (t < 16) {
      float sl = 0.f, sr = 0.f;
      for (int q = 0; q < 16; ++q) { sl += redl[t][q]; sr += redr[t][q]; }
      int row2 = row0 + t;
      if (row2 < M) { el[row2] = sl; er[row2] = sr; }
    }
  }
}

// ---------- small transpose for weight re-layout ----------
__global__ __launch_bounds__(256) void k_transpose(const float* in, int inStride,
                                                   int K, int J, float* out) {
  int idx = blockIdx.x*256 + threadIdx.x;
  if (idx >= K*J) return;
  int k = idx / J, j = idx - k*J;
  out[idx] = in[(size_t)j*inStride + k];
}

// ---------- GRU decoder: per-thread dot products ----------
__global__ __launch_bounds__(512) void k_decoder(const float* __restrict__ GI,
                                                 const float* __restrict__ W_hh,
                                                 const float* __restrict__ b_hh,
                                                 const float* __restrict__ W_attn,
                                                 const float* __restrict__ h0,
                                                 float* __restrict__ A2) {
  int b = blockIdx.x;
  __shared__ float h[128];
  __shared__ float gh[384];
  int t = threadIdx.x;
  if (t < 128) h[t] = h0[t];
  __syncthreads();
  for (int s = 0; s < 10; ++s) {
    if (t < 384) {
      const float4* wr = (const float4*)(W_hh + (size_t)t*128);
      const float4* hv = (const float4*)h;
      float a0 = 0.f, a1 = 0.f, a2 = 0.f, a3 = 0.f;
      #pragma unroll
      for (int k = 0; k < 32; k += 4) {
        float4 w0 = wr[k+0], x0 = hv[k+0];
        float4 w1 = wr[k+1], x1 = hv[k+1];
        float4 w2 = wr[k+2], x2 = hv[k+2];
        float4 w3 = wr[k+3], x3 = hv[k+3];
        a0 += w0.x*x0.x + w0.y*x0.y + w0.z*x0.z + w0.w*x0.w;
        a1 += w1.x*x1.x + w1.y*x1.y + w1.z*x1.z + w1.w*x1.w;
        a2 += w2.x*x2.x + w2.y*x2.y + w2.z*x2.z + w2.w*x2.w;
        a3 += w3.x*x3.x + w3.y*x3.y + w3.z*x3.z + w3.w*x3.w;
      }
      gh[t] = (a0 + a1) + (a2 + a3) + b_hh[t];
    }
    __syncthreads();
    if (t < 128) {
      const float* gi = GI + (size_t)(b*NV_ + s)*384;
      float rr = fast_sigmoid(gi[t]       + gh[t]);
      float zz = fast_sigmoid(gi[128 + t] + gh[128 + t]);
      float nn = fast_tanh   (gi[256 + t] + rr*gh[256 + t]);
      h[t] = (1.f - zz)*nn + zz*h[t];
    }
    __syncthreads();
    {
      int j = t >> 2, part = t & 3;
      const float4* wr = (const float4*)(W_attn + (size_t)j*256 + 128 + part*32);
      const float4* hv = (const float4*)(h + part*32);
      float a0 = 0.f, a1 = 0.f;
      #pragma unroll
      for (int k = 0; k < 8; k += 2) {
        float4 w0 = wr[k+0], x0 = hv[k+0];
        float4 w1 = wr[k+1], x1 = hv[k+1];
        a0 += w0.x*x0.x + w0.y*x0.y + w0.z*x0.z + w0.w*x0.w;
        a1 += w1.x*x1.x + w1.y*x1.y + w1.z*x1.z + w1.w*x1.w;
      }
      float p = a0 + a1;
      p += __shfl_xor(p, 1, 64);
      p += __shfl_xor(p, 2, 64);
      if (part == 0) A2[((size_t)s*B_ + b)*128 + j] = p;
    }
    __syncthreads();
  }
}

// ---------- attention score + mask ----------
__global__ __launch_bounds__(256) void k_attn(const float* A1, const float* A2,
                                              const float* v_attn, const int* vnr_VNF,
                                              const int* net_VNF, float* pi) {
  int g = (blockIdx.x*256 + threadIdx.x) >> 6;
  int lane = threadIdx.x & 63;
  if (g >= NS_) return;
  int b = g / NN_, n = g - b*NN_;
  float2 a1 = *(const float2*)(A1 + (size_t)g*H_ + lane*2);
  float2 vv = *(const float2*)(v_attn + lane*2);
  for (int s = 0; s < NV_; ++s) {
    float2 a2 = *(const float2*)(A2 + ((size_t)s*B_ + b)*H_ + lane*2);
    float p = vv.x*fast_tanh(a1.x + a2.x) + vv.y*fast_tanh(a1.y + a2.y);
    #pragma unroll
    for (int o = 32; o; o >>= 1) p += __shfl_xor(p, o, 64);
    if (lane == 0) {
      int vnf = vnr_VNF[b*NV_ + s];
      int m   = net_VNF[(size_t)g*T_ + vnf];
      pi[(size_t)b*(NV_*NN_) + s*NN_ + n] = p + __logf((float)m);
    }
  }
}

// ---------- value head ----------
__global__ __launch_bounds__(128) void k_y1(const float* Hv, const float* nmask, float* y1) {
  int b = blockIdx.x, h = threadIdx.x;
  float s = 0.f, d = 0.f;
  for (int i = 0; i < NV_; ++i) {
    float m = nmask[b*NV_ + i];
    s += Hv[(size_t)(b*NV_ + i)*H_ + h]*m;
    d += m;
  }
  y1[b*H_ + h] = s/d;
}

__global__ __launch_bounds__(128) void k_y2s(const unsigned short* hi, const unsigned short* lo,
                                             float* y2) {
  int b = blockIdx.x, slice = blockIdx.y, h = threadIdx.x;
  int n0 = slice*125, n1 = n0 + 125;
  float s = 0.f;
  for (int n = n0; n < n1; ++n) {
    size_t idx = ((size_t)b*NN_ + n)*H_ + h;
    s += bf16_tof(hi[idx]) + bf16_tof(lo[idx]);
  }
  atomicAdd(&y2[b*H_ + h], s);
}

__global__ __launch_bounds__(64) void k_value(const float* y1, const float* y2,
                                              const float* W_out, const float* b_out,
                                              float* val) {
  int b = blockIdx.x, o = threadIdx.x;
  const float* w = W_out + (size_t)o*256;
  float s = b_out[o];
  for (int h = 0; h < H_; ++h)
    s += y1[b*H_ + h]*w[h] + (y2[b*H_ + h]*(1.f/1000.f))*w[128 + h];
  val[b*O_ + o] = s;
}

extern "C" void kernel_launch(void* const* d_in, const int* in_sizes, int n_in,
                              void* d_out, int out_size, void* d_ws, size_t ws_size,
                              hipStream_t stream) {
  (void)in_sizes; (void)n_in; (void)out_size; (void)ws_size;
  const float* static_feat = (const float*)d_in[0];
  const float* vnr_feat    = (const float*)d_in[1];
  const float* nmask       = (const float*)d_in[2];
  const float* Ws1 = (const float*)d_in[3];  const float* als1 = (const float*)d_in[4];
  const float* ars1 = (const float*)d_in[5]; const float* bs1 = (const float*)d_in[6];
  const float* Ws2 = (const float*)d_in[7];  const float* als2 = (const float*)d_in[8];
  const float* ars2 = (const float*)d_in[9]; const float* bs2 = (const float*)d_in[10];
  const float* Ws3 = (const float*)d_in[11]; const float* als3 = (const float*)d_in[12];
  const float* ars3 = (const float*)d_in[13]; const float* bs3 = (const float*)d_in[14];
  const float* Wv1 = (const float*)d_in[15]; const float* alv1 = (const float*)d_in[16];
  const float* arv1 = (const float*)d_in[17]; const float* bv1 = (const float*)d_in[18];
  const float* Wv2 = (const float*)d_in[19]; const float* alv2 = (const float*)d_in[20];
  const float* arv2 = (const float*)d_in[21]; const float* bv2 = (const float*)d_in[22];
  const float* Wv3 = (const float*)d_in[23]; const float* alv3 = (const float*)d_in[24];
  const float* arv3 = (const float*)d_in[25]; const float* bv3 = (const float*)d_in[26];
  const float* W_attn = (const float*)d_in[27];
  const float* v_attn = (const float*)d_in[28];
  const float* W_ih = (const float*)d_in[29];
  const float* W_hh = (const float*)d_in[30];
  const float* b_ih = (const float*)d_in[31];
  const float* b_hh = (const float*)d_in[32];
  const float* h0   = (const float*)d_in[33];
  const float* W_out = (const float*)d_in[34];
  const float* b_out = (const float*)d_in[35];
  const int* src_s = (const int*)d_in[36];
  const int* dst_s = (const int*)d_in[37];
  const int* src_v = (const int*)d_in[38];
  const int* dst_v = (const int*)d_in[39];
  const int* vnr_VNF = (const int*)d_in[40];
  const int* net_VNF = (const int*)d_in[41];

  char* ws = (char*)d_ws;
  size_t off = 0;
  auto alloc = [&](size_t bytes) -> char* {
    off = (off + 255) & ~(size_t)255;
    char* p = ws + off;
    off += bytes;
    return p;
  };
  float* Z    = (float*)alloc((size_t)NS_*H_*4);          // z buffer; later A1
  unsigned short* HsHi = (unsigned short*)alloc((size_t)NS_*H_*2);
  unsigned short* HsLo = (unsigned short*)alloc((size_t)NS_*H_*2);
  float* Zv   = (float*)alloc((size_t)NVT_*H_*4);
  float* Hv   = (float*)alloc((size_t)NVT_*H_*4);
  float* el_s = (float*)alloc((size_t)NS_*4);
  float* er_s = (float*)alloc((size_t)NS_*4);
  float* el_v = (float*)alloc((size_t)NVT_*4);
  float* er_v = (float*)alloc((size_t)NVT_*4);
  size_t zcount = (size_t)NS_ + NS_ + NVT_ + NVT_ + B_*H_;
  char* zb = alloc(zcount*4);
  int*   counts_s = (int*)zb;
  int*   cursor_s = counts_s + NS_;
  int*   counts_v = cursor_s + NS_;
  int*   cursor_v = counts_v + NVT_;
  float* y2buf    = (float*)(cursor_v + NVT_);
  int* rowptr_s = (int*)alloc((size_t)(NS_+1)*4);
  int* rowptr_v = (int*)alloc((size_t)(NVT_+1)*4);
  int* srcp_s   = (int*)alloc((size_t)EN_*4);
  int* dstp_s   = (int*)alloc((size_t)EN_*4);
  int* srcp_v   = (int*)alloc((size_t)EV_*4);
  int* dstp_v   = (int*)alloc((size_t)EV_*4);
  float* expe_v = (float*)alloc((size_t)EV_*4);
  unsigned short* WS2hi = (unsigned short*)alloc((size_t)H_*H_*2);
  unsigned short* WS2lo = (unsigned short*)alloc((size_t)H_*H_*2);
  unsigned short* WS3hi = (unsigned short*)alloc((size_t)H_*H_*2);
  unsigned short* WS3lo = (unsigned short*)alloc((size_t)H_*H_*2);
  unsigned short* WAhi  = (unsigned short*)alloc((size_t)H_*H_*2);
  unsigned short* WAlo  = (unsigned short*)alloc((size_t)H_*H_*2);
  float* WTih   = (float*)alloc((size_t)H_*384*4);
  float* GI     = (float*)alloc((size_t)NVT_*384*4);
  float* A2     = (float*)alloc((size_t)NV_*B_*H_*4);
  float* y1buf  = (float*)alloc((size_t)B_*H_*4);

  float* pi  = (float*)d_out;
  float* val = pi + (size_t)B_*NV_*NN_;

  hipMemsetAsync(zb, 0, zcount*4, stream);

  // weight re-layouts
  k_transpose<<<(H_*384 + 255)/256, 256, 0, stream>>>(W_ih, 128, H_, 384, WTih);
  k_wsplit<<<64, 256, 0, stream>>>(Ws2, H_, 1, WS2hi, WS2lo);      // WT[j][k]=Ws2[k][j]
  k_wsplit<<<64, 256, 0, stream>>>(Ws3, H_, 1, WS3hi, WS3lo);
  k_wsplit<<<64, 256, 0, stream>>>(W_attn, 2*H_, 0, WAhi, WAlo);   // W_attn[j][k], k<128

  // CSR build (both graphs)
  k_count<<<EN_/256, 256, 0, stream>>>(dst_s, EN_, counts_s);
  k_count<<<EV_/256, 256, 0, stream>>>(dst_v, EV_, counts_v);
  k_scan<<<1, 1024, 0, stream>>>(counts_s, NS_, rowptr_s);
  k_scan<<<1, 1024, 0, stream>>>(counts_v, NVT_, rowptr_v);
  k_scatter<<<EN_/256, 256, 0, stream>>>(src_s, dst_s, EN_, rowptr_s, cursor_s, srcp_s, dstp_s);
  k_scatter<<<EV_/256, 256, 0, stream>>>(src_v, dst_v, EV_, rowptr_v, cursor_v, srcp_v, dstp_v);

  dim3 gemmV(NVT_/16, 1);
  int aggS = (NS_ + 3)/4, aggV = (NVT_ + 3)/4;

  // ---- static GAT stack ----
  // layer 1: K=8 f32 GEMM
  k_gemm<<<dim3(NS_/16, 1), 256, 0, stream>>>(static_feat, NS_, FS_, H_, Ws1, nullptr, Z, als1, ars1, el_s, er_s);
  k_aggregate_split<<<aggS, 256, 0, stream>>>(NS_, rowptr_s, srcp_s, el_s, er_s, Z, bs1, HsHi, HsLo);
  // layers 2,3: MFMA split-bf16
  k_mfma_gemm<<<NS_/64, 256, 0, stream>>>(HsHi, HsLo, WS2hi, WS2lo, Z, als2, ars2, el_s, er_s);
  k_aggregate_split<<<aggS, 256, 0, stream>>>(NS_, rowptr_s, srcp_s, el_s, er_s, Z, bs2, HsHi, HsLo);
  k_mfma_gemm<<<NS_/64, 256, 0, stream>>>(HsHi, HsLo, WS3hi, WS3lo, Z, als3, ars3, el_s, er_s);
  k_aggregate_split<<<aggS, 256, 0, stream>>>(NS_, rowptr_s, srcp_s, el_s, er_s, Z, bs3, HsHi, HsLo);

  // ---- vnr GAT stack (tiny, f32 path) ----
  k_gemm<<<gemmV, 256, 0, stream>>>(vnr_feat, NVT_, FV_, H_, Wv1, nullptr, Zv, alv1, arv1, el_v, er_v);
  k_edge_exp<<<EV_/256, 256, 0, stream>>>(EV_, srcp_v, dstp_v, el_v, er_v, expe_v);
  k_aggregate<<<aggV, 256, 0, stream>>>(NVT_, rowptr_v, srcp_v, expe_v, Zv, bv1, Hv);
  k_gemm<<<gemmV, 256, 0, stream>>>(Hv, NVT_, H_, H_, Wv2, nullptr, Zv, alv2, arv2, el_v, er_v);
  k_edge_exp<<<EV_/256, 256, 0, stream>>>(EV_, srcp_v, dstp_v, el_v, er_v, expe_v);
  k_aggregate<<<aggV, 256, 0, stream>>>(NVT_, rowptr_v, srcp_v, expe_v, Zv, bv2, Hv);
  k_gemm<<<gemmV, 256, 0, stream>>>(Hv, NVT_, H_, H_, Wv3, nullptr, Zv, alv3, arv3, el_v, er_v);
  k_edge_exp<<<EV_/256, 256, 0, stream>>>(EV_, srcp_v, dstp_v, el_v, er_v, expe_v);
  k_aggregate<<<aggV, 256, 0, stream>>>(NVT_, rowptr_v, srcp_v, expe_v, Zv, bv3, Hv);

  // ---- decoder precomputation ----
  k_gemm<<<dim3(NVT_/16, 3), 256, 0, stream>>>(Hv, NVT_, H_, 384, WTih, b_ih, GI,
                                               nullptr, nullptr, nullptr, nullptr);
  // A1 = Hs @ W_attn[:, :128]^T via MFMA (reuses Z)
  k_mfma_gemm<<<NS_/64, 256, 0, stream>>>(HsHi, HsLo, WAhi, WAlo, Z,
                                          nullptr, nullptr, nullptr, nullptr);
  k_decoder<<<B_, 512, 0, stream>>>(GI, W_hh, b_hh, W_attn, h0, A2);
  k_attn<<<(NS_ + 3)/4, 256, 0, stream>>>(Z, A2, v_attn, vnr_VNF, net_VNF, pi);

  // ---- value head ----
  k_y1<<<B_, 128, 0, stream>>>(Hv, nmask, y1buf);
  k_y2s<<<dim3(B_, 8), 128, 0, stream>>>(HsHi, HsLo, y2buf);
  k_value<<<B_, 64, 0, stream>>>(y1buf, y2buf, W_out, b_out, val);
}

// Round 4
// 618.434 us; speedup vs baseline: 2.0500x; 1.1763x over previous
//
#include <hip/hip_runtime.h>
#include <hip/hip_bf16.h>
#include <math.h>

#define B_   64
#define NN_  1000
#define NV_  10
#define H_   128
#define FS_  8
#define FV_  6
#define T_   8
#define O_   64
#define EN_  512000
#define EV_  2560
#define NS_  (B_*NN_)   /* 64000 */
#define NVT_ (B_*NV_)   /* 640 */

typedef __attribute__((ext_vector_type(8))) short short8v;   // 8 bf16
typedef __attribute__((ext_vector_type(4))) float floatx4;

__device__ __forceinline__ float fast_tanh(float x) {
  float ax = fabsf(x);
  float e  = __expf(2.f*ax);
  float t  = 1.f - 2.f/(e + 1.f);
  return x >= 0.f ? t : -t;
}
__device__ __forceinline__ float fast_sigmoid(float x) {
  return 1.f/(1.f + __expf(-x));
}
__device__ __forceinline__ unsigned short bf16_rne(float x) {
  unsigned u = __float_as_uint(x);
  return (unsigned short)((u + 0x7FFFu + ((u >> 16) & 1u)) >> 16);
}
__device__ __forceinline__ float bf16_tof(unsigned short b) {
  return __uint_as_float(((unsigned)b) << 16);
}

// ---------- CSR build ----------
__global__ __launch_bounds__(256) void k_count(const int* dst, int E, int* counts) {
  int i = blockIdx.x*256 + threadIdx.x;
  if (i < E) atomicAdd(&counts[dst[i]], 1);
}

// small single-block scan (vnr graph only, n<=1024)
__global__ __launch_bounds__(1024) void k_scan(const int* cnt, int n, int* rowptr) {
  __shared__ int sums[1024];
  int t = threadIdx.x;
  int v = (t < n) ? cnt[t] : 0;
  sums[t] = v;
  __syncthreads();
  for (int offd = 1; offd < 1024; offd <<= 1) {
    int u = (t >= offd) ? sums[t-offd] : 0;
    __syncthreads();
    sums[t] += u;
    __syncthreads();
  }
  if (t < n) rowptr[t] = sums[t] - v;     // exclusive
  if (t == n-1) rowptr[n] = sums[t];
}

// hierarchical scan for the big graph: local -> bsum -> add
__global__ __launch_bounds__(256) void k_scan_local(const int* cnt, int n, int* out, int* bsum) {
  __shared__ int s[256];
  int t = threadIdx.x; int i = blockIdx.x*256 + t;
  int v = (i < n) ? cnt[i] : 0;
  s[t] = v; __syncthreads();
  #pragma unroll
  for (int o = 1; o < 256; o <<= 1) {
    int u = (t >= o) ? s[t-o] : 0; __syncthreads();
    s[t] += u; __syncthreads();
  }
  if (i < n) out[i] = s[t] - v;          // block-local exclusive
  if (t == 255) bsum[blockIdx.x] = s[255];
}

__global__ __launch_bounds__(256) void k_scan_bsum(int* bsum, int nb) {
  __shared__ int s[256];
  int t = threadIdx.x;
  int v = (t < nb) ? bsum[t] : 0;
  s[t] = v; __syncthreads();
  #pragma unroll
  for (int o = 1; o < 256; o <<= 1) {
    int u = (t >= o) ? s[t-o] : 0; __syncthreads();
    s[t] += u; __syncthreads();
  }
  if (t < nb) bsum[t] = s[t] - v;        // exclusive block offsets
}

__global__ __launch_bounds__(256) void k_scan_add(int* out, const int* bsum, int n, int E) {
  int i = blockIdx.x*256 + threadIdx.x;
  if (i < n) out[i] += bsum[blockIdx.x];
  if (i == 0) out[n] = E;
}

__global__ __launch_bounds__(256) void k_scatter(const int* src, const int* dst, int E,
                                                 const int* rowptr, int* cursor,
                                                 int* srcp, int* dstp) {
  int i = blockIdx.x*256 + threadIdx.x;
  if (i >= E) return;
  int d = dst[i];
  int pos = rowptr[d] + atomicAdd(&cursor[d], 1);
  srcp[pos] = src[i];
  dstp[pos] = d;
}

// ---------- vnr-path GAT pieces (f32, tiny graphs) ----------
__global__ __launch_bounds__(256) void k_edge_exp(int E, const int* srcp, const int* dstp,
                                                  const float* el, const float* er, float* expe) {
  int i = blockIdx.x*256 + threadIdx.x;
  if (i >= E) return;
  float e = el[srcp[i]] + er[dstp[i]];
  e = (e > 0.f) ? e : 0.2f*e;
  expe[i] = __expf(e);
}

__global__ __launch_bounds__(256) void k_aggregate(int nNodes, const int* rowptr,
                                                   const int* srcp, const float* expe,
                                                   const float* z, const float* bias, float* out) {
  int w = (blockIdx.x*256 + threadIdx.x) >> 6;
  int lane = threadIdx.x & 63;
  if (w >= nNodes) return;
  int beg = rowptr[w], end = rowptr[w+1];
  float a0 = 0.f, a1 = 0.f, wsum = 0.f;
  for (int i = beg; i < end; ++i) {
    int sI = srcp[i];
    float wt = expe[i];
    float2 zz = *(const float2*)(z + (size_t)sI*H_ + lane*2);
    a0 += wt*zz.x; a1 += wt*zz.y; wsum += wt;
  }
  float inv = (end > beg) ? 1.f/wsum : 0.f;
  float2 o;
  o.x = a0*inv + bias[lane*2];
  o.y = a1*inv + bias[lane*2 + 1];
  *(float2*)(out + (size_t)w*H_ + lane*2) = o;
}

// ---------- static-path aggregate: fused edge-exp, split-bf16 output ----------
__global__ __launch_bounds__(256) void k_aggregate_split(int nNodes, const int* rowptr,
    const int* srcp, const float* el, const float* er,
    const float* z, const float* bias,
    unsigned short* outHi, unsigned short* outLo) {
  int w = (blockIdx.x*256 + threadIdx.x) >> 6;
  int lane = threadIdx.x & 63;
  if (w >= nNodes) return;
  int beg = rowptr[w], end = rowptr[w+1];
  float erw = er[w];
  float a0 = 0.f, a1 = 0.f, wsum = 0.f;
  for (int i = beg; i < end; ++i) {
    int sI = srcp[i];
    float e = el[sI] + erw;
    e = (e > 0.f) ? e : 0.2f*e;
    float wt = __expf(e);
    float2 zz = *(const float2*)(z + (size_t)sI*H_ + lane*2);
    a0 += wt*zz.x; a1 += wt*zz.y; wsum += wt;
  }
  float inv = (end > beg) ? 1.f/wsum : 0.f;
  float o0 = a0*inv + bias[lane*2];
  float o1 = a1*inv + bias[lane*2 + 1];
  unsigned short h0 = bf16_rne(o0), h1 = bf16_rne(o1);
  unsigned short l0 = bf16_rne(o0 - bf16_tof(h0)), l1 = bf16_rne(o1 - bf16_tof(h1));
  ushort2 hv; hv.x = h0; hv.y = h1;
  ushort2 lv; lv.x = l0; lv.y = l1;
  *(ushort2*)(outHi + (size_t)w*H_ + lane*2) = hv;
  *(ushort2*)(outLo + (size_t)w*H_ + lane*2) = lv;
}

// ---------- weight split (+optional transpose): out[j][k] (hi,lo bf16) ----------
__global__ __launch_bounds__(256) void k_wsplit(const float* in, int ld, int trans,
                                                unsigned short* hi, unsigned short* lo) {
  int idx = blockIdx.x*256 + threadIdx.x;
  if (idx >= H_*H_) return;
  int j = idx >> 7, k = idx & 127;
  float v = trans ? in[(size_t)k*ld + j] : in[(size_t)j*ld + k];
  unsigned short h = bf16_rne(v);
  unsigned short l = bf16_rne(v - bf16_tof(h));
  hi[idx] = h; lo[idx] = l;
}

// ---------- MFMA split-bf16 GEMM: C[M,128] = (Ahi+Alo)@(Whi+Wlo), WT[col][k] ----------
__global__ __launch_bounds__(256) void k_mfma_gemm(
    const unsigned short* __restrict__ Ahi, const unsigned short* __restrict__ Alo,
    const unsigned short* __restrict__ WThi, const unsigned short* __restrict__ WTlo,
    float* __restrict__ C,
    const float* __restrict__ al, const float* __restrict__ ar,
    float* __restrict__ el, float* __restrict__ er) {
  __shared__ unsigned short lAhi[64*136];
  __shared__ unsigned short lAlo[64*136];
  __shared__ float redl[4][64];
  __shared__ float redr[4][64];
  int t = threadIdx.x;
  int row0 = blockIdx.x * 64;
  int wid = t >> 6, lane = t & 63;
  int g = lane >> 4, c = lane & 15;

  #pragma unroll
  for (int i = 0; i < 4; ++i) {
    int m = t + 256*i;
    int r = m >> 4;
    int kc = (m & 15) * 8;
    *(short8v*)(lAhi + r*136 + kc) = *(const short8v*)(Ahi + (size_t)(row0 + r)*H_ + kc);
    *(short8v*)(lAlo + r*136 + kc) = *(const short8v*)(Alo + (size_t)(row0 + r)*H_ + kc);
  }

  short8v bhi[2][4], blo[2][4];
  #pragma unroll
  for (int ct = 0; ct < 2; ++ct) {
    int col = wid*32 + ct*16 + c;
    #pragma unroll
    for (int kb = 0; kb < 4; ++kb) {
      size_t o = (size_t)col*H_ + kb*32 + g*8;
      bhi[ct][kb] = *(const short8v*)(WThi + o);
      blo[ct][kb] = *(const short8v*)(WTlo + o);
    }
  }

  floatx4 acc[4][2];
  #pragma unroll
  for (int rt = 0; rt < 4; ++rt)
    #pragma unroll
    for (int ct = 0; ct < 2; ++ct)
      acc[rt][ct] = (floatx4){0.f, 0.f, 0.f, 0.f};

  __syncthreads();

  #pragma unroll
  for (int kb = 0; kb < 4; ++kb) {
    short8v ahi[4], alo[4];
    #pragma unroll
    for (int rt = 0; rt < 4; ++rt) {
      int r = rt*16 + c;
      ahi[rt] = *(const short8v*)(lAhi + r*136 + kb*32 + g*8);
      alo[rt] = *(const short8v*)(lAlo + r*136 + kb*32 + g*8);
    }
    #pragma unroll
    for (int rt = 0; rt < 4; ++rt)
      #pragma unroll
      for (int ct = 0; ct < 2; ++ct) {
        acc[rt][ct] = __builtin_amdgcn_mfma_f32_16x16x32_bf16(ahi[rt], bhi[ct][kb], acc[rt][ct], 0, 0, 0);
        acc[rt][ct] = __builtin_amdgcn_mfma_f32_16x16x32_bf16(alo[rt], bhi[ct][kb], acc[rt][ct], 0, 0, 0);
        acc[rt][ct] = __builtin_amdgcn_mfma_f32_16x16x32_bf16(ahi[rt], blo[ct][kb], acc[rt][ct], 0, 0, 0);
      }
  }

  #pragma unroll
  for (int rt = 0; rt < 4; ++rt)
    #pragma unroll
    for (int i = 0; i < 4; ++i) {
      int row = row0 + rt*16 + g*4 + i;
      float* cr = C + (size_t)row*H_ + wid*32;
      cr[c]      = acc[rt][0][i];
      cr[16 + c] = acc[rt][1][i];
    }

  if (el) {
    float av0 = al[wid*32 + c], av1 = al[wid*32 + 16 + c];
    float rv0 = ar[wid*32 + c], rv1 = ar[wid*32 + 16 + c];
    #pragma unroll
    for (int rt = 0; rt < 4; ++rt)
      #pragma unroll
      for (int i = 0; i < 4; ++i) {
        float pl = acc[rt][0][i]*av0 + acc[rt][1][i]*av1;
        float pr = acc[rt][0][i]*rv0 + acc[rt][1][i]*rv1;
        pl += __shfl_xor(pl, 1, 64); pl += __shfl_xor(pl, 2, 64);
        pl += __shfl_xor(pl, 4, 64); pl += __shfl_xor(pl, 8, 64);
        pr += __shfl_xor(pr, 1, 64); pr += __shfl_xor(pr, 2, 64);
        pr += __shfl_xor(pr, 4, 64); pr += __shfl_xor(pr, 8, 64);
        if (c == 0) { redl[wid][rt*16 + g*4 + i] = pl; redr[wid][rt*16 + g*4 + i] = pr; }
      }
    __syncthreads();
    if (t < 64) {
      el[row0 + t] = redl[0][t] + redl[1][t] + redl[2][t] + redl[3][t];
      er[row0 + t] = redr[0][t] + redr[1][t] + redr[2][t] + redr[3][t];
    }
  }
}

// ---------- generic f32 GEMM (layer-1 K=8 + tiny vnr/GI GEMMs) ----------
__global__ __launch_bounds__(256) void k_gemm(const float* A, int M, int K, int N,
                                              const float* W, const float* bias, float* C,
                                              const float* al, const float* ar,
                                              float* el, float* er) {
  __shared__ float Ws_[64*128];
  __shared__ float As_[16*128];
  __shared__ float redl[16][17];
  __shared__ float redr[16][17];
  int t = threadIdx.x;
  int j0 = blockIdx.y * 128;
  int row0 = blockIdx.x * 16;
  for (int l = t; l < 16*K; l += 256) {
    int r = l / K, k = l - r*K;
    int row = row0 + r;
    As_[r*K + k] = (row < M) ? A[(size_t)row*K + k] : 0.f;
  }
  int jg = t & 15, r = t >> 4;
  float acc[8];
  #pragma unroll
  for (int q = 0; q < 8; ++q) acc[q] = 0.f;
  for (int kc = 0; kc < K; kc += 64) {
    int kl = min(64, K - kc);
    __syncthreads();
    for (int l = t; l < (kl << 7); l += 256) {
      int k = l >> 7, j = l & 127;
      int jj = j0 + j;
      Ws_[l] = (jj < N) ? W[(size_t)(kc + k)*N + jj] : 0.f;
    }
    __syncthreads();
    for (int k = 0; k < kl; ++k) {
      float a = As_[r*K + kc + k];
      const float* wr = &Ws_[(k << 7) + jg*8];
      #pragma unroll
      for (int q = 0; q < 8; ++q) acc[q] += a * wr[q];
    }
  }
  int row = row0 + r;
  if (row < M) {
    float* crow = C + (size_t)row*N + j0 + jg*8;
    #pragma unroll
    for (int q = 0; q < 8; ++q) {
      int j = j0 + jg*8 + q;
      if (j < N) crow[q] = acc[q] + (bias ? bias[j] : 0.f);
    }
  }
  if (el) {
    float pl = 0.f, pr = 0.f;
    #pragma unroll
    for (int q = 0; q < 8; ++q) {
      int j = jg*8 + q;
      pl += acc[q]*al[j];
      pr += acc[q]*ar[j];
    }
    redl[r][jg] = pl; redr[r][jg] = pr;
    __syncthreads();
    if (t < 16) {
      float sl = 0.f, sr = 0.f;
      for (int q = 0; q < 16; ++q) { sl += redl[t][q]; sr += redr[t][q]; }
      int row2 = row0 + t;
      if (row2 < M) { el[row2] = sl; er[row2] = sr; }
    }
  }
}

// ---------- small transpose for weight re-layout ----------
__global__ __launch_bounds__(256) void k_transpose(const float* in, int inStride,
                                                   int K, int J, float* out) {
  int idx = blockIdx.x*256 + threadIdx.x;
  if (idx >= K*J) return;
  int k = idx / J, j = idx - k*J;
  out[idx] = in[(size_t)j*inStride + k];
}

// ---------- GRU decoder: per-thread dot products ----------
__global__ __launch_bounds__(512) void k_decoder(const float* __restrict__ GI,
                                                 const float* __restrict__ W_hh,
                                                 const float* __restrict__ b_hh,
                                                 const float* __restrict__ W_attn,
                                                 const float* __restrict__ h0,
                                                 float* __restrict__ A2) {
  int b = blockIdx.x;
  __shared__ float h[128];
  __shared__ float gh[384];
  int t = threadIdx.x;
  if (t < 128) h[t] = h0[t];
  __syncthreads();
  for (int s = 0; s < 10; ++s) {
    if (t < 384) {
      const float4* wr = (const float4*)(W_hh + (size_t)t*128);
      const float4* hv = (const float4*)h;
      float a0 = 0.f, a1 = 0.f, a2 = 0.f, a3 = 0.f;
      #pragma unroll
      for (int k = 0; k < 32; k += 4) {
        float4 w0 = wr[k+0], x0 = hv[k+0];
        float4 w1 = wr[k+1], x1 = hv[k+1];
        float4 w2 = wr[k+2], x2 = hv[k+2];
        float4 w3 = wr[k+3], x3 = hv[k+3];
        a0 += w0.x*x0.x + w0.y*x0.y + w0.z*x0.z + w0.w*x0.w;
        a1 += w1.x*x1.x + w1.y*x1.y + w1.z*x1.z + w1.w*x1.w;
        a2 += w2.x*x2.x + w2.y*x2.y + w2.z*x2.z + w2.w*x2.w;
        a3 += w3.x*x3.x + w3.y*x3.y + w3.z*x3.z + w3.w*x3.w;
      }
      gh[t] = (a0 + a1) + (a2 + a3) + b_hh[t];
    }
    __syncthreads();
    if (t < 128) {
      const float* gi = GI + (size_t)(b*NV_ + s)*384;
      float rr = fast_sigmoid(gi[t]       + gh[t]);
      float zz = fast_sigmoid(gi[128 + t] + gh[128 + t]);
      float nn = fast_tanh   (gi[256 + t] + rr*gh[256 + t]);
      h[t] = (1.f - zz)*nn + zz*h[t];
    }
    __syncthreads();
    {
      int j = t >> 2, part = t & 3;
      const float4* wr = (const float4*)(W_attn + (size_t)j*256 + 128 + part*32);
      const float4* hv = (const float4*)(h + part*32);
      float a0 = 0.f, a1 = 0.f;
      #pragma unroll
      for (int k = 0; k < 8; k += 2) {
        float4 w0 = wr[k+0], x0 = hv[k+0];
        float4 w1 = wr[k+1], x1 = hv[k+1];
        a0 += w0.x*x0.x + w0.y*x0.y + w0.z*x0.z + w0.w*x0.w;
        a1 += w1.x*x1.x + w1.y*x1.y + w1.z*x1.z + w1.w*x1.w;
      }
      float p = a0 + a1;
      p += __shfl_xor(p, 1, 64);
      p += __shfl_xor(p, 2, 64);
      if (part == 0) A2[((size_t)s*B_ + b)*128 + j] = p;
    }
    __syncthreads();
  }
}

// ---------- attention score + mask v2: thread owns (b,n) quarter-row ----------
// A1 part in 32 regs (loaded once), A2[10][128] in LDS (broadcast reads),
// acc[10] in regs; only 2 shuffles per step at the very end.
__global__ __launch_bounds__(256) void k_attn2(const float* __restrict__ A1,
                                               const float* __restrict__ A2,
                                               const float* __restrict__ v_attn,
                                               const int* __restrict__ vnr_VNF,
                                               const int* __restrict__ net_VNF,
                                               float* __restrict__ pi) {
  __shared__ float a2s[10][128];
  __shared__ float vs[128];
  int b = blockIdx.y;
  int t = threadIdx.x;
  for (int i = t; i < 1280; i += 256) {
    int s = i >> 7, k = i & 127;
    a2s[s][k] = A2[((size_t)s*B_ + b)*H_ + k];
  }
  if (t < 128) vs[t] = v_attn[t];
  __syncthreads();
  int nl = t >> 2, p = t & 3;
  int n = blockIdx.x*64 + nl;
  if (n >= NN_) return;
  size_t g = (size_t)b*NN_ + n;
  const float4* arow = (const float4*)(A1 + g*H_ + p*32);
  float4 a[8];
  #pragma unroll
  for (int kk = 0; kk < 8; ++kk) a[kk] = arow[kk];
  float acc[10];
  #pragma unroll
  for (int s = 0; s < 10; ++s) {
    const float* a2r = &a2s[s][p*32];
    const float* vr  = &vs[p*32];
    float sum = 0.f;
    #pragma unroll
    for (int kk = 0; kk < 8; ++kk) {
      float4 c  = *(const float4*)(a2r + kk*4);
      float4 vv = *(const float4*)(vr + kk*4);
      sum += vv.x*fast_tanh(a[kk].x + c.x);
      sum += vv.y*fast_tanh(a[kk].y + c.y);
      sum += vv.z*fast_tanh(a[kk].z + c.z);
      sum += vv.w*fast_tanh(a[kk].w + c.w);
    }
    acc[s] = sum;
  }
  #pragma unroll
  for (int s = 0; s < 10; ++s) {
    acc[s] += __shfl_xor(acc[s], 1, 64);
    acc[s] += __shfl_xor(acc[s], 2, 64);
  }
  if (p == 0) {
    #pragma unroll
    for (int s = 0; s < 10; ++s) {
      int vnf = vnr_VNF[b*NV_ + s];
      int m   = net_VNF[g*T_ + vnf];
      pi[(size_t)b*(NV_*NN_) + (size_t)s*NN_ + n] = acc[s] + __logf((float)m);
    }
  }
}

// ---------- value head ----------
__global__ __launch_bounds__(128) void k_y1(const float* Hv, const float* nmask, float* y1) {
  int b = blockIdx.x, h = threadIdx.x;
  float s = 0.f, d = 0.f;
  for (int i = 0; i < NV_; ++i) {
    float m = nmask[b*NV_ + i];
    s += Hv[(size_t)(b*NV_ + i)*H_ + h]*m;
    d += m;
  }
  y1[b*H_ + h] = s/d;
}

__global__ __launch_bounds__(128) void k_y2s(const unsigned short* hi, const unsigned short* lo,
                                             float* y2) {
  int b = blockIdx.x, slice = blockIdx.y, h = threadIdx.x;
  int n0 = slice*125, n1 = n0 + 125;
  float s = 0.f;
  for (int n = n0; n < n1; ++n) {
    size_t idx = ((size_t)b*NN_ + n)*H_ + h;
    s += bf16_tof(hi[idx]) + bf16_tof(lo[idx]);
  }
  atomicAdd(&y2[b*H_ + h], s);
}

__global__ __launch_bounds__(64) void k_value(const float* y1, const float* y2,
                                              const float* W_out, const float* b_out,
                                              float* val) {
  int b = blockIdx.x, o = threadIdx.x;
  const float* w = W_out + (size_t)o*256;
  float s = b_out[o];
  for (int h = 0; h < H_; ++h)
    s += y1[b*H_ + h]*w[h] + (y2[b*H_ + h]*(1.f/1000.f))*w[128 + h];
  val[b*O_ + o] = s;
}

extern "C" void kernel_launch(void* const* d_in, const int* in_sizes, int n_in,
                              void* d_out, int out_size, void* d_ws, size_t ws_size,
                              hipStream_t stream) {
  (void)in_sizes; (void)n_in; (void)out_size; (void)ws_size;
  const float* static_feat = (const float*)d_in[0];
  const float* vnr_feat    = (const float*)d_in[1];
  const float* nmask       = (const float*)d_in[2];
  const float* Ws1 = (const float*)d_in[3];  const float* als1 = (const float*)d_in[4];
  const float* ars1 = (const float*)d_in[5]; const float* bs1 = (const float*)d_in[6];
  const float* Ws2 = (const float*)d_in[7];  const float* als2 = (const float*)d_in[8];
  const float* ars2 = (const float*)d_in[9]; const float* bs2 = (const float*)d_in[10];
  const float* Ws3 = (const float*)d_in[11]; const float* als3 = (const float*)d_in[12];
  const float* ars3 = (const float*)d_in[13]; const float* bs3 = (const float*)d_in[14];
  const float* Wv1 = (const float*)d_in[15]; const float* alv1 = (const float*)d_in[16];
  const float* arv1 = (const float*)d_in[17]; const float* bv1 = (const float*)d_in[18];
  const float* Wv2 = (const float*)d_in[19]; const float* alv2 = (const float*)d_in[20];
  const float* arv2 = (const float*)d_in[21]; const float* bv2 = (const float*)d_in[22];
  const float* Wv3 = (const float*)d_in[23]; const float* alv3 = (const float*)d_in[24];
  const float* arv3 = (const float*)d_in[25]; const float* bv3 = (const float*)d_in[26];
  const float* W_attn = (const float*)d_in[27];
  const float* v_attn = (const float*)d_in[28];
  const float* W_ih = (const float*)d_in[29];
  const float* W_hh = (const float*)d_in[30];
  const float* b_ih = (const float*)d_in[31];
  const float* b_hh = (const float*)d_in[32];
  const float* h0   = (const float*)d_in[33];
  const float* W_out = (const float*)d_in[34];
  const float* b_out = (const float*)d_in[35];
  const int* src_s = (const int*)d_in[36];
  const int* dst_s = (const int*)d_in[37];
  const int* src_v = (const int*)d_in[38];
  const int* dst_v = (const int*)d_in[39];
  const int* vnr_VNF = (const int*)d_in[40];
  const int* net_VNF = (const int*)d_in[41];

  char* ws = (char*)d_ws;
  size_t off = 0;
  auto alloc = [&](size_t bytes) -> char* {
    off = (off + 255) & ~(size_t)255;
    char* p = ws + off;
    off += bytes;
    return p;
  };
  float* Z    = (float*)alloc((size_t)NS_*H_*4);          // z buffer; later A1
  unsigned short* HsHi = (unsigned short*)alloc((size_t)NS_*H_*2);
  unsigned short* HsLo = (unsigned short*)alloc((size_t)NS_*H_*2);
  float* Zv   = (float*)alloc((size_t)NVT_*H_*4);
  float* Hv   = (float*)alloc((size_t)NVT_*H_*4);
  float* el_s = (float*)alloc((size_t)NS_*4);
  float* er_s = (float*)alloc((size_t)NS_*4);
  float* el_v = (float*)alloc((size_t)NVT_*4);
  float* er_v = (float*)alloc((size_t)NVT_*4);
  size_t zcount = (size_t)NS_ + NS_ + NVT_ + NVT_ + B_*H_;
  char* zb = alloc(zcount*4);
  int*   counts_s = (int*)zb;
  int*   cursor_s = counts_s + NS_;
  int*   counts_v = cursor_s + NS_;
  int*   cursor_v = counts_v + NVT_;
  float* y2buf    = (float*)(cursor_v + NVT_);
  int* rowptr_s = (int*)alloc((size_t)(NS_+1)*4);
  int* rowptr_v = (int*)alloc((size_t)(NVT_+1)*4);
  int* bsum     = (int*)alloc((size_t)256*4);
  int* srcp_s   = (int*)alloc((size_t)EN_*4);
  int* dstp_s   = (int*)alloc((size_t)EN_*4);
  int* srcp_v   = (int*)alloc((size_t)EV_*4);
  int* dstp_v   = (int*)alloc((size_t)EV_*4);
  float* expe_v = (float*)alloc((size_t)EV_*4);
  unsigned short* WS2hi = (unsigned short*)alloc((size_t)H_*H_*2);
  unsigned short* WS2lo = (unsigned short*)alloc((size_t)H_*H_*2);
  unsigned short* WS3hi = (unsigned short*)alloc((size_t)H_*H_*2);
  unsigned short* WS3lo = (unsigned short*)alloc((size_t)H_*H_*2);
  unsigned short* WAhi  = (unsigned short*)alloc((size_t)H_*H_*2);
  unsigned short* WAlo  = (unsigned short*)alloc((size_t)H_*H_*2);
  float* WTih   = (float*)alloc((size_t)H_*384*4);
  float* GI     = (float*)alloc((size_t)NVT_*384*4);
  float* A2     = (float*)alloc((size_t)NV_*B_*H_*4);
  float* y1buf  = (float*)alloc((size_t)B_*H_*4);

  float* pi  = (float*)d_out;
  float* val = pi + (size_t)B_*NV_*NN_;

  hipMemsetAsync(zb, 0, zcount*4, stream);

  // weight re-layouts
  k_transpose<<<(H_*384 + 255)/256, 256, 0, stream>>>(W_ih, 128, H_, 384, WTih);
  k_wsplit<<<64, 256, 0, stream>>>(Ws2, H_, 1, WS2hi, WS2lo);
  k_wsplit<<<64, 256, 0, stream>>>(Ws3, H_, 1, WS3hi, WS3lo);
  k_wsplit<<<64, 256, 0, stream>>>(W_attn, 2*H_, 0, WAhi, WAlo);

  // CSR build (both graphs)
  k_count<<<EN_/256, 256, 0, stream>>>(dst_s, EN_, counts_s);
  k_count<<<EV_/256, 256, 0, stream>>>(dst_v, EV_, counts_v);
  // big graph: hierarchical scan (250 blocks)
  k_scan_local<<<250, 256, 0, stream>>>(counts_s, NS_, rowptr_s, bsum);
  k_scan_bsum<<<1, 256, 0, stream>>>(bsum, 250);
  k_scan_add<<<250, 256, 0, stream>>>(rowptr_s, bsum, NS_, EN_);
  // small graph: single-block scan
  k_scan<<<1, 1024, 0, stream>>>(counts_v, NVT_, rowptr_v);
  k_scatter<<<EN_/256, 256, 0, stream>>>(src_s, dst_s, EN_, rowptr_s, cursor_s, srcp_s, dstp_s);
  k_scatter<<<EV_/256, 256, 0, stream>>>(src_v, dst_v, EV_, rowptr_v, cursor_v, srcp_v, dstp_v);

  dim3 gemmV(NVT_/16, 1);
  int aggS = (NS_ + 3)/4, aggV = (NVT_ + 3)/4;

  // ---- static GAT stack ----
  k_gemm<<<dim3(NS_/16, 1), 256, 0, stream>>>(static_feat, NS_, FS_, H_, Ws1, nullptr, Z, als1, ars1, el_s, er_s);
  k_aggregate_split<<<aggS, 256, 0, stream>>>(NS_, rowptr_s, srcp_s, el_s, er_s, Z, bs1, HsHi, HsLo);
  k_mfma_gemm<<<NS_/64, 256, 0, stream>>>(HsHi, HsLo, WS2hi, WS2lo, Z, als2, ars2, el_s, er_s);
  k_aggregate_split<<<aggS, 256, 0, stream>>>(NS_, rowptr_s, srcp_s, el_s, er_s, Z, bs2, HsHi, HsLo);
  k_mfma_gemm<<<NS_/64, 256, 0, stream>>>(HsHi, HsLo, WS3hi, WS3lo, Z, als3, ars3, el_s, er_s);
  k_aggregate_split<<<aggS, 256, 0, stream>>>(NS_, rowptr_s, srcp_s, el_s, er_s, Z, bs3, HsHi, HsLo);

  // ---- vnr GAT stack (tiny, f32 path) ----
  k_gemm<<<gemmV, 256, 0, stream>>>(vnr_feat, NVT_, FV_, H_, Wv1, nullptr, Zv, alv1, arv1, el_v, er_v);
  k_edge_exp<<<EV_/256, 256, 0, stream>>>(EV_, srcp_v, dstp_v, el_v, er_v, expe_v);
  k_aggregate<<<aggV, 256, 0, stream>>>(NVT_, rowptr_v, srcp_v, expe_v, Zv, bv1, Hv);
  k_gemm<<<gemmV, 256, 0, stream>>>(Hv, NVT_, H_, H_, Wv2, nullptr, Zv, alv2, arv2, el_v, er_v);
  k_edge_exp<<<EV_/256, 256, 0, stream>>>(EV_, srcp_v, dstp_v, el_v, er_v, expe_v);
  k_aggregate<<<aggV, 256, 0, stream>>>(NVT_, rowptr_v, srcp_v, expe_v, Zv, bv2, Hv);
  k_gemm<<<gemmV, 256, 0, stream>>>(Hv, NVT_, H_, H_, Wv3, nullptr, Zv, alv3, arv3, el_v, er_v);
  k_edge_exp<<<EV_/256, 256, 0, stream>>>(EV_, srcp_v, dstp_v, el_v, er_v, expe_v);
  k_aggregate<<<aggV, 256, 0, stream>>>(NVT_, rowptr_v, srcp_v, expe_v, Zv, bv3, Hv);

  // ---- decoder precomputation ----
  k_gemm<<<dim3(NVT_/16, 3), 256, 0, stream>>>(Hv, NVT_, H_, 384, WTih, b_ih, GI,
                                               nullptr, nullptr, nullptr, nullptr);
  k_mfma_gemm<<<NS_/64, 256, 0, stream>>>(HsHi, HsLo, WAhi, WAlo, Z,
                                          nullptr, nullptr, nullptr, nullptr);
  k_decoder<<<B_, 512, 0, stream>>>(GI, W_hh, b_hh, W_attn, h0, A2);
  k_attn2<<<dim3(16, B_), 256, 0, stream>>>(Z, A2, v_attn, vnr_VNF, net_VNF, pi);

  // ---- value head ----
  k_y1<<<B_, 128, 0, stream>>>(Hv, nmask, y1buf);
  k_y2s<<<dim3(B_, 8), 128, 0, stream>>>(HsHi, HsLo, y2buf);
  k_value<<<B_, 64, 0, stream>>>(y1buf, y2buf, W_out, b_out, val);
}

// Round 5
// 576.132 us; speedup vs baseline: 2.2005x; 1.0734x over previous
//
#include <hip/hip_runtime.h>
#include <hip/hip_bf16.h>
#include <math.h>

#define B_   64
#define NN_  1000
#define NV_  10
#define H_   128
#define FS_  8
#define FV_  6
#define T_   8
#define O_   64
#define EN_  512000
#define EV_  2560
#define NS_  (B_*NN_)   /* 64000 */
#define NVT_ (B_*NV_)   /* 640 */

typedef __attribute__((ext_vector_type(8))) short short8v;   // 8 bf16
typedef __attribute__((ext_vector_type(4))) float floatx4;

__device__ __forceinline__ float fast_tanh(float x) {
  float ax = fabsf(x);
  float e  = __expf(2.f*ax);
  float t  = 1.f - 2.f/(e + 1.f);
  return x >= 0.f ? t : -t;
}
__device__ __forceinline__ float fast_sigmoid(float x) {
  return 1.f/(1.f + __expf(-x));
}
__device__ __forceinline__ unsigned short bf16_rne(float x) {
  unsigned u = __float_as_uint(x);
  return (unsigned short)((u + 0x7FFFu + ((u >> 16) & 1u)) >> 16);
}
__device__ __forceinline__ float bf16_tof(unsigned short b) {
  return __uint_as_float(((unsigned)b) << 16);
}
__device__ __forceinline__ float dot4(float4 a, float4 b) {
  return a.x*b.x + a.y*b.y + a.z*b.z + a.w*b.w;
}

// ---------- CSR build ----------
__global__ __launch_bounds__(256) void k_count(const int* dst, int E, int* counts) {
  int i = blockIdx.x*256 + threadIdx.x;
  if (i < E) atomicAdd(&counts[dst[i]], 1);
}

// small single-block scan (vnr graph only, n<=1024)
__global__ __launch_bounds__(1024) void k_scan(const int* cnt, int n, int* rowptr) {
  __shared__ int sums[1024];
  int t = threadIdx.x;
  int v = (t < n) ? cnt[t] : 0;
  sums[t] = v;
  __syncthreads();
  for (int offd = 1; offd < 1024; offd <<= 1) {
    int u = (t >= offd) ? sums[t-offd] : 0;
    __syncthreads();
    sums[t] += u;
    __syncthreads();
  }
  if (t < n) rowptr[t] = sums[t] - v;     // exclusive
  if (t == n-1) rowptr[n] = sums[t];
}

// hierarchical scan for the big graph: local -> bsum -> add
__global__ __launch_bounds__(256) void k_scan_local(const int* cnt, int n, int* out, int* bsum) {
  __shared__ int s[256];
  int t = threadIdx.x; int i = blockIdx.x*256 + t;
  int v = (i < n) ? cnt[i] : 0;
  s[t] = v; __syncthreads();
  #pragma unroll
  for (int o = 1; o < 256; o <<= 1) {
    int u = (t >= o) ? s[t-o] : 0; __syncthreads();
    s[t] += u; __syncthreads();
  }
  if (i < n) out[i] = s[t] - v;
  if (t == 255) bsum[blockIdx.x] = s[255];
}

__global__ __launch_bounds__(256) void k_scan_bsum(int* bsum, int nb) {
  __shared__ int s[256];
  int t = threadIdx.x;
  int v = (t < nb) ? bsum[t] : 0;
  s[t] = v; __syncthreads();
  #pragma unroll
  for (int o = 1; o < 256; o <<= 1) {
    int u = (t >= o) ? s[t-o] : 0; __syncthreads();
    s[t] += u; __syncthreads();
  }
  if (t < nb) bsum[t] = s[t] - v;
}

__global__ __launch_bounds__(256) void k_scan_add(int* out, const int* bsum, int n, int E) {
  int i = blockIdx.x*256 + threadIdx.x;
  if (i < n) out[i] += bsum[blockIdx.x];
  if (i == 0) out[n] = E;
}

__global__ __launch_bounds__(256) void k_scatter(const int* src, const int* dst, int E,
                                                 const int* rowptr, int* cursor,
                                                 int* srcp, int* dstp) {
  int i = blockIdx.x*256 + threadIdx.x;
  if (i >= E) return;
  int d = dst[i];
  int pos = rowptr[d] + atomicAdd(&cursor[d], 1);
  srcp[pos] = src[i];
  dstp[pos] = d;
}

// ---------- vnr-path GAT pieces (f32, tiny graphs) ----------
__global__ __launch_bounds__(256) void k_edge_exp(int E, const int* srcp, const int* dstp,
                                                  const float* el, const float* er, float* expe) {
  int i = blockIdx.x*256 + threadIdx.x;
  if (i >= E) return;
  float e = el[srcp[i]] + er[dstp[i]];
  e = (e > 0.f) ? e : 0.2f*e;
  expe[i] = __expf(e);
}

__global__ __launch_bounds__(256) void k_aggregate(int nNodes, const int* rowptr,
                                                   const int* srcp, const float* expe,
                                                   const float* z, const float* bias, float* out) {
  int w = (blockIdx.x*256 + threadIdx.x) >> 6;
  int lane = threadIdx.x & 63;
  if (w >= nNodes) return;
  int beg = rowptr[w], end = rowptr[w+1];
  float a0 = 0.f, a1 = 0.f, wsum = 0.f;
  for (int i = beg; i < end; ++i) {
    int sI = srcp[i];
    float wt = expe[i];
    float2 zz = *(const float2*)(z + (size_t)sI*H_ + lane*2);
    a0 += wt*zz.x; a1 += wt*zz.y; wsum += wt;
  }
  float inv = (end > beg) ? 1.f/wsum : 0.f;
  float2 o;
  o.x = a0*inv + bias[lane*2];
  o.y = a1*inv + bias[lane*2 + 1];
  *(float2*)(out + (size_t)w*H_ + lane*2) = o;
}

// ---------- static-path aggregate: fused edge-exp, split-bf16 output ----------
__global__ __launch_bounds__(256) void k_aggregate_split(int nNodes, const int* rowptr,
    const int* srcp, const float* el, const float* er,
    const float* z, const float* bias,
    unsigned short* outHi, unsigned short* outLo) {
  int w = (blockIdx.x*256 + threadIdx.x) >> 6;
  int lane = threadIdx.x & 63;
  if (w >= nNodes) return;
  int beg = rowptr[w], end = rowptr[w+1];
  float erw = er[w];
  float a0 = 0.f, a1 = 0.f, wsum = 0.f;
  for (int i = beg; i < end; ++i) {
    int sI = srcp[i];
    float e = el[sI] + erw;
    e = (e > 0.f) ? e : 0.2f*e;
    float wt = __expf(e);
    float2 zz = *(const float2*)(z + (size_t)sI*H_ + lane*2);
    a0 += wt*zz.x; a1 += wt*zz.y; wsum += wt;
  }
  float inv = (end > beg) ? 1.f/wsum : 0.f;
  float o0 = a0*inv + bias[lane*2];
  float o1 = a1*inv + bias[lane*2 + 1];
  unsigned short h0 = bf16_rne(o0), h1 = bf16_rne(o1);
  unsigned short l0 = bf16_rne(o0 - bf16_tof(h0)), l1 = bf16_rne(o1 - bf16_tof(h1));
  ushort2 hv; hv.x = h0; hv.y = h1;
  ushort2 lv; lv.x = l0; lv.y = l1;
  *(ushort2*)(outHi + (size_t)w*H_ + lane*2) = hv;
  *(ushort2*)(outLo + (size_t)w*H_ + lane*2) = lv;
}

// ---------- weight split (+optional transpose): out[j][k] (hi,lo bf16) ----------
__global__ __launch_bounds__(256) void k_wsplit(const float* in, int ld, int trans,
                                                unsigned short* hi, unsigned short* lo) {
  int idx = blockIdx.x*256 + threadIdx.x;
  if (idx >= H_*H_) return;
  int j = idx >> 7, k = idx & 127;
  float v = trans ? in[(size_t)k*ld + j] : in[(size_t)j*ld + k];
  unsigned short h = bf16_rne(v);
  unsigned short l = bf16_rne(v - bf16_tof(h));
  hi[idx] = h; lo[idx] = l;
}

// ---------- MFMA split-bf16 GEMM: C[M,128] = (Ahi+Alo)@(Whi+Wlo), WT[col][k] ----------
__global__ __launch_bounds__(256) void k_mfma_gemm(
    const unsigned short* __restrict__ Ahi, const unsigned short* __restrict__ Alo,
    const unsigned short* __restrict__ WThi, const unsigned short* __restrict__ WTlo,
    float* __restrict__ C,
    const float* __restrict__ al, const float* __restrict__ ar,
    float* __restrict__ el, float* __restrict__ er) {
  __shared__ unsigned short lAhi[64*136];
  __shared__ unsigned short lAlo[64*136];
  __shared__ float redl[4][64];
  __shared__ float redr[4][64];
  int t = threadIdx.x;
  int row0 = blockIdx.x * 64;
  int wid = t >> 6, lane = t & 63;
  int g = lane >> 4, c = lane & 15;

  #pragma unroll
  for (int i = 0; i < 4; ++i) {
    int m = t + 256*i;
    int r = m >> 4;
    int kc = (m & 15) * 8;
    *(short8v*)(lAhi + r*136 + kc) = *(const short8v*)(Ahi + (size_t)(row0 + r)*H_ + kc);
    *(short8v*)(lAlo + r*136 + kc) = *(const short8v*)(Alo + (size_t)(row0 + r)*H_ + kc);
  }

  short8v bhi[2][4], blo[2][4];
  #pragma unroll
  for (int ct = 0; ct < 2; ++ct) {
    int col = wid*32 + ct*16 + c;
    #pragma unroll
    for (int kb = 0; kb < 4; ++kb) {
      size_t o = (size_t)col*H_ + kb*32 + g*8;
      bhi[ct][kb] = *(const short8v*)(WThi + o);
      blo[ct][kb] = *(const short8v*)(WTlo + o);
    }
  }

  floatx4 acc[4][2];
  #pragma unroll
  for (int rt = 0; rt < 4; ++rt)
    #pragma unroll
    for (int ct = 0; ct < 2; ++ct)
      acc[rt][ct] = (floatx4){0.f, 0.f, 0.f, 0.f};

  __syncthreads();

  #pragma unroll
  for (int kb = 0; kb < 4; ++kb) {
    short8v ahi[4], alo[4];
    #pragma unroll
    for (int rt = 0; rt < 4; ++rt) {
      int r = rt*16 + c;
      ahi[rt] = *(const short8v*)(lAhi + r*136 + kb*32 + g*8);
      alo[rt] = *(const short8v*)(lAlo + r*136 + kb*32 + g*8);
    }
    #pragma unroll
    for (int rt = 0; rt < 4; ++rt)
      #pragma unroll
      for (int ct = 0; ct < 2; ++ct) {
        acc[rt][ct] = __builtin_amdgcn_mfma_f32_16x16x32_bf16(ahi[rt], bhi[ct][kb], acc[rt][ct], 0, 0, 0);
        acc[rt][ct] = __builtin_amdgcn_mfma_f32_16x16x32_bf16(alo[rt], bhi[ct][kb], acc[rt][ct], 0, 0, 0);
        acc[rt][ct] = __builtin_amdgcn_mfma_f32_16x16x32_bf16(ahi[rt], blo[ct][kb], acc[rt][ct], 0, 0, 0);
      }
  }

  #pragma unroll
  for (int rt = 0; rt < 4; ++rt)
    #pragma unroll
    for (int i = 0; i < 4; ++i) {
      int row = row0 + rt*16 + g*4 + i;
      float* cr = C + (size_t)row*H_ + wid*32;
      cr[c]      = acc[rt][0][i];
      cr[16 + c] = acc[rt][1][i];
    }

  if (el) {
    float av0 = al[wid*32 + c], av1 = al[wid*32 + 16 + c];
    float rv0 = ar[wid*32 + c], rv1 = ar[wid*32 + 16 + c];
    #pragma unroll
    for (int rt = 0; rt < 4; ++rt)
      #pragma unroll
      for (int i = 0; i < 4; ++i) {
        float pl = acc[rt][0][i]*av0 + acc[rt][1][i]*av1;
        float pr = acc[rt][0][i]*rv0 + acc[rt][1][i]*rv1;
        pl += __shfl_xor(pl, 1, 64); pl += __shfl_xor(pl, 2, 64);
        pl += __shfl_xor(pl, 4, 64); pl += __shfl_xor(pl, 8, 64);
        pr += __shfl_xor(pr, 1, 64); pr += __shfl_xor(pr, 2, 64);
        pr += __shfl_xor(pr, 4, 64); pr += __shfl_xor(pr, 8, 64);
        if (c == 0) { redl[wid][rt*16 + g*4 + i] = pl; redr[wid][rt*16 + g*4 + i] = pr; }
      }
    __syncthreads();
    if (t < 64) {
      el[row0 + t] = redl[0][t] + redl[1][t] + redl[2][t] + redl[3][t];
      er[row0 + t] = redr[0][t] + redr[1][t] + redr[2][t] + redr[3][t];
    }
  }
}

// ---------- generic f32 GEMM (layer-1 K=8 + tiny vnr/GI GEMMs) ----------
__global__ __launch_bounds__(256) void k_gemm(const float* A, int M, int K, int N,
                                              const float* W, const float* bias, float* C,
                                              const float* al, const float* ar,
                                              float* el, float* er) {
  __shared__ float Ws_[64*128];
  __shared__ float As_[16*128];
  __shared__ float redl[16][17];
  __shared__ float redr[16][17];
  int t = threadIdx.x;
  int j0 = blockIdx.y * 128;
  int row0 = blockIdx.x * 16;
  for (int l = t; l < 16*K; l += 256) {
    int r = l / K, k = l - r*K;
    int row = row0 + r;
    As_[r*K + k] = (row < M) ? A[(size_t)row*K + k] : 0.f;
  }
  int jg = t & 15, r = t >> 4;
  float acc[8];
  #pragma unroll
  for (int q = 0; q < 8; ++q) acc[q] = 0.f;
  for (int kc = 0; kc < K; kc += 64) {
    int kl = min(64, K - kc);
    __syncthreads();
    for (int l = t; l < (kl << 7); l += 256) {
      int k = l >> 7, j = l & 127;
      int jj = j0 + j;
      Ws_[l] = (jj < N) ? W[(size_t)(kc + k)*N + jj] : 0.f;
    }
    __syncthreads();
    for (int k = 0; k < kl; ++k) {
      float a = As_[r*K + kc + k];
      const float* wr = &Ws_[(k << 7) + jg*8];
      #pragma unroll
      for (int q = 0; q < 8; ++q) acc[q] += a * wr[q];
    }
  }
  int row = row0 + r;
  if (row < M) {
    float* crow = C + (size_t)row*N + j0 + jg*8;
    #pragma unroll
    for (int q = 0; q < 8; ++q) {
      int j = j0 + jg*8 + q;
      if (j < N) crow[q] = acc[q] + (bias ? bias[j] : 0.f);
    }
  }
  if (el) {
    float pl = 0.f, pr = 0.f;
    #pragma unroll
    for (int q = 0; q < 8; ++q) {
      int j = jg*8 + q;
      pl += acc[q]*al[j];
      pr += acc[q]*ar[j];
    }
    redl[r][jg] = pl; redr[r][jg] = pr;
    __syncthreads();
    if (t < 16) {
      float sl = 0.f, sr = 0.f;
      for (int q = 0; q < 16; ++q) { sl += redl[t][q]; sr += redr[t][q]; }
      int row2 = row0 + t;
      if (row2 < M) { el[row2] = sl; er[row2] = sr; }
    }
  }
}

// ---------- small transpose for weight re-layout ----------
__global__ __launch_bounds__(256) void k_transpose(const float* in, int inStride,
                                                   int K, int J, float* out) {
  int idx = blockIdx.x*256 + threadIdx.x;
  if (idx >= K*J) return;
  int k = idx / J, j = idx - k*J;
  out[idx] = in[(size_t)j*inStride + k];
}

// ---------- GRU decoder v3: weights register-resident, LDS-broadcast h ----------
// t<384: owns W_hh row t (32 float4 VGPRs). t>=384: owns W_attn[t-384,128:256].
// Per step: gh dots from regs+LDS, gates, A2 dots from regs+LDS. No per-step
// global W traffic (was 196KB/step/block scattered 64-lines-per-instr).
__global__ __launch_bounds__(512) void k_decoder(const float* __restrict__ GI,
                                                 const float* __restrict__ W_hh,
                                                 const float* __restrict__ b_hh,
                                                 const float* __restrict__ W_attn,
                                                 const float* __restrict__ h0,
                                                 float* __restrict__ A2) {
  int b = blockIdx.x;
  __shared__ float h[128];
  __shared__ float gh[384];
  int t = threadIdx.x;
  const float4* wsrc = (t < 384)
      ? (const float4*)(W_hh + (size_t)t*128)
      : (const float4*)(W_attn + (size_t)(t-384)*256 + 128);
  float4 wreg[32];
  #pragma unroll
  for (int kk = 0; kk < 32; ++kk) wreg[kk] = wsrc[kk];
  float bh = (t < 384) ? b_hh[t] : 0.f;
  if (t < 128) h[t] = h0[t];
  __syncthreads();
  for (int s = 0; s < 10; ++s) {
    const float4* h4 = (const float4*)h;
    if (t < 384) {
      float a0 = 0.f, a1 = 0.f, a2 = 0.f, a3 = 0.f;
      #pragma unroll
      for (int kk = 0; kk < 32; kk += 4) {
        a0 += dot4(wreg[kk+0], h4[kk+0]);
        a1 += dot4(wreg[kk+1], h4[kk+1]);
        a2 += dot4(wreg[kk+2], h4[kk+2]);
        a3 += dot4(wreg[kk+3], h4[kk+3]);
      }
      gh[t] = (a0 + a1) + (a2 + a3) + bh;
    }
    __syncthreads();
    if (t < 128) {
      const float* gi = GI + (size_t)(b*NV_ + s)*384;
      float rr = fast_sigmoid(gi[t]       + gh[t]);
      float zz = fast_sigmoid(gi[128 + t] + gh[128 + t]);
      float nn = fast_tanh   (gi[256 + t] + rr*gh[256 + t]);
      h[t] = (1.f - zz)*nn + zz*h[t];
    }
    __syncthreads();
    if (t >= 384) {
      float a0 = 0.f, a1 = 0.f, a2 = 0.f, a3 = 0.f;
      #pragma unroll
      for (int kk = 0; kk < 32; kk += 4) {
        a0 += dot4(wreg[kk+0], h4[kk+0]);
        a1 += dot4(wreg[kk+1], h4[kk+1]);
        a2 += dot4(wreg[kk+2], h4[kk+2]);
        a3 += dot4(wreg[kk+3], h4[kk+3]);
      }
      A2[((size_t)s*B_ + b)*128 + (t - 384)] = (a0 + a1) + (a2 + a3);
    }
    // no barrier here: A2-phase reads h; next gh-phase reads h; the barrier
    // after next gh orders the subsequent h-write against both.
  }
}

// ---------- attention score + mask v2: thread owns (b,n) quarter-row ----------
__global__ __launch_bounds__(256) void k_attn2(const float* __restrict__ A1,
                                               const float* __restrict__ A2,
                                               const float* __restrict__ v_attn,
                                               const int* __restrict__ vnr_VNF,
                                               const int* __restrict__ net_VNF,
                                               float* __restrict__ pi) {
  __shared__ float a2s[10][128];
  __shared__ float vs[128];
  int b = blockIdx.y;
  int t = threadIdx.x;
  for (int i = t; i < 1280; i += 256) {
    int s = i >> 7, k = i & 127;
    a2s[s][k] = A2[((size_t)s*B_ + b)*H_ + k];
  }
  if (t < 128) vs[t] = v_attn[t];
  __syncthreads();
  int nl = t >> 2, p = t & 3;
  int n = blockIdx.x*64 + nl;
  if (n >= NN_) return;
  size_t g = (size_t)b*NN_ + n;
  const float4* arow = (const float4*)(A1 + g*H_ + p*32);
  float4 a[8];
  #pragma unroll
  for (int kk = 0; kk < 8; ++kk) a[kk] = arow[kk];
  float acc[10];
  #pragma unroll
  for (int s = 0; s < 10; ++s) {
    const float* a2r = &a2s[s][p*32];
    const float* vr  = &vs[p*32];
    float sum = 0.f;
    #pragma unroll
    for (int kk = 0; kk < 8; ++kk) {
      float4 c  = *(const float4*)(a2r + kk*4);
      float4 vv = *(const float4*)(vr + kk*4);
      sum += vv.x*fast_tanh(a[kk].x + c.x);
      sum += vv.y*fast_tanh(a[kk].y + c.y);
      sum += vv.z*fast_tanh(a[kk].z + c.z);
      sum += vv.w*fast_tanh(a[kk].w + c.w);
    }
    acc[s] = sum;
  }
  #pragma unroll
  for (int s = 0; s < 10; ++s) {
    acc[s] += __shfl_xor(acc[s], 1, 64);
    acc[s] += __shfl_xor(acc[s], 2, 64);
  }
  if (p == 0) {
    #pragma unroll
    for (int s = 0; s < 10; ++s) {
      int vnf = vnr_VNF[b*NV_ + s];
      int m   = net_VNF[g*T_ + vnf];
      pi[(size_t)b*(NV_*NN_) + (size_t)s*NN_ + n] = acc[s] + __logf((float)m);
    }
  }
}

// ---------- value head ----------
__global__ __launch_bounds__(128) void k_y1(const float* Hv, const float* nmask, float* y1) {
  int b = blockIdx.x, h = threadIdx.x;
  float s = 0.f, d = 0.f;
  for (int i = 0; i < NV_; ++i) {
    float m = nmask[b*NV_ + i];
    s += Hv[(size_t)(b*NV_ + i)*H_ + h]*m;
    d += m;
  }
  y1[b*H_ + h] = s/d;
}

__global__ __launch_bounds__(128) void k_y2s(const unsigned short* hi, const unsigned short* lo,
                                             float* y2) {
  int b = blockIdx.x, slice = blockIdx.y, h = threadIdx.x;
  int n0 = slice*125, n1 = n0 + 125;
  float s = 0.f;
  for (int n = n0; n < n1; ++n) {
    size_t idx = ((size_t)b*NN_ + n)*H_ + h;
    s += bf16_tof(hi[idx]) + bf16_tof(lo[idx]);
  }
  atomicAdd(&y2[b*H_ + h], s);
}

__global__ __launch_bounds__(64) void k_value(const float* y1, const float* y2,
                                              const float* W_out, const float* b_out,
                                              float* val) {
  int b = blockIdx.x, o = threadIdx.x;
  const float* w = W_out + (size_t)o*256;
  float s = b_out[o];
  for (int h = 0; h < H_; ++h)
    s += y1[b*H_ + h]*w[h] + (y2[b*H_ + h]*(1.f/1000.f))*w[128 + h];
  val[b*O_ + o] = s;
}

extern "C" void kernel_launch(void* const* d_in, const int* in_sizes, int n_in,
                              void* d_out, int out_size, void* d_ws, size_t ws_size,
                              hipStream_t stream) {
  (void)in_sizes; (void)n_in; (void)out_size; (void)ws_size;
  const float* static_feat = (const float*)d_in[0];
  const float* vnr_feat    = (const float*)d_in[1];
  const float* nmask       = (const float*)d_in[2];
  const float* Ws1 = (const float*)d_in[3];  const float* als1 = (const float*)d_in[4];
  const float* ars1 = (const float*)d_in[5]; const float* bs1 = (const float*)d_in[6];
  const float* Ws2 = (const float*)d_in[7];  const float* als2 = (const float*)d_in[8];
  const float* ars2 = (const float*)d_in[9]; const float* bs2 = (const float*)d_in[10];
  const float* Ws3 = (const float*)d_in[11]; const float* als3 = (const float*)d_in[12];
  const float* ars3 = (const float*)d_in[13]; const float* bs3 = (const float*)d_in[14];
  const float* Wv1 = (const float*)d_in[15]; const float* alv1 = (const float*)d_in[16];
  const float* arv1 = (const float*)d_in[17]; const float* bv1 = (const float*)d_in[18];
  const float* Wv2 = (const float*)d_in[19]; const float* alv2 = (const float*)d_in[20];
  const float* arv2 = (const float*)d_in[21]; const float* bv2 = (const float*)d_in[22];
  const float* Wv3 = (const float*)d_in[23]; const float* alv3 = (const float*)d_in[24];
  const float* arv3 = (const float*)d_in[25]; const float* bv3 = (const float*)d_in[26];
  const float* W_attn = (const float*)d_in[27];
  const float* v_attn = (const float*)d_in[28];
  const float* W_ih = (const float*)d_in[29];
  const float* W_hh = (const float*)d_in[30];
  const float* b_ih = (const float*)d_in[31];
  const float* b_hh = (const float*)d_in[32];
  const float* h0   = (const float*)d_in[33];
  const float* W_out = (const float*)d_in[34];
  const float* b_out = (const float*)d_in[35];
  const int* src_s = (const int*)d_in[36];
  const int* dst_s = (const int*)d_in[37];
  const int* src_v = (const int*)d_in[38];
  const int* dst_v = (const int*)d_in[39];
  const int* vnr_VNF = (const int*)d_in[40];
  const int* net_VNF = (const int*)d_in[41];

  char* ws = (char*)d_ws;
  size_t off = 0;
  auto alloc = [&](size_t bytes) -> char* {
    off = (off + 255) & ~(size_t)255;
    char* p = ws + off;
    off += bytes;
    return p;
  };
  float* Z    = (float*)alloc((size_t)NS_*H_*4);          // z buffer; later A1
  unsigned short* HsHi = (unsigned short*)alloc((size_t)NS_*H_*2);
  unsigned short* HsLo = (unsigned short*)alloc((size_t)NS_*H_*2);
  float* Zv   = (float*)alloc((size_t)NVT_*H_*4);
  float* Hv   = (float*)alloc((size_t)NVT_*H_*4);
  float* el_s = (float*)alloc((size_t)NS_*4);
  float* er_s = (float*)alloc((size_t)NS_*4);
  float* el_v = (float*)alloc((size_t)NVT_*4);
  float* er_v = (float*)alloc((size_t)NVT_*4);
  size_t zcount = (size_t)NS_ + NS_ + NVT_ + NVT_ + B_*H_;
  char* zb = alloc(zcount*4);
  int*   counts_s = (int*)zb;
  int*   cursor_s = counts_s + NS_;
  int*   counts_v = cursor_s + NS_;
  int*   cursor_v = counts_v + NVT_;
  float* y2buf    = (float*)(cursor_v + NVT_);
  int* rowptr_s = (int*)alloc((size_t)(NS_+1)*4);
  int* rowptr_v = (int*)alloc((size_t)(NVT_+1)*4);
  int* bsum     = (int*)alloc((size_t)256*4);
  int* srcp_s   = (int*)alloc((size_t)EN_*4);
  int* dstp_s   = (int*)alloc((size_t)EN_*4);
  int* srcp_v   = (int*)alloc((size_t)EV_*4);
  int* dstp_v   = (int*)alloc((size_t)EV_*4);
  float* expe_v = (float*)alloc((size_t)EV_*4);
  unsigned short* WS2hi = (unsigned short*)alloc((size_t)H_*H_*2);
  unsigned short* WS2lo = (unsigned short*)alloc((size_t)H_*H_*2);
  unsigned short* WS3hi = (unsigned short*)alloc((size_t)H_*H_*2);
  unsigned short* WS3lo = (unsigned short*)alloc((size_t)H_*H_*2);
  unsigned short* WAhi  = (unsigned short*)alloc((size_t)H_*H_*2);
  unsigned short* WAlo  = (unsigned short*)alloc((size_t)H_*H_*2);
  float* WTih   = (float*)alloc((size_t)H_*384*4);
  float* GI     = (float*)alloc((size_t)NVT_*384*4);
  float* A2     = (float*)alloc((size_t)NV_*B_*H_*4);
  float* y1buf  = (float*)alloc((size_t)B_*H_*4);

  float* pi  = (float*)d_out;
  float* val = pi + (size_t)B_*NV_*NN_;

  hipMemsetAsync(zb, 0, zcount*4, stream);

  // weight re-layouts
  k_transpose<<<(H_*384 + 255)/256, 256, 0, stream>>>(W_ih, 128, H_, 384, WTih);
  k_wsplit<<<64, 256, 0, stream>>>(Ws2, H_, 1, WS2hi, WS2lo);
  k_wsplit<<<64, 256, 0, stream>>>(Ws3, H_, 1, WS3hi, WS3lo);
  k_wsplit<<<64, 256, 0, stream>>>(W_attn, 2*H_, 0, WAhi, WAlo);

  // CSR build (both graphs)
  k_count<<<EN_/256, 256, 0, stream>>>(dst_s, EN_, counts_s);
  k_count<<<EV_/256, 256, 0, stream>>>(dst_v, EV_, counts_v);
  k_scan_local<<<250, 256, 0, stream>>>(counts_s, NS_, rowptr_s, bsum);
  k_scan_bsum<<<1, 256, 0, stream>>>(bsum, 250);
  k_scan_add<<<250, 256, 0, stream>>>(rowptr_s, bsum, NS_, EN_);
  k_scan<<<1, 1024, 0, stream>>>(counts_v, NVT_, rowptr_v);
  k_scatter<<<EN_/256, 256, 0, stream>>>(src_s, dst_s, EN_, rowptr_s, cursor_s, srcp_s, dstp_s);
  k_scatter<<<EV_/256, 256, 0, stream>>>(src_v, dst_v, EV_, rowptr_v, cursor_v, srcp_v, dstp_v);

  dim3 gemmV(NVT_/16, 1);
  int aggS = (NS_ + 3)/4, aggV = (NVT_ + 3)/4;

  // ---- static GAT stack ----
  k_gemm<<<dim3(NS_/16, 1), 256, 0, stream>>>(static_feat, NS_, FS_, H_, Ws1, nullptr, Z, als1, ars1, el_s, er_s);
  k_aggregate_split<<<aggS, 256, 0, stream>>>(NS_, rowptr_s, srcp_s, el_s, er_s, Z, bs1, HsHi, HsLo);
  k_mfma_gemm<<<NS_/64, 256, 0, stream>>>(HsHi, HsLo, WS2hi, WS2lo, Z, als2, ars2, el_s, er_s);
  k_aggregate_split<<<aggS, 256, 0, stream>>>(NS_, rowptr_s, srcp_s, el_s, er_s, Z, bs2, HsHi, HsLo);
  k_mfma_gemm<<<NS_/64, 256, 0, stream>>>(HsHi, HsLo, WS3hi, WS3lo, Z, als3, ars3, el_s, er_s);
  k_aggregate_split<<<aggS, 256, 0, stream>>>(NS_, rowptr_s, srcp_s, el_s, er_s, Z, bs3, HsHi, HsLo);

  // ---- vnr GAT stack (tiny, f32 path) ----
  k_gemm<<<gemmV, 256, 0, stream>>>(vnr_feat, NVT_, FV_, H_, Wv1, nullptr, Zv, alv1, arv1, el_v, er_v);
  k_edge_exp<<<EV_/256, 256, 0, stream>>>(EV_, srcp_v, dstp_v, el_v, er_v, expe_v);
  k_aggregate<<<aggV, 256, 0, stream>>>(NVT_, rowptr_v, srcp_v, expe_v, Zv, bv1, Hv);
  k_gemm<<<gemmV, 256, 0, stream>>>(Hv, NVT_, H_, H_, Wv2, nullptr, Zv, alv2, arv2, el_v, er_v);
  k_edge_exp<<<EV_/256, 256, 0, stream>>>(EV_, srcp_v, dstp_v, el_v, er_v, expe_v);
  k_aggregate<<<aggV, 256, 0, stream>>>(NVT_, rowptr_v, srcp_v, expe_v, Zv, bv2, Hv);
  k_gemm<<<gemmV, 256, 0, stream>>>(Hv, NVT_, H_, H_, Wv3, nullptr, Zv, alv3, arv3, el_v, er_v);
  k_edge_exp<<<EV_/256, 256, 0, stream>>>(EV_, srcp_v, dstp_v, el_v, er_v, expe_v);
  k_aggregate<<<aggV, 256, 0, stream>>>(NVT_, rowptr_v, srcp_v, expe_v, Zv, bv3, Hv);

  // ---- decoder precomputation ----
  k_gemm<<<dim3(NVT_/16, 3), 256, 0, stream>>>(Hv, NVT_, H_, 384, WTih, b_ih, GI,
                                               nullptr, nullptr, nullptr, nullptr);
  k_mfma_gemm<<<NS_/64, 256, 0, stream>>>(HsHi, HsLo, WAhi, WAlo, Z,
                                          nullptr, nullptr, nullptr, nullptr);
  k_decoder<<<B_, 512, 0, stream>>>(GI, W_hh, b_hh, W_attn, h0, A2);
  k_attn2<<<dim3(16, B_), 256, 0, stream>>>(Z, A2, v_attn, vnr_VNF, net_VNF, pi);

  // ---- value head ----
  k_y1<<<B_, 128, 0, stream>>>(Hv, nmask, y1buf);
  k_y2s<<<dim3(B_, 8), 128, 0, stream>>>(HsHi, HsLo, y2buf);
  k_value<<<B_, 64, 0, stream>>>(y1buf, y2buf, W_out, b_out, val);
}

// Round 6
// 484.204 us; speedup vs baseline: 2.6183x; 1.1899x over previous
//
#include <hip/hip_runtime.h>
#include <hip/hip_bf16.h>
#include <math.h>

#define B_   64
#define NN_  1000
#define NV_  10
#define H_   128
#define FS_  8
#define FV_  6
#define T_   8
#define O_   64
#define EN_  512000
#define EV_  2560
#define NS_  (B_*NN_)   /* 64000 */
#define NVT_ (B_*NV_)   /* 640 */

typedef __attribute__((ext_vector_type(8))) short short8v;   // 8 bf16
typedef __attribute__((ext_vector_type(4))) float floatx4;

__device__ __forceinline__ float fast_tanh(float x) {
  float ax = fabsf(x);
  float e  = __expf(2.f*ax);
  float t  = 1.f - 2.f/(e + 1.f);
  return x >= 0.f ? t : -t;
}
__device__ __forceinline__ float fast_sigmoid(float x) {
  return 1.f/(1.f + __expf(-x));
}
__device__ __forceinline__ unsigned short bf16_rne(float x) {
  unsigned u = __float_as_uint(x);
  return (unsigned short)((u + 0x7FFFu + ((u >> 16) & 1u)) >> 16);
}
__device__ __forceinline__ float bf16_tof(unsigned short b) {
  return __uint_as_float(((unsigned)b) << 16);
}
__device__ __forceinline__ float dot4(float4 a, float4 b) {
  return a.x*b.x + a.y*b.y + a.z*b.z + a.w*b.w;
}
__device__ __forceinline__ float lrelu02(float e) {
  return (e > 0.f) ? e : 0.2f*e;
}

// ---------- CSR build ----------
__global__ __launch_bounds__(256) void k_count(const int* dst, int E, int* counts) {
  int i = blockIdx.x*256 + threadIdx.x;
  if (i < E) atomicAdd(&counts[dst[i]], 1);
}

// small single-block scan (vnr graph only, n<=1024)
__global__ __launch_bounds__(1024) void k_scan(const int* cnt, int n, int* rowptr) {
  __shared__ int sums[1024];
  int t = threadIdx.x;
  int v = (t < n) ? cnt[t] : 0;
  sums[t] = v;
  __syncthreads();
  for (int offd = 1; offd < 1024; offd <<= 1) {
    int u = (t >= offd) ? sums[t-offd] : 0;
    __syncthreads();
    sums[t] += u;
    __syncthreads();
  }
  if (t < n) rowptr[t] = sums[t] - v;     // exclusive
  if (t == n-1) rowptr[n] = sums[t];
}

// hierarchical scan for the big graph: local -> bsum -> add
__global__ __launch_bounds__(256) void k_scan_local(const int* cnt, int n, int* out, int* bsum) {
  __shared__ int s[256];
  int t = threadIdx.x; int i = blockIdx.x*256 + t;
  int v = (i < n) ? cnt[i] : 0;
  s[t] = v; __syncthreads();
  #pragma unroll
  for (int o = 1; o < 256; o <<= 1) {
    int u = (t >= o) ? s[t-o] : 0; __syncthreads();
    s[t] += u; __syncthreads();
  }
  if (i < n) out[i] = s[t] - v;
  if (t == 255) bsum[blockIdx.x] = s[255];
}

__global__ __launch_bounds__(256) void k_scan_bsum(int* bsum, int nb) {
  __shared__ int s[256];
  int t = threadIdx.x;
  int v = (t < nb) ? bsum[t] : 0;
  s[t] = v; __syncthreads();
  #pragma unroll
  for (int o = 1; o < 256; o <<= 1) {
    int u = (t >= o) ? s[t-o] : 0; __syncthreads();
    s[t] += u; __syncthreads();
  }
  if (t < nb) bsum[t] = s[t] - v;
}

__global__ __launch_bounds__(256) void k_scan_add(int* out, const int* bsum, int n, int E) {
  int i = blockIdx.x*256 + threadIdx.x;
  if (i < n) out[i] += bsum[blockIdx.x];
  if (i == 0) out[n] = E;
}

__global__ __launch_bounds__(256) void k_scatter(const int* src, const int* dst, int E,
                                                 const int* rowptr, int* cursor,
                                                 int* srcp, int* dstp) {
  int i = blockIdx.x*256 + threadIdx.x;
  if (i >= E) return;
  int d = dst[i];
  int pos = rowptr[d] + atomicAdd(&cursor[d], 1);
  srcp[pos] = src[i];
  dstp[pos] = d;
}

// ---------- vnr-path GAT pieces (f32, tiny graphs) ----------
__global__ __launch_bounds__(256) void k_edge_exp(int E, const int* srcp, const int* dstp,
                                                  const float* el, const float* er, float* expe) {
  int i = blockIdx.x*256 + threadIdx.x;
  if (i >= E) return;
  float e = el[srcp[i]] + er[dstp[i]];
  e = (e > 0.f) ? e : 0.2f*e;
  expe[i] = __expf(e);
}

__global__ __launch_bounds__(256) void k_aggregate(int nNodes, const int* rowptr,
                                                   const int* srcp, const float* expe,
                                                   const float* z, const float* bias, float* out) {
  int w = (blockIdx.x*256 + threadIdx.x) >> 6;
  int lane = threadIdx.x & 63;
  if (w >= nNodes) return;
  int beg = rowptr[w], end = rowptr[w+1];
  float a0 = 0.f, a1 = 0.f, wsum = 0.f;
  for (int i = beg; i < end; ++i) {
    int sI = srcp[i];
    float wt = expe[i];
    float2 zz = *(const float2*)(z + (size_t)sI*H_ + lane*2);
    a0 += wt*zz.x; a1 += wt*zz.y; wsum += wt;
  }
  float inv = (end > beg) ? 1.f/wsum : 0.f;
  float2 o;
  o.x = a0*inv + bias[lane*2];
  o.y = a1*inv + bias[lane*2 + 1];
  *(float2*)(out + (size_t)w*H_ + lane*2) = o;
}

// ---------- static-path aggregate: bf16 z gather, 4x pipelined, split-bf16 out ----------
__global__ __launch_bounds__(256) void k_aggregate_split(int nNodes, const int* __restrict__ rowptr,
    const int* __restrict__ srcp, const float* __restrict__ el, const float* __restrict__ er,
    const unsigned short* __restrict__ z, const float* __restrict__ bias,
    unsigned short* __restrict__ outHi, unsigned short* __restrict__ outLo) {
  int w = (blockIdx.x*256 + threadIdx.x) >> 6;
  int lane = threadIdx.x & 63;
  if (w >= nNodes) return;
  int beg = rowptr[w], end = rowptr[w+1];
  float erw = er[w];
  float a0 = 0.f, a1 = 0.f, wsum = 0.f;
  int i = beg;
  // 4x unroll: 4 srcp loads -> 4 el + 4 z-row loads all in flight
  for (; i + 4 <= end; i += 4) {
    int s0 = srcp[i+0], s1 = srcp[i+1], s2 = srcp[i+2], s3 = srcp[i+3];
    float l0 = el[s0], l1 = el[s1], l2 = el[s2], l3 = el[s3];
    ushort2 q0 = *(const ushort2*)(z + (size_t)s0*H_ + lane*2);
    ushort2 q1 = *(const ushort2*)(z + (size_t)s1*H_ + lane*2);
    ushort2 q2 = *(const ushort2*)(z + (size_t)s2*H_ + lane*2);
    ushort2 q3 = *(const ushort2*)(z + (size_t)s3*H_ + lane*2);
    float w0 = __expf(lrelu02(l0 + erw));
    float w1 = __expf(lrelu02(l1 + erw));
    float w2 = __expf(lrelu02(l2 + erw));
    float w3 = __expf(lrelu02(l3 + erw));
    a0 += w0*bf16_tof(q0.x) + w1*bf16_tof(q1.x) + w2*bf16_tof(q2.x) + w3*bf16_tof(q3.x);
    a1 += w0*bf16_tof(q0.y) + w1*bf16_tof(q1.y) + w2*bf16_tof(q2.y) + w3*bf16_tof(q3.y);
    wsum += (w0 + w1) + (w2 + w3);
  }
  for (; i < end; ++i) {
    int sI = srcp[i];
    float wt = __expf(lrelu02(el[sI] + erw));
    ushort2 q = *(const ushort2*)(z + (size_t)sI*H_ + lane*2);
    a0 += wt*bf16_tof(q.x); a1 += wt*bf16_tof(q.y); wsum += wt;
  }
  float inv = (end > beg) ? 1.f/wsum : 0.f;
  float o0 = a0*inv + bias[lane*2];
  float o1 = a1*inv + bias[lane*2 + 1];
  unsigned short h0 = bf16_rne(o0), h1 = bf16_rne(o1);
  unsigned short l0 = bf16_rne(o0 - bf16_tof(h0)), l1 = bf16_rne(o1 - bf16_tof(h1));
  ushort2 hv; hv.x = h0; hv.y = h1;
  ushort2 lv; lv.x = l0; lv.y = l1;
  *(ushort2*)(outHi + (size_t)w*H_ + lane*2) = hv;
  *(ushort2*)(outLo + (size_t)w*H_ + lane*2) = lv;
}

// ---------- weight split (+optional transpose): out[j][k] (hi,lo bf16) ----------
__global__ __launch_bounds__(256) void k_wsplit(const float* in, int ld, int trans,
                                                unsigned short* hi, unsigned short* lo) {
  int idx = blockIdx.x*256 + threadIdx.x;
  if (idx >= H_*H_) return;
  int j = idx >> 7, k = idx & 127;
  float v = trans ? in[(size_t)k*ld + j] : in[(size_t)j*ld + k];
  unsigned short h = bf16_rne(v);
  unsigned short l = bf16_rne(v - bf16_tof(h));
  hi[idx] = h; lo[idx] = l;
}

// ---------- MFMA split-bf16 GEMM: C/Cb[M,128] = (Ahi+Alo)@(Whi+Wlo), WT[col][k] ----------
__global__ __launch_bounds__(256) void k_mfma_gemm(
    const unsigned short* __restrict__ Ahi, const unsigned short* __restrict__ Alo,
    const unsigned short* __restrict__ WThi, const unsigned short* __restrict__ WTlo,
    float* __restrict__ C, unsigned short* __restrict__ Cb,
    const float* __restrict__ al, const float* __restrict__ ar,
    float* __restrict__ el, float* __restrict__ er) {
  __shared__ unsigned short lAhi[64*136];
  __shared__ unsigned short lAlo[64*136];
  __shared__ float redl[4][64];
  __shared__ float redr[4][64];
  int t = threadIdx.x;
  int row0 = blockIdx.x * 64;
  int wid = t >> 6, lane = t & 63;
  int g = lane >> 4, c = lane & 15;

  #pragma unroll
  for (int i = 0; i < 4; ++i) {
    int m = t + 256*i;
    int r = m >> 4;
    int kc = (m & 15) * 8;
    *(short8v*)(lAhi + r*136 + kc) = *(const short8v*)(Ahi + (size_t)(row0 + r)*H_ + kc);
    *(short8v*)(lAlo + r*136 + kc) = *(const short8v*)(Alo + (size_t)(row0 + r)*H_ + kc);
  }

  short8v bhi[2][4], blo[2][4];
  #pragma unroll
  for (int ct = 0; ct < 2; ++ct) {
    int col = wid*32 + ct*16 + c;
    #pragma unroll
    for (int kb = 0; kb < 4; ++kb) {
      size_t o = (size_t)col*H_ + kb*32 + g*8;
      bhi[ct][kb] = *(const short8v*)(WThi + o);
      blo[ct][kb] = *(const short8v*)(WTlo + o);
    }
  }

  floatx4 acc[4][2];
  #pragma unroll
  for (int rt = 0; rt < 4; ++rt)
    #pragma unroll
    for (int ct = 0; ct < 2; ++ct)
      acc[rt][ct] = (floatx4){0.f, 0.f, 0.f, 0.f};

  __syncthreads();

  #pragma unroll
  for (int kb = 0; kb < 4; ++kb) {
    short8v ahi[4], alo[4];
    #pragma unroll
    for (int rt = 0; rt < 4; ++rt) {
      int r = rt*16 + c;
      ahi[rt] = *(const short8v*)(lAhi + r*136 + kb*32 + g*8);
      alo[rt] = *(const short8v*)(lAlo + r*136 + kb*32 + g*8);
    }
    #pragma unroll
    for (int rt = 0; rt < 4; ++rt)
      #pragma unroll
      for (int ct = 0; ct < 2; ++ct) {
        acc[rt][ct] = __builtin_amdgcn_mfma_f32_16x16x32_bf16(ahi[rt], bhi[ct][kb], acc[rt][ct], 0, 0, 0);
        acc[rt][ct] = __builtin_amdgcn_mfma_f32_16x16x32_bf16(alo[rt], bhi[ct][kb], acc[rt][ct], 0, 0, 0);
        acc[rt][ct] = __builtin_amdgcn_mfma_f32_16x16x32_bf16(ahi[rt], blo[ct][kb], acc[rt][ct], 0, 0, 0);
      }
  }

  #pragma unroll
  for (int rt = 0; rt < 4; ++rt)
    #pragma unroll
    for (int i = 0; i < 4; ++i) {
      int row = row0 + rt*16 + g*4 + i;
      if (Cb) {
        unsigned short* cr = Cb + (size_t)row*H_ + wid*32;
        cr[c]      = bf16_rne(acc[rt][0][i]);
        cr[16 + c] = bf16_rne(acc[rt][1][i]);
      } else {
        float* cr = C + (size_t)row*H_ + wid*32;
        cr[c]      = acc[rt][0][i];
        cr[16 + c] = acc[rt][1][i];
      }
    }

  if (el) {
    float av0 = al[wid*32 + c], av1 = al[wid*32 + 16 + c];
    float rv0 = ar[wid*32 + c], rv1 = ar[wid*32 + 16 + c];
    #pragma unroll
    for (int rt = 0; rt < 4; ++rt)
      #pragma unroll
      for (int i = 0; i < 4; ++i) {
        float pl = acc[rt][0][i]*av0 + acc[rt][1][i]*av1;
        float pr = acc[rt][0][i]*rv0 + acc[rt][1][i]*rv1;
        pl += __shfl_xor(pl, 1, 64); pl += __shfl_xor(pl, 2, 64);
        pl += __shfl_xor(pl, 4, 64); pl += __shfl_xor(pl, 8, 64);
        pr += __shfl_xor(pr, 1, 64); pr += __shfl_xor(pr, 2, 64);
        pr += __shfl_xor(pr, 4, 64); pr += __shfl_xor(pr, 8, 64);
        if (c == 0) { redl[wid][rt*16 + g*4 + i] = pl; redr[wid][rt*16 + g*4 + i] = pr; }
      }
    __syncthreads();
    if (t < 64) {
      el[row0 + t] = redl[0][t] + redl[1][t] + redl[2][t] + redl[3][t];
      er[row0 + t] = redr[0][t] + redr[1][t] + redr[2][t] + redr[3][t];
    }
  }
}

// ---------- generic f32 GEMM (layer-1 K=8 + tiny vnr/GI GEMMs) ----------
__global__ __launch_bounds__(256) void k_gemm(const float* A, int M, int K, int N,
                                              const float* W, const float* bias,
                                              float* C, unsigned short* Cb,
                                              const float* al, const float* ar,
                                              float* el, float* er) {
  __shared__ float Ws_[64*128];
  __shared__ float As_[16*128];
  __shared__ float redl[16][17];
  __shared__ float redr[16][17];
  int t = threadIdx.x;
  int j0 = blockIdx.y * 128;
  int row0 = blockIdx.x * 16;
  for (int l = t; l < 16*K; l += 256) {
    int r = l / K, k = l - r*K;
    int row = row0 + r;
    As_[r*K + k] = (row < M) ? A[(size_t)row*K + k] : 0.f;
  }
  int jg = t & 15, r = t >> 4;
  float acc[8];
  #pragma unroll
  for (int q = 0; q < 8; ++q) acc[q] = 0.f;
  for (int kc = 0; kc < K; kc += 64) {
    int kl = min(64, K - kc);
    __syncthreads();
    for (int l = t; l < (kl << 7); l += 256) {
      int k = l >> 7, j = l & 127;
      int jj = j0 + j;
      Ws_[l] = (jj < N) ? W[(size_t)(kc + k)*N + jj] : 0.f;
    }
    __syncthreads();
    for (int k = 0; k < kl; ++k) {
      float a = As_[r*K + kc + k];
      const float* wr = &Ws_[(k << 7) + jg*8];
      #pragma unroll
      for (int q = 0; q < 8; ++q) acc[q] += a * wr[q];
    }
  }
  int row = row0 + r;
  if (row < M) {
    if (Cb) {
      unsigned short* crow = Cb + (size_t)row*N + j0 + jg*8;
      #pragma unroll
      for (int q = 0; q < 8; ++q) {
        int j = j0 + jg*8 + q;
        if (j < N) crow[q] = bf16_rne(acc[q] + (bias ? bias[j] : 0.f));
      }
    } else {
      float* crow = C + (size_t)row*N + j0 + jg*8;
      #pragma unroll
      for (int q = 0; q < 8; ++q) {
        int j = j0 + jg*8 + q;
        if (j < N) crow[q] = acc[q] + (bias ? bias[j] : 0.f);
      }
    }
  }
  if (el) {
    float pl = 0.f, pr = 0.f;
    #pragma unroll
    for (int q = 0; q < 8; ++q) {
      int j = jg*8 + q;
      pl += acc[q]*al[j];
      pr += acc[q]*ar[j];
    }
    redl[r][jg] = pl; redr[r][jg] = pr;
    __syncthreads();
    if (t < 16) {
      float sl = 0.f, sr = 0.f;
      for (int q = 0; q < 16; ++q) { sl += redl[t][q]; sr += redr[t][q]; }
      int row2 = row0 + t;
      if (row2 < M) { el[row2] = sl; er[row2] = sr; }
    }
  }
}

// ---------- small transpose for weight re-layout ----------
__global__ __launch_bounds__(256) void k_transpose(const float* in, int inStride,
                                                   int K, int J, float* out) {
  int idx = blockIdx.x*256 + threadIdx.x;
  if (idx >= K*J) return;
  int k = idx / J, j = idx - k*J;
  out[idx] = in[(size_t)j*inStride + k];
}

// ---------- GRU decoder v3: weights register-resident, LDS-broadcast h ----------
__global__ __launch_bounds__(512) void k_decoder(const float* __restrict__ GI,
                                                 const float* __restrict__ W_hh,
                                                 const float* __restrict__ b_hh,
                                                 const float* __restrict__ W_attn,
                                                 const float* __restrict__ h0,
                                                 float* __restrict__ A2) {
  int b = blockIdx.x;
  __shared__ float h[128];
  __shared__ float gh[384];
  int t = threadIdx.x;
  const float4* wsrc = (t < 384)
      ? (const float4*)(W_hh + (size_t)t*128)
      : (const float4*)(W_attn + (size_t)(t-384)*256 + 128);
  float4 wreg[32];
  #pragma unroll
  for (int kk = 0; kk < 32; ++kk) wreg[kk] = wsrc[kk];
  float bh = (t < 384) ? b_hh[t] : 0.f;
  if (t < 128) h[t] = h0[t];
  __syncthreads();
  for (int s = 0; s < 10; ++s) {
    const float4* h4 = (const float4*)h;
    if (t < 384) {
      float a0 = 0.f, a1 = 0.f, a2 = 0.f, a3 = 0.f;
      #pragma unroll
      for (int kk = 0; kk < 32; kk += 4) {
        a0 += dot4(wreg[kk+0], h4[kk+0]);
        a1 += dot4(wreg[kk+1], h4[kk+1]);
        a2 += dot4(wreg[kk+2], h4[kk+2]);
        a3 += dot4(wreg[kk+3], h4[kk+3]);
      }
      gh[t] = (a0 + a1) + (a2 + a3) + bh;
    }
    __syncthreads();
    if (t < 128) {
      const float* gi = GI + (size_t)(b*NV_ + s)*384;
      float rr = fast_sigmoid(gi[t]       + gh[t]);
      float zz = fast_sigmoid(gi[128 + t] + gh[128 + t]);
      float nn = fast_tanh   (gi[256 + t] + rr*gh[256 + t]);
      h[t] = (1.f - zz)*nn + zz*h[t];
    }
    __syncthreads();
    if (t >= 384) {
      float a0 = 0.f, a1 = 0.f, a2 = 0.f, a3 = 0.f;
      #pragma unroll
      for (int kk = 0; kk < 32; kk += 4) {
        a0 += dot4(wreg[kk+0], h4[kk+0]);
        a1 += dot4(wreg[kk+1], h4[kk+1]);
        a2 += dot4(wreg[kk+2], h4[kk+2]);
        a3 += dot4(wreg[kk+3], h4[kk+3]);
      }
      A2[((size_t)s*B_ + b)*128 + (t - 384)] = (a0 + a1) + (a2 + a3);
    }
  }
}

// ---------- attention score + mask v2: thread owns (b,n) quarter-row ----------
__global__ __launch_bounds__(256) void k_attn2(const float* __restrict__ A1,
                                               const float* __restrict__ A2,
                                               const float* __restrict__ v_attn,
                                               const int* __restrict__ vnr_VNF,
                                               const int* __restrict__ net_VNF,
                                               float* __restrict__ pi) {
  __shared__ float a2s[10][128];
  __shared__ float vs[128];
  int b = blockIdx.y;
  int t = threadIdx.x;
  for (int i = t; i < 1280; i += 256) {
    int s = i >> 7, k = i & 127;
    a2s[s][k] = A2[((size_t)s*B_ + b)*H_ + k];
  }
  if (t < 128) vs[t] = v_attn[t];
  __syncthreads();
  int nl = t >> 2, p = t & 3;
  int n = blockIdx.x*64 + nl;
  if (n >= NN_) return;
  size_t g = (size_t)b*NN_ + n;
  const float4* arow = (const float4*)(A1 + g*H_ + p*32);
  float4 a[8];
  #pragma unroll
  for (int kk = 0; kk < 8; ++kk) a[kk] = arow[kk];
  float acc[10];
  #pragma unroll
  for (int s = 0; s < 10; ++s) {
    const float* a2r = &a2s[s][p*32];
    const float* vr  = &vs[p*32];
    float sum = 0.f;
    #pragma unroll
    for (int kk = 0; kk < 8; ++kk) {
      float4 c  = *(const float4*)(a2r + kk*4);
      float4 vv = *(const float4*)(vr + kk*4);
      sum += vv.x*fast_tanh(a[kk].x + c.x);
      sum += vv.y*fast_tanh(a[kk].y + c.y);
      sum += vv.z*fast_tanh(a[kk].z + c.z);
      sum += vv.w*fast_tanh(a[kk].w + c.w);
    }
    acc[s] = sum;
  }
  #pragma unroll
  for (int s = 0; s < 10; ++s) {
    acc[s] += __shfl_xor(acc[s], 1, 64);
    acc[s] += __shfl_xor(acc[s], 2, 64);
  }
  if (p == 0) {
    #pragma unroll
    for (int s = 0; s < 10; ++s) {
      int vnf = vnr_VNF[b*NV_ + s];
      int m   = net_VNF[g*T_ + vnf];
      pi[(size_t)b*(NV_*NN_) + (size_t)s*NN_ + n] = acc[s] + __logf((float)m);
    }
  }
}

// ---------- value head ----------
__global__ __launch_bounds__(128) void k_y1(const float* Hv, const float* nmask, float* y1) {
  int b = blockIdx.x, h = threadIdx.x;
  float s = 0.f, d = 0.f;
  for (int i = 0; i < NV_; ++i) {
    float m = nmask[b*NV_ + i];
    s += Hv[(size_t)(b*NV_ + i)*H_ + h]*m;
    d += m;
  }
  y1[b*H_ + h] = s/d;
}

__global__ __launch_bounds__(128) void k_y2s(const unsigned short* hi, const unsigned short* lo,
                                             float* y2) {
  int b = blockIdx.x, slice = blockIdx.y, h = threadIdx.x;
  int n0 = slice*125, n1 = n0 + 125;
  float s = 0.f;
  for (int n = n0; n < n1; ++n) {
    size_t idx = ((size_t)b*NN_ + n)*H_ + h;
    s += bf16_tof(hi[idx]) + bf16_tof(lo[idx]);
  }
  atomicAdd(&y2[b*H_ + h], s);
}

__global__ __launch_bounds__(64) void k_value(const float* y1, const float* y2,
                                              const float* W_out, const float* b_out,
                                              float* val) {
  int b = blockIdx.x, o = threadIdx.x;
  const float* w = W_out + (size_t)o*256;
  float s = b_out[o];
  for (int h = 0; h < H_; ++h)
    s += y1[b*H_ + h]*w[h] + (y2[b*H_ + h]*(1.f/1000.f))*w[128 + h];
  val[b*O_ + o] = s;
}

extern "C" void kernel_launch(void* const* d_in, const int* in_sizes, int n_in,
                              void* d_out, int out_size, void* d_ws, size_t ws_size,
                              hipStream_t stream) {
  (void)in_sizes; (void)n_in; (void)out_size; (void)ws_size;
  const float* static_feat = (const float*)d_in[0];
  const float* vnr_feat    = (const float*)d_in[1];
  const float* nmask       = (const float*)d_in[2];
  const float* Ws1 = (const float*)d_in[3];  const float* als1 = (const float*)d_in[4];
  const float* ars1 = (const float*)d_in[5]; const float* bs1 = (const float*)d_in[6];
  const float* Ws2 = (const float*)d_in[7];  const float* als2 = (const float*)d_in[8];
  const float* ars2 = (const float*)d_in[9]; const float* bs2 = (const float*)d_in[10];
  const float* Ws3 = (const float*)d_in[11]; const float* als3 = (const float*)d_in[12];
  const float* ars3 = (const float*)d_in[13]; const float* bs3 = (const float*)d_in[14];
  const float* Wv1 = (const float*)d_in[15]; const float* alv1 = (const float*)d_in[16];
  const float* arv1 = (const float*)d_in[17]; const float* bv1 = (const float*)d_in[18];
  const float* Wv2 = (const float*)d_in[19]; const float* alv2 = (const float*)d_in[20];
  const float* arv2 = (const float*)d_in[21]; const float* bv2 = (const float*)d_in[22];
  const float* Wv3 = (const float*)d_in[23]; const float* alv3 = (const float*)d_in[24];
  const float* arv3 = (const float*)d_in[25]; const float* bv3 = (const float*)d_in[26];
  const float* W_attn = (const float*)d_in[27];
  const float* v_attn = (const float*)d_in[28];
  const float* W_ih = (const float*)d_in[29];
  const float* W_hh = (const float*)d_in[30];
  const float* b_ih = (const float*)d_in[31];
  const float* b_hh = (const float*)d_in[32];
  const float* h0   = (const float*)d_in[33];
  const float* W_out = (const float*)d_in[34];
  const float* b_out = (const float*)d_in[35];
  const int* src_s = (const int*)d_in[36];
  const int* dst_s = (const int*)d_in[37];
  const int* src_v = (const int*)d_in[38];
  const int* dst_v = (const int*)d_in[39];
  const int* vnr_VNF = (const int*)d_in[40];
  const int* net_VNF = (const int*)d_in[41];

  char* ws = (char*)d_ws;
  size_t off = 0;
  auto alloc = [&](size_t bytes) -> char* {
    off = (off + 255) & ~(size_t)255;
    char* p = ws + off;
    off += bytes;
    return p;
  };
  float* Z    = (float*)alloc((size_t)NS_*H_*4);                 // A1 (f32)
  unsigned short* Zb   = (unsigned short*)alloc((size_t)NS_*H_*2);  // bf16 z for gather
  unsigned short* HsHi = (unsigned short*)alloc((size_t)NS_*H_*2);
  unsigned short* HsLo = (unsigned short*)alloc((size_t)NS_*H_*2);
  float* Zv   = (float*)alloc((size_t)NVT_*H_*4);
  float* Hv   = (float*)alloc((size_t)NVT_*H_*4);
  float* el_s = (float*)alloc((size_t)NS_*4);
  float* er_s = (float*)alloc((size_t)NS_*4);
  float* el_v = (float*)alloc((size_t)NVT_*4);
  float* er_v = (float*)alloc((size_t)NVT_*4);
  size_t zcount = (size_t)NS_ + NS_ + NVT_ + NVT_ + B_*H_;
  char* zb = alloc(zcount*4);
  int*   counts_s = (int*)zb;
  int*   cursor_s = counts_s + NS_;
  int*   counts_v = cursor_s + NS_;
  int*   cursor_v = counts_v + NVT_;
  float* y2buf    = (float*)(cursor_v + NVT_);
  int* rowptr_s = (int*)alloc((size_t)(NS_+1)*4);
  int* rowptr_v = (int*)alloc((size_t)(NVT_+1)*4);
  int* bsum     = (int*)alloc((size_t)256*4);
  int* srcp_s   = (int*)alloc((size_t)EN_*4);
  int* dstp_s   = (int*)alloc((size_t)EN_*4);
  int* srcp_v   = (int*)alloc((size_t)EV_*4);
  int* dstp_v   = (int*)alloc((size_t)EV_*4);
  float* expe_v = (float*)alloc((size_t)EV_*4);
  unsigned short* WS2hi = (unsigned short*)alloc((size_t)H_*H_*2);
  unsigned short* WS2lo = (unsigned short*)alloc((size_t)H_*H_*2);
  unsigned short* WS3hi = (unsigned short*)alloc((size_t)H_*H_*2);
  unsigned short* WS3lo = (unsigned short*)alloc((size_t)H_*H_*2);
  unsigned short* WAhi  = (unsigned short*)alloc((size_t)H_*H_*2);
  unsigned short* WAlo  = (unsigned short*)alloc((size_t)H_*H_*2);
  float* WTih   = (float*)alloc((size_t)H_*384*4);
  float* GI     = (float*)alloc((size_t)NVT_*384*4);
  float* A2     = (float*)alloc((size_t)NV_*B_*H_*4);
  float* y1buf  = (float*)alloc((size_t)B_*H_*4);

  float* pi  = (float*)d_out;
  float* val = pi + (size_t)B_*NV_*NN_;

  hipMemsetAsync(zb, 0, zcount*4, stream);

  // weight re-layouts
  k_transpose<<<(H_*384 + 255)/256, 256, 0, stream>>>(W_ih, 128, H_, 384, WTih);
  k_wsplit<<<64, 256, 0, stream>>>(Ws2, H_, 1, WS2hi, WS2lo);
  k_wsplit<<<64, 256, 0, stream>>>(Ws3, H_, 1, WS3hi, WS3lo);
  k_wsplit<<<64, 256, 0, stream>>>(W_attn, 2*H_, 0, WAhi, WAlo);

  // CSR build (both graphs)
  k_count<<<EN_/256, 256, 0, stream>>>(dst_s, EN_, counts_s);
  k_count<<<EV_/256, 256, 0, stream>>>(dst_v, EV_, counts_v);
  k_scan_local<<<250, 256, 0, stream>>>(counts_s, NS_, rowptr_s, bsum);
  k_scan_bsum<<<1, 256, 0, stream>>>(bsum, 250);
  k_scan_add<<<250, 256, 0, stream>>>(rowptr_s, bsum, NS_, EN_);
  k_scan<<<1, 1024, 0, stream>>>(counts_v, NVT_, rowptr_v);
  k_scatter<<<EN_/256, 256, 0, stream>>>(src_s, dst_s, EN_, rowptr_s, cursor_s, srcp_s, dstp_s);
  k_scatter<<<EV_/256, 256, 0, stream>>>(src_v, dst_v, EV_, rowptr_v, cursor_v, srcp_v, dstp_v);

  dim3 gemmV(NVT_/16, 1);
  int aggS = (NS_ + 3)/4, aggV = (NVT_ + 3)/4;

  // ---- static GAT stack ----
  k_gemm<<<dim3(NS_/16, 1), 256, 0, stream>>>(static_feat, NS_, FS_, H_, Ws1, nullptr,
                                              nullptr, Zb, als1, ars1, el_s, er_s);
  k_aggregate_split<<<aggS, 256, 0, stream>>>(NS_, rowptr_s, srcp_s, el_s, er_s, Zb, bs1, HsHi, HsLo);
  k_mfma_gemm<<<NS_/64, 256, 0, stream>>>(HsHi, HsLo, WS2hi, WS2lo, nullptr, Zb, als2, ars2, el_s, er_s);
  k_aggregate_split<<<aggS, 256, 0, stream>>>(NS_, rowptr_s, srcp_s, el_s, er_s, Zb, bs2, HsHi, HsLo);
  k_mfma_gemm<<<NS_/64, 256, 0, stream>>>(HsHi, HsLo, WS3hi, WS3lo, nullptr, Zb, als3, ars3, el_s, er_s);
  k_aggregate_split<<<aggS, 256, 0, stream>>>(NS_, rowptr_s, srcp_s, el_s, er_s, Zb, bs3, HsHi, HsLo);

  // ---- vnr GAT stack (tiny, f32 path) ----
  k_gemm<<<gemmV, 256, 0, stream>>>(vnr_feat, NVT_, FV_, H_, Wv1, nullptr, Zv, nullptr, alv1, arv1, el_v, er_v);
  k_edge_exp<<<EV_/256, 256, 0, stream>>>(EV_, srcp_v, dstp_v, el_v, er_v, expe_v);
  k_aggregate<<<aggV, 256, 0, stream>>>(NVT_, rowptr_v, srcp_v, expe_v, Zv, bv1, Hv);
  k_gemm<<<gemmV, 256, 0, stream>>>(Hv, NVT_, H_, H_, Wv2, nullptr, Zv, nullptr, alv2, arv2, el_v, er_v);
  k_edge_exp<<<EV_/256, 256, 0, stream>>>(EV_, srcp_v, dstp_v, el_v, er_v, expe_v);
  k_aggregate<<<aggV, 256, 0, stream>>>(NVT_, rowptr_v, srcp_v, expe_v, Zv, bv2, Hv);
  k_gemm<<<gemmV, 256, 0, stream>>>(Hv, NVT_, H_, H_, Wv3, nullptr, Zv, nullptr, alv3, arv3, el_v, er_v);
  k_edge_exp<<<EV_/256, 256, 0, stream>>>(EV_, srcp_v, dstp_v, el_v, er_v, expe_v);
  k_aggregate<<<aggV, 256, 0, stream>>>(NVT_, rowptr_v, srcp_v, expe_v, Zv, bv3, Hv);

  // ---- decoder precomputation ----
  k_gemm<<<dim3(NVT_/16, 3), 256, 0, stream>>>(Hv, NVT_, H_, 384, WTih, b_ih, GI, nullptr,
                                               nullptr, nullptr, nullptr, nullptr);
  k_mfma_gemm<<<NS_/64, 256, 0, stream>>>(HsHi, HsLo, WAhi, WAlo, Z, nullptr,
                                          nullptr, nullptr, nullptr, nullptr);
  k_decoder<<<B_, 512, 0, stream>>>(GI, W_hh, b_hh, W_attn, h0, A2);
  k_attn2<<<dim3(16, B_), 256, 0, stream>>>(Z, A2, v_attn, vnr_VNF, net_VNF, pi);

  // ---- value head ----
  k_y1<<<B_, 128, 0, stream>>>(Hv, nmask, y1buf);
  k_y2s<<<dim3(B_, 8), 128, 0, stream>>>(HsHi, HsLo, y2buf);
  k_value<<<B_, 64, 0, stream>>>(y1buf, y2buf, W_out, b_out, val);
}

// Round 7
// 474.762 us; speedup vs baseline: 2.6703x; 1.0199x over previous
//
#include <hip/hip_runtime.h>
#include <hip/hip_bf16.h>
#include <math.h>

#define B_   64
#define NN_  1000
#define NV_  10
#define H_   128
#define FS_  8
#define FV_  6
#define T_   8
#define O_   64
#define EN_  512000
#define EV_  2560
#define NS_  (B_*NN_)   /* 64000 */
#define NVT_ (B_*NV_)   /* 640 */

typedef __attribute__((ext_vector_type(8))) short short8v;   // 8 bf16
typedef __attribute__((ext_vector_type(4))) float floatx4;

// rcp-based fast math: v_rcp_f32 (~1 ulp) instead of the ~10-instr exact divide
__device__ __forceinline__ float fast_rcp(float x) { return __builtin_amdgcn_rcpf(x); }
__device__ __forceinline__ float fast_tanh(float x) {
  return 1.f - 2.f*fast_rcp(1.f + __expf(2.f*x));
}
__device__ __forceinline__ float fast_sigmoid(float x) {
  return fast_rcp(1.f + __expf(-x));
}
__device__ __forceinline__ unsigned short bf16_rne(float x) {
  unsigned u = __float_as_uint(x);
  return (unsigned short)((u + 0x7FFFu + ((u >> 16) & 1u)) >> 16);
}
__device__ __forceinline__ float bf16_tof(unsigned short b) {
  return __uint_as_float(((unsigned)b) << 16);
}
__device__ __forceinline__ float dot4(float4 a, float4 b) {
  return a.x*b.x + a.y*b.y + a.z*b.z + a.w*b.w;
}
__device__ __forceinline__ float lrelu02(float e) {
  return (e > 0.f) ? e : 0.2f*e;
}

// ---------- CSR build ----------
__global__ __launch_bounds__(256) void k_count(const int* dst, int E, int* counts) {
  int i = blockIdx.x*256 + threadIdx.x;
  if (i < E) atomicAdd(&counts[dst[i]], 1);
}

__global__ __launch_bounds__(1024) void k_scan(const int* cnt, int n, int* rowptr) {
  __shared__ int sums[1024];
  int t = threadIdx.x;
  int v = (t < n) ? cnt[t] : 0;
  sums[t] = v;
  __syncthreads();
  for (int offd = 1; offd < 1024; offd <<= 1) {
    int u = (t >= offd) ? sums[t-offd] : 0;
    __syncthreads();
    sums[t] += u;
    __syncthreads();
  }
  if (t < n) rowptr[t] = sums[t] - v;
  if (t == n-1) rowptr[n] = sums[t];
}

__global__ __launch_bounds__(256) void k_scan_local(const int* cnt, int n, int* out, int* bsum) {
  __shared__ int s[256];
  int t = threadIdx.x; int i = blockIdx.x*256 + t;
  int v = (i < n) ? cnt[i] : 0;
  s[t] = v; __syncthreads();
  #pragma unroll
  for (int o = 1; o < 256; o <<= 1) {
    int u = (t >= o) ? s[t-o] : 0; __syncthreads();
    s[t] += u; __syncthreads();
  }
  if (i < n) out[i] = s[t] - v;
  if (t == 255) bsum[blockIdx.x] = s[255];
}

__global__ __launch_bounds__(256) void k_scan_bsum(int* bsum, int nb) {
  __shared__ int s[256];
  int t = threadIdx.x;
  int v = (t < nb) ? bsum[t] : 0;
  s[t] = v; __syncthreads();
  #pragma unroll
  for (int o = 1; o < 256; o <<= 1) {
    int u = (t >= o) ? s[t-o] : 0; __syncthreads();
    s[t] += u; __syncthreads();
  }
  if (t < nb) bsum[t] = s[t] - v;
}

__global__ __launch_bounds__(256) void k_scan_add(int* out, const int* bsum, int n, int E) {
  int i = blockIdx.x*256 + threadIdx.x;
  if (i < n) out[i] += bsum[blockIdx.x];
  if (i == 0) out[n] = E;
}

__global__ __launch_bounds__(256) void k_scatter(const int* src, const int* dst, int E,
                                                 const int* rowptr, int* cursor,
                                                 int* srcp, int* dstp) {
  int i = blockIdx.x*256 + threadIdx.x;
  if (i >= E) return;
  int d = dst[i];
  int pos = rowptr[d] + atomicAdd(&cursor[d], 1);
  srcp[pos] = src[i];
  dstp[pos] = d;
}

// ---------- vnr-path GAT pieces (f32, tiny graphs) ----------
__global__ __launch_bounds__(256) void k_edge_exp(int E, const int* srcp, const int* dstp,
                                                  const float* el, const float* er, float* expe) {
  int i = blockIdx.x*256 + threadIdx.x;
  if (i >= E) return;
  float e = el[srcp[i]] + er[dstp[i]];
  e = (e > 0.f) ? e : 0.2f*e;
  expe[i] = __expf(e);
}

__global__ __launch_bounds__(256) void k_aggregate(int nNodes, const int* rowptr,
                                                   const int* srcp, const float* expe,
                                                   const float* z, const float* bias, float* out) {
  int w = (blockIdx.x*256 + threadIdx.x) >> 6;
  int lane = threadIdx.x & 63;
  if (w >= nNodes) return;
  int beg = rowptr[w], end = rowptr[w+1];
  float a0 = 0.f, a1 = 0.f, wsum = 0.f;
  for (int i = beg; i < end; ++i) {
    int sI = srcp[i];
    float wt = expe[i];
    float2 zz = *(const float2*)(z + (size_t)sI*H_ + lane*2);
    a0 += wt*zz.x; a1 += wt*zz.y; wsum += wt;
  }
  float inv = (end > beg) ? fast_rcp(wsum) : 0.f;
  float2 o;
  o.x = a0*inv + bias[lane*2];
  o.y = a1*inv + bias[lane*2 + 1];
  *(float2*)(out + (size_t)w*H_ + lane*2) = o;
}

// ---------- static-path aggregate: bf16 z gather, 8x pipelined, split-bf16 out ----------
__global__ __launch_bounds__(256) void k_aggregate_split(int nNodes, const int* __restrict__ rowptr,
    const int* __restrict__ srcp, const float* __restrict__ el, const float* __restrict__ er,
    const unsigned short* __restrict__ z, const float* __restrict__ bias,
    unsigned short* __restrict__ outHi, unsigned short* __restrict__ outLo) {
  int w = (blockIdx.x*256 + threadIdx.x) >> 6;
  int lane = threadIdx.x & 63;
  if (w >= nNodes) return;
  int beg = rowptr[w], end = rowptr[w+1];
  float erw = er[w];
  float a0 = 0.f, a1 = 0.f, wsum = 0.f;
  int i = beg;
  // 8x unroll: avg degree is 8 -> most nodes complete in one batch, 8 rows in flight
  for (; i + 8 <= end; i += 8) {
    int sI[8]; float lv[8]; ushort2 q[8];
    #pragma unroll
    for (int u = 0; u < 8; ++u) sI[u] = srcp[i+u];
    #pragma unroll
    for (int u = 0; u < 8; ++u) lv[u] = el[sI[u]];
    #pragma unroll
    for (int u = 0; u < 8; ++u) q[u] = *(const ushort2*)(z + (size_t)sI[u]*H_ + lane*2);
    #pragma unroll
    for (int u = 0; u < 8; ++u) {
      float wt = __expf(lrelu02(lv[u] + erw));
      a0 += wt*bf16_tof(q[u].x);
      a1 += wt*bf16_tof(q[u].y);
      wsum += wt;
    }
  }
  for (; i < end; ++i) {
    int sI = srcp[i];
    float wt = __expf(lrelu02(el[sI] + erw));
    ushort2 q = *(const ushort2*)(z + (size_t)sI*H_ + lane*2);
    a0 += wt*bf16_tof(q.x); a1 += wt*bf16_tof(q.y); wsum += wt;
  }
  float inv = (end > beg) ? fast_rcp(wsum) : 0.f;
  float o0 = a0*inv + bias[lane*2];
  float o1 = a1*inv + bias[lane*2 + 1];
  unsigned short h0 = bf16_rne(o0), h1 = bf16_rne(o1);
  unsigned short l0 = bf16_rne(o0 - bf16_tof(h0)), l1 = bf16_rne(o1 - bf16_tof(h1));
  ushort2 hv; hv.x = h0; hv.y = h1;
  ushort2 lv; lv.x = l0; lv.y = l1;
  *(ushort2*)(outHi + (size_t)w*H_ + lane*2) = hv;
  *(ushort2*)(outLo + (size_t)w*H_ + lane*2) = lv;
}

// ---------- weight split (+optional transpose): out[j][k] (hi,lo bf16) ----------
__global__ __launch_bounds__(256) void k_wsplit(const float* in, int ld, int trans,
                                                unsigned short* hi, unsigned short* lo) {
  int idx = blockIdx.x*256 + threadIdx.x;
  if (idx >= H_*H_) return;
  int j = idx >> 7, k = idx & 127;
  float v = trans ? in[(size_t)k*ld + j] : in[(size_t)j*ld + k];
  unsigned short h = bf16_rne(v);
  unsigned short l = bf16_rne(v - bf16_tof(h));
  hi[idx] = h; lo[idx] = l;
}

// ---------- MFMA split-bf16 GEMM: C/Cb[M,128] = (Ahi+Alo)@(Whi+Wlo), WT[col][k] ----------
__global__ __launch_bounds__(256) void k_mfma_gemm(
    const unsigned short* __restrict__ Ahi, const unsigned short* __restrict__ Alo,
    const unsigned short* __restrict__ WThi, const unsigned short* __restrict__ WTlo,
    float* __restrict__ C, unsigned short* __restrict__ Cb,
    const float* __restrict__ al, const float* __restrict__ ar,
    float* __restrict__ el, float* __restrict__ er) {
  __shared__ unsigned short lAhi[64*136];
  __shared__ unsigned short lAlo[64*136];
  __shared__ float redl[4][64];
  __shared__ float redr[4][64];
  int t = threadIdx.x;
  int row0 = blockIdx.x * 64;
  int wid = t >> 6, lane = t & 63;
  int g = lane >> 4, c = lane & 15;

  #pragma unroll
  for (int i = 0; i < 4; ++i) {
    int m = t + 256*i;
    int r = m >> 4;
    int kc = (m & 15) * 8;
    *(short8v*)(lAhi + r*136 + kc) = *(const short8v*)(Ahi + (size_t)(row0 + r)*H_ + kc);
    *(short8v*)(lAlo + r*136 + kc) = *(const short8v*)(Alo + (size_t)(row0 + r)*H_ + kc);
  }

  short8v bhi[2][4], blo[2][4];
  #pragma unroll
  for (int ct = 0; ct < 2; ++ct) {
    int col = wid*32 + ct*16 + c;
    #pragma unroll
    for (int kb = 0; kb < 4; ++kb) {
      size_t o = (size_t)col*H_ + kb*32 + g*8;
      bhi[ct][kb] = *(const short8v*)(WThi + o);
      blo[ct][kb] = *(const short8v*)(WTlo + o);
    }
  }

  floatx4 acc[4][2];
  #pragma unroll
  for (int rt = 0; rt < 4; ++rt)
    #pragma unroll
    for (int ct = 0; ct < 2; ++ct)
      acc[rt][ct] = (floatx4){0.f, 0.f, 0.f, 0.f};

  __syncthreads();

  #pragma unroll
  for (int kb = 0; kb < 4; ++kb) {
    short8v ahi[4], alo[4];
    #pragma unroll
    for (int rt = 0; rt < 4; ++rt) {
      int r = rt*16 + c;
      ahi[rt] = *(const short8v*)(lAhi + r*136 + kb*32 + g*8);
      alo[rt] = *(const short8v*)(lAlo + r*136 + kb*32 + g*8);
    }
    #pragma unroll
    for (int rt = 0; rt < 4; ++rt)
      #pragma unroll
      for (int ct = 0; ct < 2; ++ct) {
        acc[rt][ct] = __builtin_amdgcn_mfma_f32_16x16x32_bf16(ahi[rt], bhi[ct][kb], acc[rt][ct], 0, 0, 0);
        acc[rt][ct] = __builtin_amdgcn_mfma_f32_16x16x32_bf16(alo[rt], bhi[ct][kb], acc[rt][ct], 0, 0, 0);
        acc[rt][ct] = __builtin_amdgcn_mfma_f32_16x16x32_bf16(ahi[rt], blo[ct][kb], acc[rt][ct], 0, 0, 0);
      }
  }

  #pragma unroll
  for (int rt = 0; rt < 4; ++rt)
    #pragma unroll
    for (int i = 0; i < 4; ++i) {
      int row = row0 + rt*16 + g*4 + i;
      if (Cb) {
        unsigned short* cr = Cb + (size_t)row*H_ + wid*32;
        cr[c]      = bf16_rne(acc[rt][0][i]);
        cr[16 + c] = bf16_rne(acc[rt][1][i]);
      } else {
        float* cr = C + (size_t)row*H_ + wid*32;
        cr[c]      = acc[rt][0][i];
        cr[16 + c] = acc[rt][1][i];
      }
    }

  if (el) {
    float av0 = al[wid*32 + c], av1 = al[wid*32 + 16 + c];
    float rv0 = ar[wid*32 + c], rv1 = ar[wid*32 + 16 + c];
    #pragma unroll
    for (int rt = 0; rt < 4; ++rt)
      #pragma unroll
      for (int i = 0; i < 4; ++i) {
        float pl = acc[rt][0][i]*av0 + acc[rt][1][i]*av1;
        float pr = acc[rt][0][i]*rv0 + acc[rt][1][i]*rv1;
        pl += __shfl_xor(pl, 1, 64); pl += __shfl_xor(pl, 2, 64);
        pl += __shfl_xor(pl, 4, 64); pl += __shfl_xor(pl, 8, 64);
        pr += __shfl_xor(pr, 1, 64); pr += __shfl_xor(pr, 2, 64);
        pr += __shfl_xor(pr, 4, 64); pr += __shfl_xor(pr, 8, 64);
        if (c == 0) { redl[wid][rt*16 + g*4 + i] = pl; redr[wid][rt*16 + g*4 + i] = pr; }
      }
    __syncthreads();
    if (t < 64) {
      el[row0 + t] = redl[0][t] + redl[1][t] + redl[2][t] + redl[3][t];
      er[row0 + t] = redr[0][t] + redr[1][t] + redr[2][t] + redr[3][t];
    }
  }
}

// ---------- generic f32 GEMM (layer-1 K=8 + tiny vnr/GI GEMMs) ----------
__global__ __launch_bounds__(256) void k_gemm(const float* A, int M, int K, int N,
                                              const float* W, const float* bias,
                                              float* C, unsigned short* Cb,
                                              const float* al, const float* ar,
                                              float* el, float* er) {
  __shared__ float Ws_[64*128];
  __shared__ float As_[16*128];
  __shared__ float redl[16][17];
  __shared__ float redr[16][17];
  int t = threadIdx.x;
  int j0 = blockIdx.y * 128;
  int row0 = blockIdx.x * 16;
  for (int l = t; l < 16*K; l += 256) {
    int r = l / K, k = l - r*K;
    int row = row0 + r;
    As_[r*K + k] = (row < M) ? A[(size_t)row*K + k] : 0.f;
  }
  int jg = t & 15, r = t >> 4;
  float acc[8];
  #pragma unroll
  for (int q = 0; q < 8; ++q) acc[q] = 0.f;
  for (int kc = 0; kc < K; kc += 64) {
    int kl = min(64, K - kc);
    __syncthreads();
    for (int l = t; l < (kl << 7); l += 256) {
      int k = l >> 7, j = l & 127;
      int jj = j0 + j;
      Ws_[l] = (jj < N) ? W[(size_t)(kc + k)*N + jj] : 0.f;
    }
    __syncthreads();
    for (int k = 0; k < kl; ++k) {
      float a = As_[r*K + kc + k];
      const float* wr = &Ws_[(k << 7) + jg*8];
      #pragma unroll
      for (int q = 0; q < 8; ++q) acc[q] += a * wr[q];
    }
  }
  int row = row0 + r;
  if (row < M) {
    if (Cb) {
      unsigned short* crow = Cb + (size_t)row*N + j0 + jg*8;
      #pragma unroll
      for (int q = 0; q < 8; ++q) {
        int j = j0 + jg*8 + q;
        if (j < N) crow[q] = bf16_rne(acc[q] + (bias ? bias[j] : 0.f));
      }
    } else {
      float* crow = C + (size_t)row*N + j0 + jg*8;
      #pragma unroll
      for (int q = 0; q < 8; ++q) {
        int j = j0 + jg*8 + q;
        if (j < N) crow[q] = acc[q] + (bias ? bias[j] : 0.f);
      }
    }
  }
  if (el) {
    float pl = 0.f, pr = 0.f;
    #pragma unroll
    for (int q = 0; q < 8; ++q) {
      int j = jg*8 + q;
      pl += acc[q]*al[j];
      pr += acc[q]*ar[j];
    }
    redl[r][jg] = pl; redr[r][jg] = pr;
    __syncthreads();
    if (t < 16) {
      float sl = 0.f, sr = 0.f;
      for (int q = 0; q < 16; ++q) { sl += redl[t][q]; sr += redr[t][q]; }
      int row2 = row0 + t;
      if (row2 < M) { el[row2] = sl; er[row2] = sr; }
    }
  }
}

// ---------- small transpose for weight re-layout ----------
__global__ __launch_bounds__(256) void k_transpose(const float* in, int inStride,
                                                   int K, int J, float* out) {
  int idx = blockIdx.x*256 + threadIdx.x;
  if (idx >= K*J) return;
  int k = idx / J, j = idx - k*J;
  out[idx] = in[(size_t)j*inStride + k];
}

// ---------- GRU decoder v3: weights register-resident, LDS-broadcast h ----------
__global__ __launch_bounds__(512) void k_decoder(const float* __restrict__ GI,
                                                 const float* __restrict__ W_hh,
                                                 const float* __restrict__ b_hh,
                                                 const float* __restrict__ W_attn,
                                                 const float* __restrict__ h0,
                                                 float* __restrict__ A2) {
  int b = blockIdx.x;
  __shared__ float h[128];
  __shared__ float gh[384];
  int t = threadIdx.x;
  const float4* wsrc = (t < 384)
      ? (const float4*)(W_hh + (size_t)t*128)
      : (const float4*)(W_attn + (size_t)(t-384)*256 + 128);
  float4 wreg[32];
  #pragma unroll
  for (int kk = 0; kk < 32; ++kk) wreg[kk] = wsrc[kk];
  float bh = (t < 384) ? b_hh[t] : 0.f;
  if (t < 128) h[t] = h0[t];
  __syncthreads();
  for (int s = 0; s < 10; ++s) {
    const float4* h4 = (const float4*)h;
    if (t < 384) {
      float a0 = 0.f, a1 = 0.f, a2 = 0.f, a3 = 0.f;
      #pragma unroll
      for (int kk = 0; kk < 32; kk += 4) {
        a0 += dot4(wreg[kk+0], h4[kk+0]);
        a1 += dot4(wreg[kk+1], h4[kk+1]);
        a2 += dot4(wreg[kk+2], h4[kk+2]);
        a3 += dot4(wreg[kk+3], h4[kk+3]);
      }
      gh[t] = (a0 + a1) + (a2 + a3) + bh;
    }
    __syncthreads();
    if (t < 128) {
      const float* gi = GI + (size_t)(b*NV_ + s)*384;
      float rr = fast_sigmoid(gi[t]       + gh[t]);
      float zz = fast_sigmoid(gi[128 + t] + gh[128 + t]);
      float nn = fast_tanh   (gi[256 + t] + rr*gh[256 + t]);
      h[t] = (1.f - zz)*nn + zz*h[t];
    }
    __syncthreads();
    if (t >= 384) {
      float a0 = 0.f, a1 = 0.f, a2 = 0.f, a3 = 0.f;
      #pragma unroll
      for (int kk = 0; kk < 32; kk += 4) {
        a0 += dot4(wreg[kk+0], h4[kk+0]);
        a1 += dot4(wreg[kk+1], h4[kk+1]);
        a2 += dot4(wreg[kk+2], h4[kk+2]);
        a3 += dot4(wreg[kk+3], h4[kk+3]);
      }
      A2[((size_t)s*B_ + b)*128 + (t - 384)] = (a0 + a1) + (a2 + a3);
    }
  }
}

// ---------- attention score + mask v3: rcp-form tanh, v in regs ----------
// sum_h v*tanh(a1+a2) = vsum - sum_h (2v)*rcp(1 + exp(2a1+2a2)).
// A1/A2 pre-scaled by 2; per element: add, exp, add, rcp, fma (2 trans + 3 VALU).
__global__ __launch_bounds__(256) void k_attn3(const float* __restrict__ A1,
                                               const float* __restrict__ A2,
                                               const float* __restrict__ v_attn,
                                               const int* __restrict__ vnr_VNF,
                                               const int* __restrict__ net_VNF,
                                               float* __restrict__ pi) {
  __shared__ float a2s[10][128];   // 2*A2
  __shared__ float vv2s[128];      // 2*v
  int b = blockIdx.y;
  int t = threadIdx.x;
  for (int i = t; i < 1280; i += 256) {
    int s = i >> 7, k = i & 127;
    a2s[s][k] = 2.f*A2[((size_t)s*B_ + b)*H_ + k];
  }
  if (t < 128) vv2s[t] = 2.f*v_attn[t];
  __syncthreads();
  int nl = t >> 2, p = t & 3;
  int n = blockIdx.x*64 + nl;
  if (n >= NN_) return;
  size_t g = (size_t)b*NN_ + n;
  const float4* arow = (const float4*)(A1 + g*H_ + p*32);
  float4 a[8], w2[8];
  #pragma unroll
  for (int kk = 0; kk < 8; ++kk) {
    float4 av = arow[kk];
    a[kk] = make_float4(2.f*av.x, 2.f*av.y, 2.f*av.z, 2.f*av.w);
    w2[kk] = *(const float4*)(&vv2s[p*32 + kk*4]);
  }
  float vsum = 0.f;
  #pragma unroll
  for (int kk = 0; kk < 8; ++kk)
    vsum += (w2[kk].x + w2[kk].y) + (w2[kk].z + w2[kk].w);
  vsum *= 0.5f;
  float acc[10];
  #pragma unroll
  for (int s = 0; s < 10; ++s) {
    const float* a2r = &a2s[s][p*32];
    float sum2 = 0.f;
    #pragma unroll
    for (int kk = 0; kk < 8; ++kk) {
      float4 c = *(const float4*)(a2r + kk*4);
      sum2 = fmaf(w2[kk].x, fast_rcp(1.f + __expf(a[kk].x + c.x)), sum2);
      sum2 = fmaf(w2[kk].y, fast_rcp(1.f + __expf(a[kk].y + c.y)), sum2);
      sum2 = fmaf(w2[kk].z, fast_rcp(1.f + __expf(a[kk].z + c.z)), sum2);
      sum2 = fmaf(w2[kk].w, fast_rcp(1.f + __expf(a[kk].w + c.w)), sum2);
    }
    acc[s] = vsum - sum2;
  }
  #pragma unroll
  for (int s = 0; s < 10; ++s) {
    acc[s] += __shfl_xor(acc[s], 1, 64);
    acc[s] += __shfl_xor(acc[s], 2, 64);
  }
  if (p == 0) {
    #pragma unroll
    for (int s = 0; s < 10; ++s) {
      int vnf = vnr_VNF[b*NV_ + s];
      int m   = net_VNF[g*T_ + vnf];
      pi[(size_t)b*(NV_*NN_) + (size_t)s*NN_ + n] = acc[s] + __logf((float)m);
    }
  }
}

// ---------- value head ----------
__global__ __launch_bounds__(128) void k_y1(const float* Hv, const float* nmask, float* y1) {
  int b = blockIdx.x, h = threadIdx.x;
  float s = 0.f, d = 0.f;
  for (int i = 0; i < NV_; ++i) {
    float m = nmask[b*NV_ + i];
    s += Hv[(size_t)(b*NV_ + i)*H_ + h]*m;
    d += m;
  }
  y1[b*H_ + h] = s/d;
}

__global__ __launch_bounds__(128) void k_y2s(const unsigned short* hi, const unsigned short* lo,
                                             float* y2) {
  int b = blockIdx.x, slice = blockIdx.y, h = threadIdx.x;
  int n0 = slice*125, n1 = n0 + 125;
  float s = 0.f;
  for (int n = n0; n < n1; ++n) {
    size_t idx = ((size_t)b*NN_ + n)*H_ + h;
    s += bf16_tof(hi[idx]) + bf16_tof(lo[idx]);
  }
  atomicAdd(&y2[b*H_ + h], s);
}

__global__ __launch_bounds__(64) void k_value(const float* y1, const float* y2,
                                              const float* W_out, const float* b_out,
                                              float* val) {
  int b = blockIdx.x, o = threadIdx.x;
  const float* w = W_out + (size_t)o*256;
  float s = b_out[o];
  for (int h = 0; h < H_; ++h)
    s += y1[b*H_ + h]*w[h] + (y2[b*H_ + h]*(1.f/1000.f))*w[128 + h];
  val[b*O_ + o] = s;
}

extern "C" void kernel_launch(void* const* d_in, const int* in_sizes, int n_in,
                              void* d_out, int out_size, void* d_ws, size_t ws_size,
                              hipStream_t stream) {
  (void)in_sizes; (void)n_in; (void)out_size; (void)ws_size;
  const float* static_feat = (const float*)d_in[0];
  const float* vnr_feat    = (const float*)d_in[1];
  const float* nmask       = (const float*)d_in[2];
  const float* Ws1 = (const float*)d_in[3];  const float* als1 = (const float*)d_in[4];
  const float* ars1 = (const float*)d_in[5]; const float* bs1 = (const float*)d_in[6];
  const float* Ws2 = (const float*)d_in[7];  const float* als2 = (const float*)d_in[8];
  const float* ars2 = (const float*)d_in[9]; const float* bs2 = (const float*)d_in[10];
  const float* Ws3 = (const float*)d_in[11]; const float* als3 = (const float*)d_in[12];
  const float* ars3 = (const float*)d_in[13]; const float* bs3 = (const float*)d_in[14];
  const float* Wv1 = (const float*)d_in[15]; const float* alv1 = (const float*)d_in[16];
  const float* arv1 = (const float*)d_in[17]; const float* bv1 = (const float*)d_in[18];
  const float* Wv2 = (const float*)d_in[19]; const float* alv2 = (const float*)d_in[20];
  const float* arv2 = (const float*)d_in[21]; const float* bv2 = (const float*)d_in[22];
  const float* Wv3 = (const float*)d_in[23]; const float* alv3 = (const float*)d_in[24];
  const float* arv3 = (const float*)d_in[25]; const float* bv3 = (const float*)d_in[26];
  const float* W_attn = (const float*)d_in[27];
  const float* v_attn = (const float*)d_in[28];
  const float* W_ih = (const float*)d_in[29];
  const float* W_hh = (const float*)d_in[30];
  const float* b_ih = (const float*)d_in[31];
  const float* b_hh = (const float*)d_in[32];
  const float* h0   = (const float*)d_in[33];
  const float* W_out = (const float*)d_in[34];
  const float* b_out = (const float*)d_in[35];
  const int* src_s = (const int*)d_in[36];
  const int* dst_s = (const int*)d_in[37];
  const int* src_v = (const int*)d_in[38];
  const int* dst_v = (const int*)d_in[39];
  const int* vnr_VNF = (const int*)d_in[40];
  const int* net_VNF = (const int*)d_in[41];

  char* ws = (char*)d_ws;
  size_t off = 0;
  auto alloc = [&](size_t bytes) -> char* {
    off = (off + 255) & ~(size_t)255;
    char* p = ws + off;
    off += bytes;
    return p;
  };
  float* Z    = (float*)alloc((size_t)NS_*H_*4);                 // A1 (f32)
  unsigned short* Zb   = (unsigned short*)alloc((size_t)NS_*H_*2);  // bf16 z for gather
  unsigned short* HsHi = (unsigned short*)alloc((size_t)NS_*H_*2);
  unsigned short* HsLo = (unsigned short*)alloc((size_t)NS_*H_*2);
  float* Zv   = (float*)alloc((size_t)NVT_*H_*4);
  float* Hv   = (float*)alloc((size_t)NVT_*H_*4);
  float* el_s = (float*)alloc((size_t)NS_*4);
  float* er_s = (float*)alloc((size_t)NS_*4);
  float* el_v = (float*)alloc((size_t)NVT_*4);
  float* er_v = (float*)alloc((size_t)NVT_*4);
  size_t zcount = (size_t)NS_ + NS_ + NVT_ + NVT_ + B_*H_;
  char* zb = alloc(zcount*4);
  int*   counts_s = (int*)zb;
  int*   cursor_s = counts_s + NS_;
  int*   counts_v = cursor_s + NS_;
  int*   cursor_v = counts_v + NVT_;
  float* y2buf    = (float*)(cursor_v + NVT_);
  int* rowptr_s = (int*)alloc((size_t)(NS_+1)*4);
  int* rowptr_v = (int*)alloc((size_t)(NVT_+1)*4);
  int* bsum     = (int*)alloc((size_t)256*4);
  int* srcp_s   = (int*)alloc((size_t)EN_*4);
  int* dstp_s   = (int*)alloc((size_t)EN_*4);
  int* srcp_v   = (int*)alloc((size_t)EV_*4);
  int* dstp_v   = (int*)alloc((size_t)EV_*4);
  float* expe_v = (float*)alloc((size_t)EV_*4);
  unsigned short* WS2hi = (unsigned short*)alloc((size_t)H_*H_*2);
  unsigned short* WS2lo = (unsigned short*)alloc((size_t)H_*H_*2);
  unsigned short* WS3hi = (unsigned short*)alloc((size_t)H_*H_*2);
  unsigned short* WS3lo = (unsigned short*)alloc((size_t)H_*H_*2);
  unsigned short* WAhi  = (unsigned short*)alloc((size_t)H_*H_*2);
  unsigned short* WAlo  = (unsigned short*)alloc((size_t)H_*H_*2);
  float* WTih   = (float*)alloc((size_t)H_*384*4);
  float* GI     = (float*)alloc((size_t)NVT_*384*4);
  float* A2     = (float*)alloc((size_t)NV_*B_*H_*4);
  float* y1buf  = (float*)alloc((size_t)B_*H_*4);

  float* pi  = (float*)d_out;
  float* val = pi + (size_t)B_*NV_*NN_;

  hipMemsetAsync(zb, 0, zcount*4, stream);

  // weight re-layouts
  k_transpose<<<(H_*384 + 255)/256, 256, 0, stream>>>(W_ih, 128, H_, 384, WTih);
  k_wsplit<<<64, 256, 0, stream>>>(Ws2, H_, 1, WS2hi, WS2lo);
  k_wsplit<<<64, 256, 0, stream>>>(Ws3, H_, 1, WS3hi, WS3lo);
  k_wsplit<<<64, 256, 0, stream>>>(W_attn, 2*H_, 0, WAhi, WAlo);

  // CSR build (both graphs)
  k_count<<<EN_/256, 256, 0, stream>>>(dst_s, EN_, counts_s);
  k_count<<<EV_/256, 256, 0, stream>>>(dst_v, EV_, counts_v);
  k_scan_local<<<250, 256, 0, stream>>>(counts_s, NS_, rowptr_s, bsum);
  k_scan_bsum<<<1, 256, 0, stream>>>(bsum, 250);
  k_scan_add<<<250, 256, 0, stream>>>(rowptr_s, bsum, NS_, EN_);
  k_scan<<<1, 1024, 0, stream>>>(counts_v, NVT_, rowptr_v);
  k_scatter<<<EN_/256, 256, 0, stream>>>(src_s, dst_s, EN_, rowptr_s, cursor_s, srcp_s, dstp_s);
  k_scatter<<<EV_/256, 256, 0, stream>>>(src_v, dst_v, EV_, rowptr_v, cursor_v, srcp_v, dstp_v);

  dim3 gemmV(NVT_/16, 1);
  int aggS = (NS_ + 3)/4, aggV = (NVT_ + 3)/4;

  // ---- static GAT stack ----
  k_gemm<<<dim3(NS_/16, 1), 256, 0, stream>>>(static_feat, NS_, FS_, H_, Ws1, nullptr,
                                              nullptr, Zb, als1, ars1, el_s, er_s);
  k_aggregate_split<<<aggS, 256, 0, stream>>>(NS_, rowptr_s, srcp_s, el_s, er_s, Zb, bs1, HsHi, HsLo);
  k_mfma_gemm<<<NS_/64, 256, 0, stream>>>(HsHi, HsLo, WS2hi, WS2lo, nullptr, Zb, als2, ars2, el_s, er_s);
  k_aggregate_split<<<aggS, 256, 0, stream>>>(NS_, rowptr_s, srcp_s, el_s, er_s, Zb, bs2, HsHi, HsLo);
  k_mfma_gemm<<<NS_/64, 256, 0, stream>>>(HsHi, HsLo, WS3hi, WS3lo, nullptr, Zb, als3, ars3, el_s, er_s);
  k_aggregate_split<<<aggS, 256, 0, stream>>>(NS_, rowptr_s, srcp_s, el_s, er_s, Zb, bs3, HsHi, HsLo);

  // ---- vnr GAT stack (tiny, f32 path) ----
  k_gemm<<<gemmV, 256, 0, stream>>>(vnr_feat, NVT_, FV_, H_, Wv1, nullptr, Zv, nullptr, alv1, arv1, el_v, er_v);
  k_edge_exp<<<EV_/256, 256, 0, stream>>>(EV_, srcp_v, dstp_v, el_v, er_v, expe_v);
  k_aggregate<<<aggV, 256, 0, stream>>>(NVT_, rowptr_v, srcp_v, expe_v, Zv, bv1, Hv);
  k_gemm<<<gemmV, 256, 0, stream>>>(Hv, NVT_, H_, H_, Wv2, nullptr, Zv, nullptr, alv2, arv2, el_v, er_v);
  k_edge_exp<<<EV_/256, 256, 0, stream>>>(EV_, srcp_v, dstp_v, el_v, er_v, expe_v);
  k_aggregate<<<aggV, 256, 0, stream>>>(NVT_, rowptr_v, srcp_v, expe_v, Zv, bv2, Hv);
  k_gemm<<<gemmV, 256, 0, stream>>>(Hv, NVT_, H_, H_, Wv3, nullptr, Zv, nullptr, alv3, arv3, el_v, er_v);
  k_edge_exp<<<EV_/256, 256, 0, stream>>>(EV_, srcp_v, dstp_v, el_v, er_v, expe_v);
  k_aggregate<<<aggV, 256, 0, stream>>>(NVT_, rowptr_v, srcp_v, expe_v, Zv, bv3, Hv);

  // ---- decoder precomputation ----
  k_gemm<<<dim3(NVT_/16, 3), 256, 0, stream>>>(Hv, NVT_, H_, 384, WTih, b_ih, GI, nullptr,
                                               nullptr, nullptr, nullptr, nullptr);
  k_mfma_gemm<<<NS_/64, 256, 0, stream>>>(HsHi, HsLo, WAhi, WAlo, Z, nullptr,
                                          nullptr, nullptr, nullptr, nullptr);
  k_decoder<<<B_, 512, 0, stream>>>(GI, W_hh, b_hh, W_attn, h0, A2);
  k_attn3<<<dim3(16, B_), 256, 0, stream>>>(Z, A2, v_attn, vnr_VNF, net_VNF, pi);

  // ---- value head ----
  k_y1<<<B_, 128, 0, stream>>>(Hv, nmask, y1buf);
  k_y2s<<<dim3(B_, 8), 128, 0, stream>>>(HsHi, HsLo, y2buf);
  k_value<<<B_, 64, 0, stream>>>(y1buf, y2buf, W_out, b_out, val);
}

// Round 8
// 448.840 us; speedup vs baseline: 2.8246x; 1.0578x over previous
//
#include <hip/hip_runtime.h>
#include <hip/hip_bf16.h>
#include <math.h>

#define B_   64
#define NN_  1000
#define NV_  10
#define H_   128
#define FS_  8
#define FV_  6
#define T_   8
#define O_   64
#define EN_  512000
#define EV_  2560
#define NS_  (B_*NN_)   /* 64000 */
#define NVT_ (B_*NV_)   /* 640 */

typedef __attribute__((ext_vector_type(8))) short short8v;   // 8 bf16
typedef __attribute__((ext_vector_type(4))) float floatx4;

// rcp-based fast math: v_rcp_f32 (~1 ulp) instead of the ~10-instr exact divide
__device__ __forceinline__ float fast_rcp(float x) { return __builtin_amdgcn_rcpf(x); }
__device__ __forceinline__ float fast_tanh(float x) {
  return 1.f - 2.f*fast_rcp(1.f + __expf(2.f*x));
}
__device__ __forceinline__ float fast_sigmoid(float x) {
  return fast_rcp(1.f + __expf(-x));
}
__device__ __forceinline__ unsigned short bf16_rne(float x) {
  unsigned u = __float_as_uint(x);
  return (unsigned short)((u + 0x7FFFu + ((u >> 16) & 1u)) >> 16);
}
__device__ __forceinline__ float bf16_tof(unsigned short b) {
  return __uint_as_float(((unsigned)b) << 16);
}
__device__ __forceinline__ float dot4(float4 a, float4 b) {
  return a.x*b.x + a.y*b.y + a.z*b.z + a.w*b.w;
}
__device__ __forceinline__ float lrelu02(float e) {
  return (e > 0.f) ? e : 0.2f*e;
}

// ---------- CSR build ----------
__global__ __launch_bounds__(256) void k_count(const int* dst, int E, int* counts) {
  int i = blockIdx.x*256 + threadIdx.x;
  if (i < E) atomicAdd(&counts[dst[i]], 1);
}

__global__ __launch_bounds__(1024) void k_scan(const int* cnt, int n, int* rowptr) {
  __shared__ int sums[1024];
  int t = threadIdx.x;
  int v = (t < n) ? cnt[t] : 0;
  sums[t] = v;
  __syncthreads();
  for (int offd = 1; offd < 1024; offd <<= 1) {
    int u = (t >= offd) ? sums[t-offd] : 0;
    __syncthreads();
    sums[t] += u;
    __syncthreads();
  }
  if (t < n) rowptr[t] = sums[t] - v;
  if (t == n-1) rowptr[n] = sums[t];
}

__global__ __launch_bounds__(256) void k_scan_local(const int* cnt, int n, int* out, int* bsum) {
  __shared__ int s[256];
  int t = threadIdx.x; int i = blockIdx.x*256 + t;
  int v = (i < n) ? cnt[i] : 0;
  s[t] = v; __syncthreads();
  #pragma unroll
  for (int o = 1; o < 256; o <<= 1) {
    int u = (t >= o) ? s[t-o] : 0; __syncthreads();
    s[t] += u; __syncthreads();
  }
  if (i < n) out[i] = s[t] - v;
  if (t == 255) bsum[blockIdx.x] = s[255];
}

__global__ __launch_bounds__(256) void k_scan_bsum(int* bsum, int nb) {
  __shared__ int s[256];
  int t = threadIdx.x;
  int v = (t < nb) ? bsum[t] : 0;
  s[t] = v; __syncthreads();
  #pragma unroll
  for (int o = 1; o < 256; o <<= 1) {
    int u = (t >= o) ? s[t-o] : 0; __syncthreads();
    s[t] += u; __syncthreads();
  }
  if (t < nb) bsum[t] = s[t] - v;
}

__global__ __launch_bounds__(256) void k_scan_add(int* out, const int* bsum, int n, int E) {
  int i = blockIdx.x*256 + threadIdx.x;
  if (i < n) out[i] += bsum[blockIdx.x];
  if (i == 0) out[n] = E;
}

// scatter: srcp only (dstp never read), ushort payload (node ids < 65536)
__global__ __launch_bounds__(256) void k_scatter(const int* src, const int* dst, int E,
                                                 const int* rowptr, int* cursor,
                                                 unsigned short* srcp) {
  int i = blockIdx.x*256 + threadIdx.x;
  if (i >= E) return;
  int d = dst[i];
  int pos = rowptr[d] + atomicAdd(&cursor[d], 1);
  srcp[pos] = (unsigned short)src[i];
}

// ---------- vnr-path aggregate: fused edge-exp, f32 ----------
__global__ __launch_bounds__(256) void k_aggregate_v(int nNodes, const int* __restrict__ rowptr,
    const unsigned short* __restrict__ srcp, const float* __restrict__ el,
    const float* __restrict__ er, const float* __restrict__ z,
    const float* __restrict__ bias, float* __restrict__ out) {
  int w = (blockIdx.x*256 + threadIdx.x) >> 6;
  int lane = threadIdx.x & 63;
  if (w >= nNodes) return;
  int beg = rowptr[w], end = rowptr[w+1];
  float erw = er[w];
  float a0 = 0.f, a1 = 0.f, wsum = 0.f;
  for (int i = beg; i < end; ++i) {
    int sI = srcp[i];
    float wt = __expf(lrelu02(el[sI] + erw));
    float2 zz = *(const float2*)(z + (size_t)sI*H_ + lane*2);
    a0 += wt*zz.x; a1 += wt*zz.y; wsum += wt;
  }
  float inv = (end > beg) ? fast_rcp(wsum) : 0.f;
  float2 o;
  o.x = a0*inv + bias[lane*2];
  o.y = a1*inv + bias[lane*2 + 1];
  *(float2*)(out + (size_t)w*H_ + lane*2) = o;
}

// ---------- static-path aggregate: bf16 z gather, 8x pipelined, split-bf16 out ----------
__global__ __launch_bounds__(256) void k_aggregate_split(int nNodes, const int* __restrict__ rowptr,
    const unsigned short* __restrict__ srcp, const float* __restrict__ el, const float* __restrict__ er,
    const unsigned short* __restrict__ z, const float* __restrict__ bias,
    unsigned short* __restrict__ outHi, unsigned short* __restrict__ outLo) {
  int w = (blockIdx.x*256 + threadIdx.x) >> 6;
  int lane = threadIdx.x & 63;
  if (w >= nNodes) return;
  int beg = rowptr[w], end = rowptr[w+1];
  float erw = er[w];
  float a0 = 0.f, a1 = 0.f, wsum = 0.f;
  int i = beg;
  for (; i + 8 <= end; i += 8) {
    int sI[8]; float lv[8]; ushort2 q[8];
    #pragma unroll
    for (int u = 0; u < 8; ++u) sI[u] = srcp[i+u];
    #pragma unroll
    for (int u = 0; u < 8; ++u) lv[u] = el[sI[u]];
    #pragma unroll
    for (int u = 0; u < 8; ++u) q[u] = *(const ushort2*)(z + (size_t)sI[u]*H_ + lane*2);
    #pragma unroll
    for (int u = 0; u < 8; ++u) {
      float wt = __expf(lrelu02(lv[u] + erw));
      a0 += wt*bf16_tof(q[u].x);
      a1 += wt*bf16_tof(q[u].y);
      wsum += wt;
    }
  }
  for (; i < end; ++i) {
    int sI = srcp[i];
    float wt = __expf(lrelu02(el[sI] + erw));
    ushort2 q = *(const ushort2*)(z + (size_t)sI*H_ + lane*2);
    a0 += wt*bf16_tof(q.x); a1 += wt*bf16_tof(q.y); wsum += wt;
  }
  float inv = (end > beg) ? fast_rcp(wsum) : 0.f;
  float o0 = a0*inv + bias[lane*2];
  float o1 = a1*inv + bias[lane*2 + 1];
  unsigned short h0 = bf16_rne(o0), h1 = bf16_rne(o1);
  unsigned short l0 = bf16_rne(o0 - bf16_tof(h0)), l1 = bf16_rne(o1 - bf16_tof(h1));
  ushort2 hv; hv.x = h0; hv.y = h1;
  ushort2 lv; lv.x = l0; lv.y = l1;
  *(ushort2*)(outHi + (size_t)w*H_ + lane*2) = hv;
  *(ushort2*)(outLo + (size_t)w*H_ + lane*2) = lv;
}

// ---------- fused weight prep: W_ih transpose + 3x split ----------
__global__ __launch_bounds__(256) void k_prep(const float* W_ih, const float* Ws2,
                                              const float* Ws3, const float* W_attn,
                                              float* WTih,
                                              unsigned short* WS2hi, unsigned short* WS2lo,
                                              unsigned short* WS3hi, unsigned short* WS3lo,
                                              unsigned short* WAhi, unsigned short* WAlo) {
  int idx = blockIdx.x*256 + threadIdx.x;
  int task = blockIdx.y;
  if (task == 0) {
    if (idx < 128*384) {
      int k = idx / 384, j = idx - k*384;
      WTih[idx] = W_ih[(size_t)j*128 + k];      // WTih[k][j] = W_ih[j][k]
    }
  } else {
    if (idx >= 128*128) return;
    int j = idx >> 7, k = idx & 127;
    float v; unsigned short *hi, *lo;
    if (task == 1)      { v = Ws2[(size_t)k*128 + j];    hi = WS2hi; lo = WS2lo; }
    else if (task == 2) { v = Ws3[(size_t)k*128 + j];    hi = WS3hi; lo = WS3lo; }
    else                { v = W_attn[(size_t)j*256 + k]; hi = WAhi;  lo = WAlo;  }
    unsigned short h = bf16_rne(v);
    hi[idx] = h; lo[idx] = bf16_rne(v - bf16_tof(h));
  }
}

// ---------- MFMA split-bf16 GEMM: C/Cb[M,128] = (Ahi+Alo)@(Whi+Wlo), WT[col][k] ----------
__global__ __launch_bounds__(256) void k_mfma_gemm(
    const unsigned short* __restrict__ Ahi, const unsigned short* __restrict__ Alo,
    const unsigned short* __restrict__ WThi, const unsigned short* __restrict__ WTlo,
    float* __restrict__ C, unsigned short* __restrict__ Cb,
    const float* __restrict__ al, const float* __restrict__ ar,
    float* __restrict__ el, float* __restrict__ er) {
  __shared__ unsigned short lAhi[64*136];
  __shared__ unsigned short lAlo[64*136];
  __shared__ float redl[4][64];
  __shared__ float redr[4][64];
  int t = threadIdx.x;
  int row0 = blockIdx.x * 64;
  int wid = t >> 6, lane = t & 63;
  int g = lane >> 4, c = lane & 15;

  #pragma unroll
  for (int i = 0; i < 4; ++i) {
    int m = t + 256*i;
    int r = m >> 4;
    int kc = (m & 15) * 8;
    *(short8v*)(lAhi + r*136 + kc) = *(const short8v*)(Ahi + (size_t)(row0 + r)*H_ + kc);
    *(short8v*)(lAlo + r*136 + kc) = *(const short8v*)(Alo + (size_t)(row0 + r)*H_ + kc);
  }

  short8v bhi[2][4], blo[2][4];
  #pragma unroll
  for (int ct = 0; ct < 2; ++ct) {
    int col = wid*32 + ct*16 + c;
    #pragma unroll
    for (int kb = 0; kb < 4; ++kb) {
      size_t o = (size_t)col*H_ + kb*32 + g*8;
      bhi[ct][kb] = *(const short8v*)(WThi + o);
      blo[ct][kb] = *(const short8v*)(WTlo + o);
    }
  }

  floatx4 acc[4][2];
  #pragma unroll
  for (int rt = 0; rt < 4; ++rt)
    #pragma unroll
    for (int ct = 0; ct < 2; ++ct)
      acc[rt][ct] = (floatx4){0.f, 0.f, 0.f, 0.f};

  __syncthreads();

  #pragma unroll
  for (int kb = 0; kb < 4; ++kb) {
    short8v ahi[4], alo[4];
    #pragma unroll
    for (int rt = 0; rt < 4; ++rt) {
      int r = rt*16 + c;
      ahi[rt] = *(const short8v*)(lAhi + r*136 + kb*32 + g*8);
      alo[rt] = *(const short8v*)(lAlo + r*136 + kb*32 + g*8);
    }
    #pragma unroll
    for (int rt = 0; rt < 4; ++rt)
      #pragma unroll
      for (int ct = 0; ct < 2; ++ct) {
        acc[rt][ct] = __builtin_amdgcn_mfma_f32_16x16x32_bf16(ahi[rt], bhi[ct][kb], acc[rt][ct], 0, 0, 0);
        acc[rt][ct] = __builtin_amdgcn_mfma_f32_16x16x32_bf16(alo[rt], bhi[ct][kb], acc[rt][ct], 0, 0, 0);
        acc[rt][ct] = __builtin_amdgcn_mfma_f32_16x16x32_bf16(ahi[rt], blo[ct][kb], acc[rt][ct], 0, 0, 0);
      }
  }

  #pragma unroll
  for (int rt = 0; rt < 4; ++rt)
    #pragma unroll
    for (int i = 0; i < 4; ++i) {
      int row = row0 + rt*16 + g*4 + i;
      if (Cb) {
        unsigned short* cr = Cb + (size_t)row*H_ + wid*32;
        cr[c]      = bf16_rne(acc[rt][0][i]);
        cr[16 + c] = bf16_rne(acc[rt][1][i]);
      } else {
        float* cr = C + (size_t)row*H_ + wid*32;
        cr[c]      = acc[rt][0][i];
        cr[16 + c] = acc[rt][1][i];
      }
    }

  if (el) {
    float av0 = al[wid*32 + c], av1 = al[wid*32 + 16 + c];
    float rv0 = ar[wid*32 + c], rv1 = ar[wid*32 + 16 + c];
    #pragma unroll
    for (int rt = 0; rt < 4; ++rt)
      #pragma unroll
      for (int i = 0; i < 4; ++i) {
        float pl = acc[rt][0][i]*av0 + acc[rt][1][i]*av1;
        float pr = acc[rt][0][i]*rv0 + acc[rt][1][i]*rv1;
        pl += __shfl_xor(pl, 1, 64); pl += __shfl_xor(pl, 2, 64);
        pl += __shfl_xor(pl, 4, 64); pl += __shfl_xor(pl, 8, 64);
        pr += __shfl_xor(pr, 1, 64); pr += __shfl_xor(pr, 2, 64);
        pr += __shfl_xor(pr, 4, 64); pr += __shfl_xor(pr, 8, 64);
        if (c == 0) { redl[wid][rt*16 + g*4 + i] = pl; redr[wid][rt*16 + g*4 + i] = pr; }
      }
    __syncthreads();
    if (t < 64) {
      el[row0 + t] = redl[0][t] + redl[1][t] + redl[2][t] + redl[3][t];
      er[row0 + t] = redr[0][t] + redr[1][t] + redr[2][t] + redr[3][t];
    }
  }
}

// ---------- generic f32 GEMM (layer-1 K=8 + tiny vnr/GI GEMMs) ----------
__global__ __launch_bounds__(256) void k_gemm(const float* A, int M, int K, int N,
                                              const float* W, const float* bias,
                                              float* C, unsigned short* Cb,
                                              const float* al, const float* ar,
                                              float* el, float* er) {
  __shared__ float Ws_[64*128];
  __shared__ float As_[16*128];
  __shared__ float redl[16][17];
  __shared__ float redr[16][17];
  int t = threadIdx.x;
  int j0 = blockIdx.y * 128;
  int row0 = blockIdx.x * 16;
  for (int l = t; l < 16*K; l += 256) {
    int r = l / K, k = l - r*K;
    int row = row0 + r;
    As_[r*K + k] = (row < M) ? A[(size_t)row*K + k] : 0.f;
  }
  int jg = t & 15, r = t >> 4;
  float acc[8];
  #pragma unroll
  for (int q = 0; q < 8; ++q) acc[q] = 0.f;
  for (int kc = 0; kc < K; kc += 64) {
    int kl = min(64, K - kc);
    __syncthreads();
    for (int l = t; l < (kl << 7); l += 256) {
      int k = l >> 7, j = l & 127;
      int jj = j0 + j;
      Ws_[l] = (jj < N) ? W[(size_t)(kc + k)*N + jj] : 0.f;
    }
    __syncthreads();
    for (int k = 0; k < kl; ++k) {
      float a = As_[r*K + kc + k];
      const float* wr = &Ws_[(k << 7) + jg*8];
      #pragma unroll
      for (int q = 0; q < 8; ++q) acc[q] += a * wr[q];
    }
  }
  int row = row0 + r;
  if (row < M) {
    if (Cb) {
      unsigned short* crow = Cb + (size_t)row*N + j0 + jg*8;
      #pragma unroll
      for (int q = 0; q < 8; ++q) {
        int j = j0 + jg*8 + q;
        if (j < N) crow[q] = bf16_rne(acc[q] + (bias ? bias[j] : 0.f));
      }
    } else {
      float* crow = C + (size_t)row*N + j0 + jg*8;
      #pragma unroll
      for (int q = 0; q < 8; ++q) {
        int j = j0 + jg*8 + q;
        if (j < N) crow[q] = acc[q] + (bias ? bias[j] : 0.f);
      }
    }
  }
  if (el) {
    float pl = 0.f, pr = 0.f;
    #pragma unroll
    for (int q = 0; q < 8; ++q) {
      int j = jg*8 + q;
      pl += acc[q]*al[j];
      pr += acc[q]*ar[j];
    }
    redl[r][jg] = pl; redr[r][jg] = pr;
    __syncthreads();
    if (t < 16) {
      float sl = 0.f, sr = 0.f;
      for (int q = 0; q < 16; ++q) { sl += redl[t][q]; sr += redr[t][q]; }
      int row2 = row0 + t;
      if (row2 < M) { el[row2] = sl; er[row2] = sr; }
    }
  }
}

// ---------- GRU decoder v3: weights register-resident, LDS-broadcast h ----------
__global__ __launch_bounds__(512) void k_decoder(const float* __restrict__ GI,
                                                 const float* __restrict__ W_hh,
                                                 const float* __restrict__ b_hh,
                                                 const float* __restrict__ W_attn,
                                                 const float* __restrict__ h0,
                                                 float* __restrict__ A2) {
  int b = blockIdx.x;
  __shared__ float h[128];
  __shared__ float gh[384];
  int t = threadIdx.x;
  const float4* wsrc = (t < 384)
      ? (const float4*)(W_hh + (size_t)t*128)
      : (const float4*)(W_attn + (size_t)(t-384)*256 + 128);
  float4 wreg[32];
  #pragma unroll
  for (int kk = 0; kk < 32; ++kk) wreg[kk] = wsrc[kk];
  float bh = (t < 384) ? b_hh[t] : 0.f;
  if (t < 128) h[t] = h0[t];
  __syncthreads();
  for (int s = 0; s < 10; ++s) {
    const float4* h4 = (const float4*)h;
    if (t < 384) {
      float a0 = 0.f, a1 = 0.f, a2 = 0.f, a3 = 0.f;
      #pragma unroll
      for (int kk = 0; kk < 32; kk += 4) {
        a0 += dot4(wreg[kk+0], h4[kk+0]);
        a1 += dot4(wreg[kk+1], h4[kk+1]);
        a2 += dot4(wreg[kk+2], h4[kk+2]);
        a3 += dot4(wreg[kk+3], h4[kk+3]);
      }
      gh[t] = (a0 + a1) + (a2 + a3) + bh;
    }
    __syncthreads();
    if (t < 128) {
      const float* gi = GI + (size_t)(b*NV_ + s)*384;
      float rr = fast_sigmoid(gi[t]       + gh[t]);
      float zz = fast_sigmoid(gi[128 + t] + gh[128 + t]);
      float nn = fast_tanh   (gi[256 + t] + rr*gh[256 + t]);
      h[t] = (1.f - zz)*nn + zz*h[t];
    }
    __syncthreads();
    if (t >= 384) {
      float a0 = 0.f, a1 = 0.f, a2 = 0.f, a3 = 0.f;
      #pragma unroll
      for (int kk = 0; kk < 32; kk += 4) {
        a0 += dot4(wreg[kk+0], h4[kk+0]);
        a1 += dot4(wreg[kk+1], h4[kk+1]);
        a2 += dot4(wreg[kk+2], h4[kk+2]);
        a3 += dot4(wreg[kk+3], h4[kk+3]);
      }
      A2[((size_t)s*B_ + b)*128 + (t - 384)] = (a0 + a1) + (a2 + a3);
    }
  }
}

// ---------- attention score + mask v3: rcp-form tanh, v in regs ----------
__global__ __launch_bounds__(256) void k_attn3(const float* __restrict__ A1,
                                               const float* __restrict__ A2,
                                               const float* __restrict__ v_attn,
                                               const int* __restrict__ vnr_VNF,
                                               const int* __restrict__ net_VNF,
                                               float* __restrict__ pi) {
  __shared__ float a2s[10][128];   // 2*A2
  __shared__ float vv2s[128];      // 2*v
  int b = blockIdx.y;
  int t = threadIdx.x;
  for (int i = t; i < 1280; i += 256) {
    int s = i >> 7, k = i & 127;
    a2s[s][k] = 2.f*A2[((size_t)s*B_ + b)*H_ + k];
  }
  if (t < 128) vv2s[t] = 2.f*v_attn[t];
  __syncthreads();
  int nl = t >> 2, p = t & 3;
  int n = blockIdx.x*64 + nl;
  if (n >= NN_) return;
  size_t g = (size_t)b*NN_ + n;
  const float4* arow = (const float4*)(A1 + g*H_ + p*32);
  float4 a[8], w2[8];
  #pragma unroll
  for (int kk = 0; kk < 8; ++kk) {
    float4 av = arow[kk];
    a[kk] = make_float4(2.f*av.x, 2.f*av.y, 2.f*av.z, 2.f*av.w);
    w2[kk] = *(const float4*)(&vv2s[p*32 + kk*4]);
  }
  float vsum = 0.f;
  #pragma unroll
  for (int kk = 0; kk < 8; ++kk)
    vsum += (w2[kk].x + w2[kk].y) + (w2[kk].z + w2[kk].w);
  vsum *= 0.5f;
  float acc[10];
  #pragma unroll
  for (int s = 0; s < 10; ++s) {
    const float* a2r = &a2s[s][p*32];
    float sum2 = 0.f;
    #pragma unroll
    for (int kk = 0; kk < 8; ++kk) {
      float4 c = *(const float4*)(a2r + kk*4);
      sum2 = fmaf(w2[kk].x, fast_rcp(1.f + __expf(a[kk].x + c.x)), sum2);
      sum2 = fmaf(w2[kk].y, fast_rcp(1.f + __expf(a[kk].y + c.y)), sum2);
      sum2 = fmaf(w2[kk].z, fast_rcp(1.f + __expf(a[kk].z + c.z)), sum2);
      sum2 = fmaf(w2[kk].w, fast_rcp(1.f + __expf(a[kk].w + c.w)), sum2);
    }
    acc[s] = vsum - sum2;
  }
  #pragma unroll
  for (int s = 0; s < 10; ++s) {
    acc[s] += __shfl_xor(acc[s], 1, 64);
    acc[s] += __shfl_xor(acc[s], 2, 64);
  }
  if (p == 0) {
    #pragma unroll
    for (int s = 0; s < 10; ++s) {
      int vnf = vnr_VNF[b*NV_ + s];
      int m   = net_VNF[g*T_ + vnf];
      pi[(size_t)b*(NV_*NN_) + (size_t)s*NN_ + n] = acc[s] + __logf((float)m);
    }
  }
}

// ---------- value head ----------
__global__ __launch_bounds__(128) void k_y2s(const unsigned short* hi, const unsigned short* lo,
                                             float* y2) {
  int b = blockIdx.x, slice = blockIdx.y, h = threadIdx.x;
  int n0 = slice*125, n1 = n0 + 125;
  float s = 0.f;
  for (int n = n0; n < n1; ++n) {
    size_t idx = ((size_t)b*NN_ + n)*H_ + h;
    s += bf16_tof(hi[idx]) + bf16_tof(lo[idx]);
  }
  atomicAdd(&y2[b*H_ + h], s);
}

// fused y1 + output projection
__global__ __launch_bounds__(128) void k_value(const float* __restrict__ Hv,
                                               const float* __restrict__ nmask,
                                               const float* __restrict__ y2,
                                               const float* __restrict__ W_out,
                                               const float* __restrict__ b_out,
                                               float* __restrict__ val) {
  __shared__ float y1s[128];
  int b = blockIdx.x, t = threadIdx.x;
  float s = 0.f, d = 0.f;
  #pragma unroll
  for (int i = 0; i < NV_; ++i) {
    float m = nmask[b*NV_ + i];
    s += Hv[(size_t)(b*NV_ + i)*H_ + t]*m;
    d += m;
  }
  y1s[t] = s/d;
  __syncthreads();
  if (t < 64) {
    const float* w = W_out + (size_t)t*256;
    float acc = b_out[t];
    for (int h = 0; h < H_; ++h)
      acc += y1s[h]*w[h] + (y2[b*H_ + h]*(1.f/1000.f))*w[128 + h];
    val[b*O_ + t] = acc;
  }
}

extern "C" void kernel_launch(void* const* d_in, const int* in_sizes, int n_in,
                              void* d_out, int out_size, void* d_ws, size_t ws_size,
                              hipStream_t stream) {
  (void)in_sizes; (void)n_in; (void)out_size; (void)ws_size;
  const float* static_feat = (const float*)d_in[0];
  const float* vnr_feat    = (const float*)d_in[1];
  const float* nmask       = (const float*)d_in[2];
  const float* Ws1 = (const float*)d_in[3];  const float* als1 = (const float*)d_in[4];
  const float* ars1 = (const float*)d_in[5]; const float* bs1 = (const float*)d_in[6];
  const float* Ws2 = (const float*)d_in[7];  const float* als2 = (const float*)d_in[8];
  const float* ars2 = (const float*)d_in[9]; const float* bs2 = (const float*)d_in[10];
  const float* Ws3 = (const float*)d_in[11]; const float* als3 = (const float*)d_in[12];
  const float* ars3 = (const float*)d_in[13]; const float* bs3 = (const float*)d_in[14];
  const float* Wv1 = (const float*)d_in[15]; const float* alv1 = (const float*)d_in[16];
  const float* arv1 = (const float*)d_in[17]; const float* bv1 = (const float*)d_in[18];
  const float* Wv2 = (const float*)d_in[19]; const float* alv2 = (const float*)d_in[20];
  const float* arv2 = (const float*)d_in[21]; const float* bv2 = (const float*)d_in[22];
  const float* Wv3 = (const float*)d_in[23]; const float* alv3 = (const float*)d_in[24];
  const float* arv3 = (const float*)d_in[25]; const float* bv3 = (const float*)d_in[26];
  const float* W_attn = (const float*)d_in[27];
  const float* v_attn = (const float*)d_in[28];
  const float* W_ih = (const float*)d_in[29];
  const float* W_hh = (const float*)d_in[30];
  const float* b_ih = (const float*)d_in[31];
  const float* b_hh = (const float*)d_in[32];
  const float* h0   = (const float*)d_in[33];
  const float* W_out = (const float*)d_in[34];
  const float* b_out = (const float*)d_in[35];
  const int* src_s = (const int*)d_in[36];
  const int* dst_s = (const int*)d_in[37];
  const int* src_v = (const int*)d_in[38];
  const int* dst_v = (const int*)d_in[39];
  const int* vnr_VNF = (const int*)d_in[40];
  const int* net_VNF = (const int*)d_in[41];

  char* ws = (char*)d_ws;
  size_t off = 0;
  auto alloc = [&](size_t bytes) -> char* {
    off = (off + 255) & ~(size_t)255;
    char* p = ws + off;
    off += bytes;
    return p;
  };
  float* Z    = (float*)alloc((size_t)NS_*H_*4);                 // A1 (f32)
  unsigned short* Zb   = (unsigned short*)alloc((size_t)NS_*H_*2);  // bf16 z for gather
  unsigned short* HsHi = (unsigned short*)alloc((size_t)NS_*H_*2);
  unsigned short* HsLo = (unsigned short*)alloc((size_t)NS_*H_*2);
  float* Zv   = (float*)alloc((size_t)NVT_*H_*4);
  float* Hv   = (float*)alloc((size_t)NVT_*H_*4);
  float* el_s = (float*)alloc((size_t)NS_*4);
  float* er_s = (float*)alloc((size_t)NS_*4);
  float* el_v = (float*)alloc((size_t)NVT_*4);
  float* er_v = (float*)alloc((size_t)NVT_*4);
  size_t zcount = (size_t)NS_ + NS_ + NVT_ + NVT_ + B_*H_;
  char* zb = alloc(zcount*4);
  int*   counts_s = (int*)zb;
  int*   cursor_s = counts_s + NS_;
  int*   counts_v = cursor_s + NS_;
  int*   cursor_v = counts_v + NVT_;
  float* y2buf    = (float*)(cursor_v + NVT_);
  int* rowptr_s = (int*)alloc((size_t)(NS_+1)*4);
  int* rowptr_v = (int*)alloc((size_t)(NVT_+1)*4);
  int* bsum     = (int*)alloc((size_t)256*4);
  unsigned short* srcp_s = (unsigned short*)alloc((size_t)EN_*2);
  unsigned short* srcp_v = (unsigned short*)alloc((size_t)EV_*2);
  unsigned short* WS2hi = (unsigned short*)alloc((size_t)H_*H_*2);
  unsigned short* WS2lo = (unsigned short*)alloc((size_t)H_*H_*2);
  unsigned short* WS3hi = (unsigned short*)alloc((size_t)H_*H_*2);
  unsigned short* WS3lo = (unsigned short*)alloc((size_t)H_*H_*2);
  unsigned short* WAhi  = (unsigned short*)alloc((size_t)H_*H_*2);
  unsigned short* WAlo  = (unsigned short*)alloc((size_t)H_*H_*2);
  float* WTih   = (float*)alloc((size_t)H_*384*4);
  float* GI     = (float*)alloc((size_t)NVT_*384*4);
  float* A2     = (float*)alloc((size_t)NV_*B_*H_*4);

  float* pi  = (float*)d_out;
  float* val = pi + (size_t)B_*NV_*NN_;

  hipMemsetAsync(zb, 0, zcount*4, stream);

  // weight re-layouts (fused)
  k_prep<<<dim3(192, 4), 256, 0, stream>>>(W_ih, Ws2, Ws3, W_attn, WTih,
                                           WS2hi, WS2lo, WS3hi, WS3lo, WAhi, WAlo);

  // CSR build (both graphs)
  k_count<<<EN_/256, 256, 0, stream>>>(dst_s, EN_, counts_s);
  k_count<<<EV_/256, 256, 0, stream>>>(dst_v, EV_, counts_v);
  k_scan_local<<<250, 256, 0, stream>>>(counts_s, NS_, rowptr_s, bsum);
  k_scan_bsum<<<1, 256, 0, stream>>>(bsum, 250);
  k_scan_add<<<250, 256, 0, stream>>>(rowptr_s, bsum, NS_, EN_);
  k_scan<<<1, 1024, 0, stream>>>(counts_v, NVT_, rowptr_v);
  k_scatter<<<EN_/256, 256, 0, stream>>>(src_s, dst_s, EN_, rowptr_s, cursor_s, srcp_s);
  k_scatter<<<EV_/256, 256, 0, stream>>>(src_v, dst_v, EV_, rowptr_v, cursor_v, srcp_v);

  dim3 gemmV(NVT_/16, 1);
  int aggS = (NS_ + 3)/4, aggV = (NVT_ + 3)/4;

  // ---- static GAT stack ----
  k_gemm<<<dim3(NS_/16, 1), 256, 0, stream>>>(static_feat, NS_, FS_, H_, Ws1, nullptr,
                                              nullptr, Zb, als1, ars1, el_s, er_s);
  k_aggregate_split<<<aggS, 256, 0, stream>>>(NS_, rowptr_s, srcp_s, el_s, er_s, Zb, bs1, HsHi, HsLo);
  k_mfma_gemm<<<NS_/64, 256, 0, stream>>>(HsHi, HsLo, WS2hi, WS2lo, nullptr, Zb, als2, ars2, el_s, er_s);
  k_aggregate_split<<<aggS, 256, 0, stream>>>(NS_, rowptr_s, srcp_s, el_s, er_s, Zb, bs2, HsHi, HsLo);
  k_mfma_gemm<<<NS_/64, 256, 0, stream>>>(HsHi, HsLo, WS3hi, WS3lo, nullptr, Zb, als3, ars3, el_s, er_s);
  k_aggregate_split<<<aggS, 256, 0, stream>>>(NS_, rowptr_s, srcp_s, el_s, er_s, Zb, bs3, HsHi, HsLo);

  // ---- vnr GAT stack (tiny, f32 path, fused edge-exp) ----
  k_gemm<<<gemmV, 256, 0, stream>>>(vnr_feat, NVT_, FV_, H_, Wv1, nullptr, Zv, nullptr, alv1, arv1, el_v, er_v);
  k_aggregate_v<<<aggV, 256, 0, stream>>>(NVT_, rowptr_v, srcp_v, el_v, er_v, Zv, bv1, Hv);
  k_gemm<<<gemmV, 256, 0, stream>>>(Hv, NVT_, H_, H_, Wv2, nullptr, Zv, nullptr, alv2, arv2, el_v, er_v);
  k_aggregate_v<<<aggV, 256, 0, stream>>>(NVT_, rowptr_v, srcp_v, el_v, er_v, Zv, bv2, Hv);
  k_gemm<<<gemmV, 256, 0, stream>>>(Hv, NVT_, H_, H_, Wv3, nullptr, Zv, nullptr, alv3, arv3, el_v, er_v);
  k_aggregate_v<<<aggV, 256, 0, stream>>>(NVT_, rowptr_v, srcp_v, el_v, er_v, Zv, bv3, Hv);

  // ---- decoder precomputation ----
  k_gemm<<<dim3(NVT_/16, 3), 256, 0, stream>>>(Hv, NVT_, H_, 384, WTih, b_ih, GI, nullptr,
                                               nullptr, nullptr, nullptr, nullptr);
  k_mfma_gemm<<<NS_/64, 256, 0, stream>>>(HsHi, HsLo, WAhi, WAlo, Z, nullptr,
                                          nullptr, nullptr, nullptr, nullptr);
  k_decoder<<<B_, 512, 0, stream>>>(GI, W_hh, b_hh, W_attn, h0, A2);
  k_attn3<<<dim3(16, B_), 256, 0, stream>>>(Z, A2, v_attn, vnr_VNF, net_VNF, pi);

  // ---- value head ----
  k_y2s<<<dim3(B_, 8), 128, 0, stream>>>(HsHi, HsLo, y2buf);
  k_value<<<B_, 128, 0, stream>>>(Hv, nmask, y2buf, W_out, b_out, val);
}